// Round 12
// baseline (1260.416 us; speedup 1.0000x reference)
//
#include <hip/hip_runtime.h>
#include <math.h>

#define SRC_LEN  1024
#define BSZ      64
#define CDIM     1024
#define ADIM     1024
#define KDIM     1024
#define MROWS    (SRC_LEN * BSZ)
#define NEG_MASK -1000000.0f

// tiled fp16 layout (256-row x 32-col tiles), halfword index within tile:
//   fr = row>>4 (0..15), lr = row&15, g = (col>>3)&3, e = col&7
//   hw = fr*512 + g*128 + lr*8 + e        (tile = 8192 hw = 16 KB)
// => fragment ds_read_b128 (64 lanes, lane=(g,lc)) covers 1KB contiguous
//    -> conflict-free; global->LDS staging is a plain contiguous copy.
#define THW32 8192

typedef _Float16 f16x8 __attribute__((ext_vector_type(8)));
typedef float    f32x4 __attribute__((ext_vector_type(4)));

__device__ __forceinline__ float fast_tanh(float x) {
    float e = __expf(2.0f * x);
    return 1.0f - 2.0f / (e + 1.0f);
}

// async global(16B) -> LDS, per-lane global src, wave-uniform LDS base
__device__ __forceinline__ void gload16(const _Float16* g, _Float16* l) {
    __builtin_amdgcn_global_load_lds(
        (const __attribute__((address_space(1))) unsigned int*)g,
        (__attribute__((address_space(3))) unsigned int*)l, 16, 0, 0);
}

__device__ __forceinline__ f16x8 cvt8(float4 x, float4 y) {
    f16x8 o;
    o[0] = (_Float16)x.x; o[1] = (_Float16)x.y;
    o[2] = (_Float16)x.z; o[3] = (_Float16)x.w;
    o[4] = (_Float16)y.x; o[5] = (_Float16)y.y;
    o[6] = (_Float16)y.z; o[7] = (_Float16)y.w;
    return o;
}

// ---------------------------------------------------------------------------
// fp32 [rows][1024] -> fp16 tiled, 256x32 tiles (tile id = rt*32 + ktn).
// Each block: 256 threads x 8 f16 = 2048 hw = 1/4 tile.
// ---------------------------------------------------------------------------
__global__ __launch_bounds__(256)
void convert_tiled32_kernel(const float* __restrict__ in, _Float16* __restrict__ out)
{
    const int bid  = blockIdx.x;
    const int part = bid & 3;            // quarter of the tile
    const int tile = bid >> 2;           // rt*32 + ktn
    const int ktn  = tile & 31;
    const int rt   = tile >> 5;
    const int t    = threadIdx.x;
    const int u    = part * 256 + t;     // 8-elem group 0..1023
    const int fr = u >> 6;
    const int gg = (u >> 4) & 3;
    const int lr = u & 15;

    const size_t row = (size_t)rt * 256 + fr * 16 + lr;
    const int    col = ktn * 32 + gg * 8;

    float4 x = *reinterpret_cast<const float4*>(&in[row * KDIM + col]);
    float4 y = *reinterpret_cast<const float4*>(&in[row * KDIM + col + 4]);
    *reinterpret_cast<f16x8*>(&out[(size_t)tile * THW32 + (size_t)u * 8]) = cvt8(x, y);
}

// ---------------------------------------------------------------------------
// fp32 -> fp16 linear (fallback path W conversion)
// ---------------------------------------------------------------------------
__global__ __launch_bounds__(256)
void convert8_kernel(const float* __restrict__ in, _Float16* __restrict__ out)
{
    size_t i = ((size_t)blockIdx.x * 256 + threadIdx.x) * 8;
    float4 x = *reinterpret_cast<const float4*>(in + i);
    float4 y = *reinterpret_cast<const float4*>(in + i + 4);
    *reinterpret_cast<f16x8*>(out + i) = cvt8(x, y);
}

// ---------------------------------------------------------------------------
// decb[b][n] += decoder_state @ W_dec^T  (k-split, atomic; no bias)
// ---------------------------------------------------------------------------
__global__ __launch_bounds__(256)
void dec_kernel(const float* __restrict__ A, const float* __restrict__ W,
                float* __restrict__ out)
{
    const int n0  = blockIdx.x * 64;
    const int k0  = blockIdx.y * 256;
    const int tid = threadIdx.x;
    const int tx  = tid & 15;
    const int ty  = tid >> 4;

    __shared__ float Asl[16][64];
    __shared__ float Bsl[16][64];

    float acc[4][4];
#pragma unroll
    for (int i = 0; i < 4; ++i)
#pragma unroll
        for (int j = 0; j < 4; ++j) acc[i][j] = 0.f;

    const int lr = tid >> 2;
    const int lk = (tid & 3) * 4;

    for (int kb = k0; kb < k0 + 256; kb += 16) {
        float4 a4 = *reinterpret_cast<const float4*>(&A[(size_t)lr * KDIM + kb + lk]);
        float4 b4 = *reinterpret_cast<const float4*>(&W[(size_t)(n0 + lr) * KDIM + kb + lk]);
        __syncthreads();
        Asl[lk + 0][lr] = a4.x; Asl[lk + 1][lr] = a4.y;
        Asl[lk + 2][lr] = a4.z; Asl[lk + 3][lr] = a4.w;
        Bsl[lk + 0][lr] = b4.x; Bsl[lk + 1][lr] = b4.y;
        Bsl[lk + 2][lr] = b4.z; Bsl[lk + 3][lr] = b4.w;
        __syncthreads();
#pragma unroll
        for (int k = 0; k < 16; ++k) {
            float4 av = *reinterpret_cast<const float4*>(&Asl[k][ty * 4]);
            float4 bv = *reinterpret_cast<const float4*>(&Bsl[k][tx * 4]);
            float am[4] = {av.x, av.y, av.z, av.w};
            float bn[4] = {bv.x, bv.y, bv.z, bv.w};
#pragma unroll
            for (int i = 0; i < 4; ++i)
#pragma unroll
                for (int j = 0; j < 4; ++j)
                    acc[i][j] = fmaf(am[i], bn[j], acc[i][j]);
        }
    }
#pragma unroll
    for (int i = 0; i < 4; ++i) {
        int m = ty * 4 + i;
#pragma unroll
        for (int j = 0; j < 4; ++j) {
            int n = n0 + tx * 4 + j;
            atomicAdd(&out[(size_t)m * ADIM + n], acc[i][j]);
        }
    }
}

// ---------------------------------------------------------------------------
// FAST PATH: 256x256 tile, BK=32 double-buffered (64 KB LDS -> 2 blocks/CU),
// 8 waves (2Mx4N), wave tile 128x64. Per K-tile: one vmcnt(0) + one barrier;
// all 4 stage-gloads of kt+1 issued at top (full-tile slack); reads 12 b128
// per wave (minimal); MFMA in two setprio-wrapped bursts of 16.
// TLP from 2 co-resident blocks covers the drain (m114 mechanism).
// ---------------------------------------------------------------------------
__global__ __launch_bounds__(512, 4)
void enc_score_256(const _Float16* __restrict__ At,   // [256mb*32] tiles
                   const _Float16* __restrict__ Bt,   // [4*32] tiles
                   const float* __restrict__ decb,    // [64][1024] (no bias)
                   const float* __restrict__ be,      // b_enc
                   const float* __restrict__ bd,      // b_dec
                   const float* __restrict__ v,       // [1024]
                   float* __restrict__ scores)        // [65536]
{
    // nwg=1024, XCD-grouped: the 4 nbt-sharers of one mb on one XCD.
    const int bid = blockIdx.x;
    const int nbt = (bid >> 3) & 3;
    const int mb  = (bid & 7) + ((bid >> 5) << 3);
    const int m0 = mb * 256, n0 = nbt * 256;
    const int tid  = threadIdx.x;
    const int lane = tid & 63;
    const int wid  = tid >> 6;          // 0..7
    const int wm   = wid >> 2;          // 0..1
    const int wn   = wid & 3;           // 0..3
    const int lc   = lane & 15, g = lane >> 4;

    __shared__ __align__(16) _Float16 As[2][THW32];   // 32 KB
    __shared__ __align__(16) _Float16 Bs[2][THW32];   // 32 KB

    f32x4 acc[8][4];
#pragma unroll
    for (int i = 0; i < 8; ++i)
#pragma unroll
        for (int j = 0; j < 4; ++j) acc[i][j] = (f32x4){0.f, 0.f, 0.f, 0.f};

    const _Float16* Abase = At + (size_t)(mb * 32) * THW32;
    const _Float16* Bbase = Bt + (size_t)(nbt * 32) * THW32;

    // staging: tile = 16 chunks of 1KB; wave wid owns chunks 2*wid, 2*wid+1
    const int off0 = (wid * 2) * 512 + lane * 8;
    const int off1 = off0 + 512;

    // ---- prologue: stage K-tile 0 ----
    gload16(Abase + off0, &As[0][off0]);
    gload16(Abase + off1, &As[0][off1]);
    gload16(Bbase + off0, &Bs[0][off0]);
    gload16(Bbase + off1, &Bs[0][off1]);
    asm volatile("s_waitcnt vmcnt(0)" ::: "memory");
    __builtin_amdgcn_s_barrier();
    asm volatile("" ::: "memory");

    for (int kt = 0; kt < 32; ++kt) {
        const int cur = kt & 1;
        const _Float16* Ac = As[cur];
        const _Float16* Bc = Bs[cur];

        if (kt) asm volatile("s_waitcnt vmcnt(0)" ::: "memory");  // tile kt landed

        f16x8 bf[4], af[4];
#pragma unroll
        for (int ni = 0; ni < 4; ++ni)
            bf[ni] = *reinterpret_cast<const f16x8*>(
                &Bc[(wn * 4 + ni) * 512 + g * 128 + lc * 8]);
#pragma unroll
        for (int mi = 0; mi < 4; ++mi)
            af[mi] = *reinterpret_cast<const f16x8*>(
                &Ac[(wm * 8 + mi) * 512 + g * 128 + lc * 8]);

        if (kt < 31) {   // stage tile kt+1 into the other buffer (full-tile slack)
            const _Float16* Ag = Abase + (size_t)(kt + 1) * THW32;
            const _Float16* Bg = Bbase + (size_t)(kt + 1) * THW32;
            _Float16* Ad = &As[cur ^ 1][0];
            _Float16* Bd = &Bs[cur ^ 1][0];
            gload16(Ag + off0, Ad + off0);
            gload16(Ag + off1, Ad + off1);
            gload16(Bg + off0, Bd + off0);
            gload16(Bg + off1, Bd + off1);
        }

        asm volatile("s_waitcnt lgkmcnt(0)" ::: "memory");
        __builtin_amdgcn_sched_barrier(0);
        __builtin_amdgcn_s_setprio(1);
#pragma unroll
        for (int mi = 0; mi < 4; ++mi)
#pragma unroll
            for (int ni = 0; ni < 4; ++ni)
                acc[mi][ni] = __builtin_amdgcn_mfma_f32_16x16x32_f16(
                    af[mi], bf[ni], acc[mi][ni], 0, 0, 0);
        __builtin_amdgcn_s_setprio(0);

        f16x8 af2[4];
#pragma unroll
        for (int mi = 0; mi < 4; ++mi)
            af2[mi] = *reinterpret_cast<const f16x8*>(
                &Ac[(wm * 8 + 4 + mi) * 512 + g * 128 + lc * 8]);
        asm volatile("s_waitcnt lgkmcnt(0)" ::: "memory");
        __builtin_amdgcn_sched_barrier(0);
        __builtin_amdgcn_s_setprio(1);
#pragma unroll
        for (int mi = 0; mi < 4; ++mi)
#pragma unroll
            for (int ni = 0; ni < 4; ++ni)
                acc[4 + mi][ni] = __builtin_amdgcn_mfma_f32_16x16x32_f16(
                    af2[mi], bf[ni], acc[4 + mi][ni], 0, 0, 0);
        __builtin_amdgcn_s_setprio(0);

        __builtin_amdgcn_s_barrier();   // all reads of [cur] done -> kt+1 may stage into it
        asm volatile("" ::: "memory");
    }

    // ---- fused epilogue: tanh + v-dot + reduce ----
    __syncthreads();

    float psum[8][4];
#pragma unroll
    for (int mi = 0; mi < 8; ++mi)
#pragma unroll
        for (int r = 0; r < 4; ++r) psum[mi][r] = 0.f;

#pragma unroll
    for (int mi = 0; mi < 8; ++mi) {
#pragma unroll
        for (int ni = 0; ni < 4; ++ni) {
            int n = n0 + wn * 64 + ni * 16 + lc;
            float vn = v[n];
            float bb = be[n] + bd[n];
#pragma unroll
            for (int r = 0; r < 4; ++r) {
                int b = ((mi & 3) * 16) + g * 4 + r;   // row & 63
                float x = acc[mi][ni][r] + decb[(size_t)b * ADIM + n] + bb;
                psum[mi][r] = fmaf(fast_tanh(x), vn, psum[mi][r]);
            }
        }
    }
#pragma unroll
    for (int mi = 0; mi < 8; ++mi)
#pragma unroll
        for (int r = 0; r < 4; ++r) {
            float s = psum[mi][r];
            s += __shfl_xor(s, 1);
            s += __shfl_xor(s, 2);
            s += __shfl_xor(s, 4);
            s += __shfl_xor(s, 8);
            psum[mi][r] = s;
        }

    float* red = reinterpret_cast<float*>(&As[0][0]);   // [256][4] = 4 KB
    if (lc == 0) {
#pragma unroll
        for (int mi = 0; mi < 8; ++mi)
#pragma unroll
            for (int r = 0; r < 4; ++r) {
                int row = wm * 128 + mi * 16 + g * 4 + r;
                red[row * 4 + wn] = psum[mi][r];
            }
    }
    __syncthreads();
    if (tid < 256)
        atomicAdd(&scores[m0 + tid],
                  red[tid * 4] + red[tid * 4 + 1] + red[tid * 4 + 2] + red[tid * 4 + 3]);
}

// ---------------------------------------------------------------------------
// FALLBACK (ws too small): reg-staged fp32-A 128x128 version.
// ---------------------------------------------------------------------------
__global__ __launch_bounds__(256)
void enc_score_fallback(const float* __restrict__ A,
                        const _Float16* __restrict__ Bw,
                        const float* __restrict__ decb,
                        const float* __restrict__ be,
                        const float* __restrict__ bd,
                        const float* __restrict__ v,
                        float* __restrict__ scores)
{
    const int bid = blockIdx.x;
    const int nb  = (bid >> 3) & 7;
    const int mb  = (bid & 7) + ((bid >> 6) << 3);
    const int m0 = mb * 128, n0 = nb * 128;
    const int tid  = threadIdx.x;
    const int lane = tid & 63;
    const int wid  = tid >> 6;
    const int wm   = wid >> 1, wn = wid & 1;
    const int lc   = lane & 15, g = lane >> 4;

    __shared__ __align__(16) _Float16 As[128 * 64];
    __shared__ __align__(16) _Float16 Bs[128 * 64];

    const int srow = tid >> 1;
    const int scol = (tid & 1) * 32;
    const int sw   = (srow & 7) << 3;

    f32x4 acc[4][4];
#pragma unroll
    for (int i = 0; i < 4; ++i)
#pragma unroll
        for (int j = 0; j < 4; ++j) acc[i][j] = (f32x4){0.f, 0.f, 0.f, 0.f};

    const float*    Aptr = A  + (size_t)(m0 + srow) * KDIM + scol;
    const _Float16* Bptr = Bw + (size_t)(n0 + srow) * KDIM + scol;

    float4 aR[8];
    uint4  bR[4];
#pragma unroll
    for (int i = 0; i < 8; ++i) aR[i] = reinterpret_cast<const float4*>(Aptr)[i];
#pragma unroll
    for (int i = 0; i < 4; ++i) bR[i] = reinterpret_cast<const uint4*>(Bptr)[i];

    for (int kb = 0; kb < KDIM; kb += 64) {
        __syncthreads();
#pragma unroll
        for (int w = 0; w < 4; ++w) {
            int hw = (srow * 64 + scol + 8 * w) ^ sw;
            *reinterpret_cast<f16x8*>(&As[hw]) = cvt8(aR[2 * w], aR[2 * w + 1]);
            *reinterpret_cast<uint4*>(&Bs[hw]) = bR[w];
        }
        __syncthreads();
        if (kb + 64 < KDIM) {
#pragma unroll
            for (int i = 0; i < 8; ++i)
                aR[i] = reinterpret_cast<const float4*>(Aptr + kb + 64)[i];
#pragma unroll
            for (int i = 0; i < 4; ++i)
                bR[i] = reinterpret_cast<const uint4*>(Bptr + kb + 64)[i];
        }
#pragma unroll
        for (int ks = 0; ks < 2; ++ks) {
            f16x8 af[4], bf[4];
#pragma unroll
            for (int mi = 0; mi < 4; ++mi) {
                int r  = wm * 64 + mi * 16 + lc;
                int hw = (r * 64 + ks * 32 + g * 8) ^ ((r & 7) << 3);
                af[mi] = *reinterpret_cast<const f16x8*>(&As[hw]);
            }
#pragma unroll
            for (int ni = 0; ni < 4; ++ni) {
                int r  = wn * 64 + ni * 16 + lc;
                int hw = (r * 64 + ks * 32 + g * 8) ^ ((r & 7) << 3);
                bf[ni] = *reinterpret_cast<const f16x8*>(&Bs[hw]);
            }
#pragma unroll
            for (int mi = 0; mi < 4; ++mi)
#pragma unroll
                for (int ni = 0; ni < 4; ++ni)
                    acc[mi][ni] = __builtin_amdgcn_mfma_f32_16x16x32_f16(
                        af[mi], bf[ni], acc[mi][ni], 0, 0, 0);
        }
    }

    __syncthreads();

    float psum[4][4];
#pragma unroll
    for (int mi = 0; mi < 4; ++mi)
#pragma unroll
        for (int r = 0; r < 4; ++r) psum[mi][r] = 0.f;

#pragma unroll
    for (int mi = 0; mi < 4; ++mi) {
#pragma unroll
        for (int ni = 0; ni < 4; ++ni) {
            int n = n0 + wn * 64 + ni * 16 + lc;
            float vn = v[n];
            float bb = be[n] + bd[n];
#pragma unroll
            for (int r = 0; r < 4; ++r) {
                int b = mi * 16 + g * 4 + r;
                float x = acc[mi][ni][r] + decb[(size_t)b * ADIM + n] + bb;
                psum[mi][r] = fmaf(fast_tanh(x), vn, psum[mi][r]);
            }
        }
    }
#pragma unroll
    for (int mi = 0; mi < 4; ++mi)
#pragma unroll
        for (int r = 0; r < 4; ++r) {
            float s = psum[mi][r];
            s += __shfl_xor(s, 1);
            s += __shfl_xor(s, 2);
            s += __shfl_xor(s, 4);
            s += __shfl_xor(s, 8);
            psum[mi][r] = s;
        }

    float* red = reinterpret_cast<float*>(As);
    if (lc == 0) {
#pragma unroll
        for (int mi = 0; mi < 4; ++mi)
#pragma unroll
            for (int r = 0; r < 4; ++r) {
                int row = wm * 64 + mi * 16 + g * 4 + r;
                red[row * 2 + wn] = psum[mi][r];
            }
    }
    __syncthreads();
    if (tid < 128)
        atomicAdd(&scores[m0 + tid], red[tid * 2] + red[tid * 2 + 1]);
}

// ---------------------------------------------------------------------------
// Masked softmax over S per batch column, in place. One block per b.
// ---------------------------------------------------------------------------
__global__ __launch_bounds__(256)
void softmax_kernel(const int* __restrict__ lens, float* __restrict__ attn)
{
    const int b   = blockIdx.x;
    const int tid = threadIdx.x;
    const int len = lens[b];

    float sc[4];
#pragma unroll
    for (int k = 0; k < 4; ++k) {
        int s = k * 256 + tid;
        float x = attn[(size_t)s * BSZ + b];
        sc[k] = (s < len) ? x : NEG_MASK;
    }

    __shared__ float red[8];

    float m = fmaxf(fmaxf(sc[0], sc[1]), fmaxf(sc[2], sc[3]));
#pragma unroll
    for (int off = 32; off > 0; off >>= 1) m = fmaxf(m, __shfl_xor(m, off));
    if ((tid & 63) == 0) red[tid >> 6] = m;
    __syncthreads();
    m = fmaxf(fmaxf(red[0], red[1]), fmaxf(red[2], red[3]));

    float e[4];
    float sum = 0.f;
#pragma unroll
    for (int k = 0; k < 4; ++k) { e[k] = expf(sc[k] - m); sum += e[k]; }
#pragma unroll
    for (int off = 32; off > 0; off >>= 1) sum += __shfl_xor(sum, off);
    __syncthreads();
    if ((tid & 63) == 0) red[4 + (tid >> 6)] = sum;
    __syncthreads();
    float total = red[4] + red[5] + red[6] + red[7];
    float inv = 1.f / total;

#pragma unroll
    for (int k = 0; k < 4; ++k) {
        int s = k * 256 + tid;
        attn[(size_t)s * BSZ + b] = e[k] * inv;
    }
}

// ---------------------------------------------------------------------------
// ctx[b][c] = sum_s attn[s][b] * hids[s][b][c]   (fp32 source, coalesced)
// ---------------------------------------------------------------------------
__global__ __launch_bounds__(256)
void ctx_kernel(const float* __restrict__ hids, const float* __restrict__ attn,
                float* __restrict__ ctx)
{
    const int b   = blockIdx.x;
    const int s0  = blockIdx.y * (SRC_LEN / 8);
    const int tid = threadIdx.x;

    float4 acc = make_float4(0.f, 0.f, 0.f, 0.f);
    for (int s = s0; s < s0 + SRC_LEN / 8; ++s) {
        float w = attn[(size_t)s * BSZ + b];
        if (w != 0.f) {
            float4 h = *reinterpret_cast<const float4*>(
                &hids[((size_t)s * BSZ + b) * CDIM + tid * 4]);
            acc.x = fmaf(w, h.x, acc.x);
            acc.y = fmaf(w, h.y, acc.y);
            acc.z = fmaf(w, h.z, acc.z);
            acc.w = fmaf(w, h.w, acc.w);
        }
    }
    float* dst = &ctx[(size_t)b * CDIM + tid * 4];
    atomicAdd(dst + 0, acc.x);
    atomicAdd(dst + 1, acc.y);
    atomicAdd(dst + 2, acc.z);
    atomicAdd(dst + 3, acc.w);
}

// ---------------------------------------------------------------------------
extern "C" void kernel_launch(void* const* d_in, const int* in_sizes, int n_in,
                              void* d_out, int out_size, void* d_ws, size_t ws_size,
                              hipStream_t stream)
{
    const float* dsr   = (const float*)d_in[0];
    const float* hids  = (const float*)d_in[1];
    const int*   lens  = (const int*)  d_in[2];
    const float* W_enc = (const float*)d_in[3];
    const float* b_enc = (const float*)d_in[4];
    const float* W_dec = (const float*)d_in[5];
    const float* b_dec = (const float*)d_in[6];
    const float* v     = (const float*)d_in[7];

    float* out  = (float*)d_out;
    float* ctx  = out;                       // [64*1024]
    float* attn = out + BSZ * CDIM;          // [1024*64] scores -> probs

    const size_t decb_b = (size_t)BSZ * ADIM * 4;     // 256 KB
    const size_t wf16_b = (size_t)ADIM * KDIM * 2;    // 2 MB
    const size_t af16_b = (size_t)MROWS * KDIM * 2;   // 128 MB

    float*    decb = (float*)d_ws;
    _Float16* Wt   = (_Float16*)((char*)d_ws + decb_b);
    _Float16* At   = (_Float16*)((char*)d_ws + decb_b + wf16_b);

    const bool fast = ws_size >= decb_b + wf16_b + af16_b;

    hipMemsetAsync(d_out, 0, (size_t)(BSZ * CDIM + SRC_LEN * BSZ) * sizeof(float), stream);
    hipMemsetAsync(d_ws, 0, decb_b, stream);   // decb is an atomic target

    dec_kernel<<<dim3(16, 4), 256, 0, stream>>>(dsr, W_dec, decb);

    if (fast) {
        convert_tiled32_kernel<<<(ADIM / 256) * 32 * 4, 256, 0, stream>>>(W_enc, Wt);
        convert_tiled32_kernel<<<(MROWS / 256) * 32 * 4, 256, 0, stream>>>(hids, At);
        enc_score_256<<<1024, 512, 0, stream>>>(At, Wt, decb, b_enc, b_dec, v, attn);
    } else {
        convert8_kernel<<<ADIM * KDIM / 8 / 256, 256, 0, stream>>>(W_enc, Wt);
        enc_score_fallback<<<4096, 256, 0, stream>>>(hids, Wt, decb, b_enc, b_dec, v, attn);
    }
    softmax_kernel<<<BSZ, 256, 0, stream>>>(lens, attn);
    ctx_kernel<<<dim3(BSZ, 8), 256, 0, stream>>>(hids, attn, ctx);
}

// Round 14
// 397.134 us; speedup vs baseline: 3.1738x; 3.1738x over previous
//
#include <hip/hip_runtime.h>
#include <math.h>

#define SRC_LEN  1024
#define BSZ      64
#define CDIM     1024
#define ADIM     1024
#define KDIM     1024
#define MROWS    (SRC_LEN * BSZ)
#define NEG_MASK -1000000.0f

// tiled fp16 layout (256-row x 32-col tiles), halfword index within tile:
//   fr = row>>4 (0..15), lr = row&15, g = (col>>3)&3, e = col&7
//   hw = fr*512 + g*128 + lr*8 + e        (tile = 8192 hw = 16 KB)
// => fragment ds_read_b128 (64 lanes, lane=(g,lc)) covers 1KB contiguous
//    -> conflict-free; global->LDS staging is a plain contiguous copy.
#define THW32 8192

typedef _Float16 f16x8 __attribute__((ext_vector_type(8)));
typedef float    f32x4 __attribute__((ext_vector_type(4)));

__device__ __forceinline__ float fast_tanh(float x) {
    float e = __expf(2.0f * x);
    return 1.0f - 2.0f / (e + 1.0f);
}

// async global(16B) -> LDS, per-lane global src, wave-uniform LDS base
__device__ __forceinline__ void gload16(const _Float16* g, _Float16* l) {
    __builtin_amdgcn_global_load_lds(
        (const __attribute__((address_space(1))) unsigned int*)g,
        (__attribute__((address_space(3))) unsigned int*)l, 16, 0, 0);
}

__device__ __forceinline__ f16x8 cvt8(float4 x, float4 y) {
    f16x8 o;
    o[0] = (_Float16)x.x; o[1] = (_Float16)x.y;
    o[2] = (_Float16)x.z; o[3] = (_Float16)x.w;
    o[4] = (_Float16)y.x; o[5] = (_Float16)y.y;
    o[6] = (_Float16)y.z; o[7] = (_Float16)y.w;
    return o;
}

// ---------------------------------------------------------------------------
// fp32 [rows][1024] -> fp16 tiled, 256x32 tiles (tile id = rt*32 + ktn).
// Each block: 256 threads x 8 f16 = 2048 hw = 1/4 tile.
// ---------------------------------------------------------------------------
__global__ __launch_bounds__(256)
void convert_tiled32_kernel(const float* __restrict__ in, _Float16* __restrict__ out)
{
    const int bid  = blockIdx.x;
    const int part = bid & 3;            // quarter of the tile
    const int tile = bid >> 2;           // rt*32 + ktn
    const int ktn  = tile & 31;
    const int rt   = tile >> 5;
    const int t    = threadIdx.x;
    const int u    = part * 256 + t;     // 8-elem group 0..1023
    const int fr = u >> 6;
    const int gg = (u >> 4) & 3;
    const int lr = u & 15;

    const size_t row = (size_t)rt * 256 + fr * 16 + lr;
    const int    col = ktn * 32 + gg * 8;

    float4 x = *reinterpret_cast<const float4*>(&in[row * KDIM + col]);
    float4 y = *reinterpret_cast<const float4*>(&in[row * KDIM + col + 4]);
    *reinterpret_cast<f16x8*>(&out[(size_t)tile * THW32 + (size_t)u * 8]) = cvt8(x, y);
}

// ---------------------------------------------------------------------------
// fp32 -> fp16 linear (fallback path W conversion)
// ---------------------------------------------------------------------------
__global__ __launch_bounds__(256)
void convert8_kernel(const float* __restrict__ in, _Float16* __restrict__ out)
{
    size_t i = ((size_t)blockIdx.x * 256 + threadIdx.x) * 8;
    float4 x = *reinterpret_cast<const float4*>(in + i);
    float4 y = *reinterpret_cast<const float4*>(in + i + 4);
    *reinterpret_cast<f16x8*>(out + i) = cvt8(x, y);
}

// ---------------------------------------------------------------------------
// decb[b][n] += decoder_state @ W_dec^T  (k-split, atomic; no bias)
// ---------------------------------------------------------------------------
__global__ __launch_bounds__(256)
void dec_kernel(const float* __restrict__ A, const float* __restrict__ W,
                float* __restrict__ out)
{
    const int n0  = blockIdx.x * 64;
    const int k0  = blockIdx.y * 256;
    const int tid = threadIdx.x;
    const int tx  = tid & 15;
    const int ty  = tid >> 4;

    __shared__ float Asl[16][64];
    __shared__ float Bsl[16][64];

    float acc[4][4];
#pragma unroll
    for (int i = 0; i < 4; ++i)
#pragma unroll
        for (int j = 0; j < 4; ++j) acc[i][j] = 0.f;

    const int lr = tid >> 2;
    const int lk = (tid & 3) * 4;

    for (int kb = k0; kb < k0 + 256; kb += 16) {
        float4 a4 = *reinterpret_cast<const float4*>(&A[(size_t)lr * KDIM + kb + lk]);
        float4 b4 = *reinterpret_cast<const float4*>(&W[(size_t)(n0 + lr) * KDIM + kb + lk]);
        __syncthreads();
        Asl[lk + 0][lr] = a4.x; Asl[lk + 1][lr] = a4.y;
        Asl[lk + 2][lr] = a4.z; Asl[lk + 3][lr] = a4.w;
        Bsl[lk + 0][lr] = b4.x; Bsl[lk + 1][lr] = b4.y;
        Bsl[lk + 2][lr] = b4.z; Bsl[lk + 3][lr] = b4.w;
        __syncthreads();
#pragma unroll
        for (int k = 0; k < 16; ++k) {
            float4 av = *reinterpret_cast<const float4*>(&Asl[k][ty * 4]);
            float4 bv = *reinterpret_cast<const float4*>(&Bsl[k][tx * 4]);
            float am[4] = {av.x, av.y, av.z, av.w};
            float bn[4] = {bv.x, bv.y, bv.z, bv.w};
#pragma unroll
            for (int i = 0; i < 4; ++i)
#pragma unroll
                for (int j = 0; j < 4; ++j)
                    acc[i][j] = fmaf(am[i], bn[j], acc[i][j]);
        }
    }
#pragma unroll
    for (int i = 0; i < 4; ++i) {
        int m = ty * 4 + i;
#pragma unroll
        for (int j = 0; j < 4; ++j) {
            int n = n0 + tx * 4 + j;
            atomicAdd(&out[(size_t)m * ADIM + n], acc[i][j]);
        }
    }
}

// ---------------------------------------------------------------------------
// FAST PATH: 256x256 tile, BK=32, TRIPLE-buffered (96 KB LDS), 8 waves,
// wave tile 128x64, launch_bounds(512,1) -> no VGPR spill (R12 lesson).
// Per K-tile: entry vmcnt(4) (counted: retires tile kt exactly; kt+1's 4
// loads stay in flight) + 1 barrier; stage tile kt+2 (2A+2B gloads/wave,
// ~2 tiles of slack); 2 MFMA phases (12 b128 reads total, minimal);
// lgkmcnt(0) + 1 end barrier. 2 barriers/tile vs R8's 8.
// ---------------------------------------------------------------------------
__global__ __launch_bounds__(512, 1)
void enc_score_256(const _Float16* __restrict__ At,   // [256mb*32] tiles
                   const _Float16* __restrict__ Bt,   // [4*32] tiles
                   const float* __restrict__ decb,    // [64][1024] (no bias)
                   const float* __restrict__ be,      // b_enc
                   const float* __restrict__ bd,      // b_dec
                   const float* __restrict__ v,       // [1024]
                   float* __restrict__ scores)        // [65536]
{
    // nwg=1024, XCD-grouped: the 4 nbt-sharers of one mb on one XCD.
    const int bid = blockIdx.x;
    const int nbt = (bid >> 3) & 3;
    const int mb  = (bid & 7) + ((bid >> 5) << 3);
    const int m0 = mb * 256, n0 = nbt * 256;
    const int tid  = threadIdx.x;
    const int lane = tid & 63;
    const int wid  = tid >> 6;          // 0..7
    const int wm   = wid >> 2;          // 0..1
    const int wn   = wid & 3;           // 0..3
    const int lc   = lane & 15, g = lane >> 4;

    __shared__ __align__(16) _Float16 As[3][THW32];   // 48 KB
    __shared__ __align__(16) _Float16 Bs[3][THW32];   // 48 KB

    f32x4 acc[8][4];
#pragma unroll
    for (int i = 0; i < 8; ++i)
#pragma unroll
        for (int j = 0; j < 4; ++j) acc[i][j] = (f32x4){0.f, 0.f, 0.f, 0.f};

    const _Float16* Abase = At + (size_t)(mb * 32) * THW32;
    const _Float16* Bbase = Bt + (size_t)(nbt * 32) * THW32;

    // staging: tile = 16 chunks of 1KB; wave wid owns chunks 2*wid, 2*wid+1
    const int off0 = (wid * 2) * 512 + lane * 8;
    const int off1 = off0 + 512;

    // ---- prologue: stage K-tiles 0 and 1 (order: t0 A,B then t1 A,B) ----
    gload16(Abase + off0, &As[0][off0]);
    gload16(Abase + off1, &As[0][off1]);
    gload16(Bbase + off0, &Bs[0][off0]);
    gload16(Bbase + off1, &Bs[0][off1]);
    gload16(Abase + THW32 + off0, &As[1][off0]);
    gload16(Abase + THW32 + off1, &As[1][off1]);
    gload16(Bbase + THW32 + off0, &Bs[1][off0]);
    gload16(Bbase + THW32 + off1, &Bs[1][off1]);

    int cur = 0;
    for (int kt = 0; kt < 32; ++kt) {
        const _Float16* Ac = As[cur];
        const _Float16* Bc = Bs[cur];

        // counted wait: retires tile kt's 4 loads exactly (kt+1's stay in flight)
        if (kt < 31) asm volatile("s_waitcnt vmcnt(4)" ::: "memory");
        else         asm volatile("s_waitcnt vmcnt(0)" ::: "memory");
        __builtin_amdgcn_s_barrier();      // tile kt visible to all waves
        asm volatile("" ::: "memory");

        if (kt < 30) {   // stage tile kt+2 into buf[(kt+2)%3] (~2 tiles slack)
            const int b2 = (cur + 2 >= 3) ? cur - 1 : cur + 2;
            const _Float16* Ag = Abase + (size_t)(kt + 2) * THW32;
            const _Float16* Bg = Bbase + (size_t)(kt + 2) * THW32;
            gload16(Ag + off0, &As[b2][off0]);
            gload16(Ag + off1, &As[b2][off1]);
            gload16(Bg + off0, &Bs[b2][off0]);
            gload16(Bg + off1, &Bs[b2][off1]);
        }

        // ---- phase 0: mi 0..3 ----
        f16x8 bf[4], af[4];
#pragma unroll
        for (int ni = 0; ni < 4; ++ni)
            bf[ni] = *reinterpret_cast<const f16x8*>(
                &Bc[(wn * 4 + ni) * 512 + g * 128 + lc * 8]);
#pragma unroll
        for (int mi = 0; mi < 4; ++mi)
            af[mi] = *reinterpret_cast<const f16x8*>(
                &Ac[(wm * 8 + mi) * 512 + g * 128 + lc * 8]);
        asm volatile("s_waitcnt lgkmcnt(0)" ::: "memory");
        __builtin_amdgcn_sched_barrier(0);
        __builtin_amdgcn_s_setprio(1);
#pragma unroll
        for (int mi = 0; mi < 4; ++mi)
#pragma unroll
            for (int ni = 0; ni < 4; ++ni)
                acc[mi][ni] = __builtin_amdgcn_mfma_f32_16x16x32_f16(
                    af[mi], bf[ni], acc[mi][ni], 0, 0, 0);
        __builtin_amdgcn_s_setprio(0);

        // ---- phase 1: mi 4..7 ----
        f16x8 af2[4];
#pragma unroll
        for (int mi = 0; mi < 4; ++mi)
            af2[mi] = *reinterpret_cast<const f16x8*>(
                &Ac[(wm * 8 + 4 + mi) * 512 + g * 128 + lc * 8]);
        asm volatile("s_waitcnt lgkmcnt(0)" ::: "memory");
        __builtin_amdgcn_sched_barrier(0);
        __builtin_amdgcn_s_setprio(1);
#pragma unroll
        for (int mi = 0; mi < 4; ++mi)
#pragma unroll
            for (int ni = 0; ni < 4; ++ni)
                acc[4 + mi][ni] = __builtin_amdgcn_mfma_f32_16x16x32_f16(
                    af2[mi], bf[ni], acc[4 + mi][ni], 0, 0, 0);
        __builtin_amdgcn_s_setprio(0);

        // all reads of buf[cur] retired -> staging during kt+1 may overwrite it
        asm volatile("s_waitcnt lgkmcnt(0)" ::: "memory");
        __builtin_amdgcn_s_barrier();
        asm volatile("" ::: "memory");

        cur = (cur == 2) ? 0 : cur + 1;
    }

    // ---- fused epilogue: tanh + v-dot + reduce ----
    __syncthreads();

    float psum[8][4];
#pragma unroll
    for (int mi = 0; mi < 8; ++mi)
#pragma unroll
        for (int r = 0; r < 4; ++r) psum[mi][r] = 0.f;

#pragma unroll
    for (int mi = 0; mi < 8; ++mi) {
#pragma unroll
        for (int ni = 0; ni < 4; ++ni) {
            int n = n0 + wn * 64 + ni * 16 + lc;
            float vn = v[n];
            float bb = be[n] + bd[n];
#pragma unroll
            for (int r = 0; r < 4; ++r) {
                int b = ((mi & 3) * 16) + g * 4 + r;   // row & 63
                float x = acc[mi][ni][r] + decb[(size_t)b * ADIM + n] + bb;
                psum[mi][r] = fmaf(fast_tanh(x), vn, psum[mi][r]);
            }
        }
    }
#pragma unroll
    for (int mi = 0; mi < 8; ++mi)
#pragma unroll
        for (int r = 0; r < 4; ++r) {
            float s = psum[mi][r];
            s += __shfl_xor(s, 1);
            s += __shfl_xor(s, 2);
            s += __shfl_xor(s, 4);
            s += __shfl_xor(s, 8);
            psum[mi][r] = s;
        }

    float* red = reinterpret_cast<float*>(&As[0][0]);   // [256][4] = 4 KB
    if (lc == 0) {
#pragma unroll
        for (int mi = 0; mi < 8; ++mi)
#pragma unroll
            for (int r = 0; r < 4; ++r) {
                int row = wm * 128 + mi * 16 + g * 4 + r;
                red[row * 4 + wn] = psum[mi][r];
            }
    }
    __syncthreads();
    if (tid < 256)
        atomicAdd(&scores[m0 + tid],
                  red[tid * 4] + red[tid * 4 + 1] + red[tid * 4 + 2] + red[tid * 4 + 3]);
}

// ---------------------------------------------------------------------------
// FALLBACK (ws too small): reg-staged fp32-A 128x128 version.
// ---------------------------------------------------------------------------
__global__ __launch_bounds__(256)
void enc_score_fallback(const float* __restrict__ A,
                        const _Float16* __restrict__ Bw,
                        const float* __restrict__ decb,
                        const float* __restrict__ be,
                        const float* __restrict__ bd,
                        const float* __restrict__ v,
                        float* __restrict__ scores)
{
    const int bid = blockIdx.x;
    const int nb  = (bid >> 3) & 7;
    const int mb  = (bid & 7) + ((bid >> 6) << 3);
    const int m0 = mb * 128, n0 = nb * 128;
    const int tid  = threadIdx.x;
    const int lane = tid & 63;
    const int wid  = tid >> 6;
    const int wm   = wid >> 1, wn = wid & 1;
    const int lc   = lane & 15, g = lane >> 4;

    __shared__ __align__(16) _Float16 As[128 * 64];
    __shared__ __align__(16) _Float16 Bs[128 * 64];

    const int srow = tid >> 1;
    const int scol = (tid & 1) * 32;
    const int sw   = (srow & 7) << 3;

    f32x4 acc[4][4];
#pragma unroll
    for (int i = 0; i < 4; ++i)
#pragma unroll
        for (int j = 0; j < 4; ++j) acc[i][j] = (f32x4){0.f, 0.f, 0.f, 0.f};

    const float*    Aptr = A  + (size_t)(m0 + srow) * KDIM + scol;
    const _Float16* Bptr = Bw + (size_t)(n0 + srow) * KDIM + scol;

    float4 aR[8];
    uint4  bR[4];
#pragma unroll
    for (int i = 0; i < 8; ++i) aR[i] = reinterpret_cast<const float4*>(Aptr)[i];
#pragma unroll
    for (int i = 0; i < 4; ++i) bR[i] = reinterpret_cast<const uint4*>(Bptr)[i];

    for (int kb = 0; kb < KDIM; kb += 64) {
        __syncthreads();
#pragma unroll
        for (int w = 0; w < 4; ++w) {
            int hw = (srow * 64 + scol + 8 * w) ^ sw;
            *reinterpret_cast<f16x8*>(&As[hw]) = cvt8(aR[2 * w], aR[2 * w + 1]);
            *reinterpret_cast<uint4*>(&Bs[hw]) = bR[w];
        }
        __syncthreads();
        if (kb + 64 < KDIM) {
#pragma unroll
            for (int i = 0; i < 8; ++i)
                aR[i] = reinterpret_cast<const float4*>(Aptr + kb + 64)[i];
#pragma unroll
            for (int i = 0; i < 4; ++i)
                bR[i] = reinterpret_cast<const uint4*>(Bptr + kb + 64)[i];
        }
#pragma unroll
        for (int ks = 0; ks < 2; ++ks) {
            f16x8 af[4], bf[4];
#pragma unroll
            for (int mi = 0; mi < 4; ++mi) {
                int r  = wm * 64 + mi * 16 + lc;
                int hw = (r * 64 + ks * 32 + g * 8) ^ ((r & 7) << 3);
                af[mi] = *reinterpret_cast<const f16x8*>(&As[hw]);
            }
#pragma unroll
            for (int ni = 0; ni < 4; ++ni) {
                int r  = wn * 64 + ni * 16 + lc;
                int hw = (r * 64 + ks * 32 + g * 8) ^ ((r & 7) << 3);
                bf[ni] = *reinterpret_cast<const f16x8*>(&Bs[hw]);
            }
#pragma unroll
            for (int mi = 0; mi < 4; ++mi)
#pragma unroll
                for (int ni = 0; ni < 4; ++ni)
                    acc[mi][ni] = __builtin_amdgcn_mfma_f32_16x16x32_f16(
                        af[mi], bf[ni], acc[mi][ni], 0, 0, 0);
        }
    }

    __syncthreads();

    float psum[4][4];
#pragma unroll
    for (int mi = 0; mi < 4; ++mi)
#pragma unroll
        for (int r = 0; r < 4; ++r) psum[mi][r] = 0.f;

#pragma unroll
    for (int mi = 0; mi < 4; ++mi) {
#pragma unroll
        for (int ni = 0; ni < 4; ++ni) {
            int n = n0 + wn * 64 + ni * 16 + lc;
            float vn = v[n];
            float bb = be[n] + bd[n];
#pragma unroll
            for (int r = 0; r < 4; ++r) {
                int b = mi * 16 + g * 4 + r;
                float x = acc[mi][ni][r] + decb[(size_t)b * ADIM + n] + bb;
                psum[mi][r] = fmaf(fast_tanh(x), vn, psum[mi][r]);
            }
        }
    }
#pragma unroll
    for (int mi = 0; mi < 4; ++mi)
#pragma unroll
        for (int r = 0; r < 4; ++r) {
            float s = psum[mi][r];
            s += __shfl_xor(s, 1);
            s += __shfl_xor(s, 2);
            s += __shfl_xor(s, 4);
            s += __shfl_xor(s, 8);
            psum[mi][r] = s;
        }

    float* red = reinterpret_cast<float*>(As);
    if (lc == 0) {
#pragma unroll
        for (int mi = 0; mi < 4; ++mi)
#pragma unroll
            for (int r = 0; r < 4; ++r) {
                int row = wm * 64 + mi * 16 + g * 4 + r;
                red[row * 2 + wn] = psum[mi][r];
            }
    }
    __syncthreads();
    if (tid < 128)
        atomicAdd(&scores[m0 + tid], red[tid * 2] + red[tid * 2 + 1]);
}

// ---------------------------------------------------------------------------
// Masked softmax over S per batch column, in place. One block per b.
// ---------------------------------------------------------------------------
__global__ __launch_bounds__(256)
void softmax_kernel(const int* __restrict__ lens, float* __restrict__ attn)
{
    const int b   = blockIdx.x;
    const int tid = threadIdx.x;
    const int len = lens[b];

    float sc[4];
#pragma unroll
    for (int k = 0; k < 4; ++k) {
        int s = k * 256 + tid;
        float x = attn[(size_t)s * BSZ + b];
        sc[k] = (s < len) ? x : NEG_MASK;
    }

    __shared__ float red[8];

    float m = fmaxf(fmaxf(sc[0], sc[1]), fmaxf(sc[2], sc[3]));
#pragma unroll
    for (int off = 32; off > 0; off >>= 1) m = fmaxf(m, __shfl_xor(m, off));
    if ((tid & 63) == 0) red[tid >> 6] = m;
    __syncthreads();
    m = fmaxf(fmaxf(red[0], red[1]), fmaxf(red[2], red[3]));

    float e[4];
    float sum = 0.f;
#pragma unroll
    for (int k = 0; k < 4; ++k) { e[k] = expf(sc[k] - m); sum += e[k]; }
#pragma unroll
    for (int off = 32; off > 0; off >>= 1) sum += __shfl_xor(sum, off);
    __syncthreads();
    if ((tid & 63) == 0) red[4 + (tid >> 6)] = sum;
    __syncthreads();
    float total = red[4] + red[5] + red[6] + red[7];
    float inv = 1.f / total;

#pragma unroll
    for (int k = 0; k < 4; ++k) {
        int s = k * 256 + tid;
        attn[(size_t)s * BSZ + b] = e[k] * inv;
    }
}

// ---------------------------------------------------------------------------
// ctx[b][c] = sum_s attn[s][b] * hids[s][b][c]   (fp32 source, coalesced)
// ---------------------------------------------------------------------------
__global__ __launch_bounds__(256)
void ctx_kernel(const float* __restrict__ hids, const float* __restrict__ attn,
                float* __restrict__ ctx)
{
    const int b   = blockIdx.x;
    const int s0  = blockIdx.y * (SRC_LEN / 8);
    const int tid = threadIdx.x;

    float4 acc = make_float4(0.f, 0.f, 0.f, 0.f);
    for (int s = s0; s < s0 + SRC_LEN / 8; ++s) {
        float w = attn[(size_t)s * BSZ + b];
        if (w != 0.f) {
            float4 h = *reinterpret_cast<const float4*>(
                &hids[((size_t)s * BSZ + b) * CDIM + tid * 4]);
            acc.x = fmaf(w, h.x, acc.x);
            acc.y = fmaf(w, h.y, acc.y);
            acc.z = fmaf(w, h.z, acc.z);
            acc.w = fmaf(w, h.w, acc.w);
        }
    }
    float* dst = &ctx[(size_t)b * CDIM + tid * 4];
    atomicAdd(dst + 0, acc.x);
    atomicAdd(dst + 1, acc.y);
    atomicAdd(dst + 2, acc.z);
    atomicAdd(dst + 3, acc.w);
}

// ---------------------------------------------------------------------------
extern "C" void kernel_launch(void* const* d_in, const int* in_sizes, int n_in,
                              void* d_out, int out_size, void* d_ws, size_t ws_size,
                              hipStream_t stream)
{
    const float* dsr   = (const float*)d_in[0];
    const float* hids  = (const float*)d_in[1];
    const int*   lens  = (const int*)  d_in[2];
    const float* W_enc = (const float*)d_in[3];
    const float* b_enc = (const float*)d_in[4];
    const float* W_dec = (const float*)d_in[5];
    const float* b_dec = (const float*)d_in[6];
    const float* v     = (const float*)d_in[7];

    float* out  = (float*)d_out;
    float* ctx  = out;                       // [64*1024]
    float* attn = out + BSZ * CDIM;          // [1024*64] scores -> probs

    const size_t decb_b = (size_t)BSZ * ADIM * 4;     // 256 KB
    const size_t wf16_b = (size_t)ADIM * KDIM * 2;    // 2 MB
    const size_t af16_b = (size_t)MROWS * KDIM * 2;   // 128 MB

    float*    decb = (float*)d_ws;
    _Float16* Wt   = (_Float16*)((char*)d_ws + decb_b);
    _Float16* At   = (_Float16*)((char*)d_ws + decb_b + wf16_b);

    const bool fast = ws_size >= decb_b + wf16_b + af16_b;

    hipMemsetAsync(d_out, 0, (size_t)(BSZ * CDIM + SRC_LEN * BSZ) * sizeof(float), stream);
    hipMemsetAsync(d_ws, 0, decb_b, stream);   // decb is an atomic target

    dec_kernel<<<dim3(16, 4), 256, 0, stream>>>(dsr, W_dec, decb);

    if (fast) {
        convert_tiled32_kernel<<<(ADIM / 256) * 32 * 4, 256, 0, stream>>>(W_enc, Wt);
        convert_tiled32_kernel<<<(MROWS / 256) * 32 * 4, 256, 0, stream>>>(hids, At);
        enc_score_256<<<1024, 512, 0, stream>>>(At, Wt, decb, b_enc, b_dec, v, attn);
    } else {
        convert8_kernel<<<ADIM * KDIM / 8 / 256, 256, 0, stream>>>(W_enc, Wt);
        enc_score_fallback<<<4096, 256, 0, stream>>>(hids, Wt, decb, b_enc, b_dec, v, attn);
    }
    softmax_kernel<<<BSZ, 256, 0, stream>>>(lens, attn);
    ctx_kernel<<<dim3(BSZ, 8), 256, 0, stream>>>(hids, attn, ctx);
}

// Round 15
// 394.841 us; speedup vs baseline: 3.1922x; 1.0058x over previous
//
#include <hip/hip_runtime.h>
#include <math.h>

#define SRC_LEN  1024
#define BSZ      64
#define CDIM     1024
#define ADIM     1024
#define KDIM     1024
#define MROWS    (SRC_LEN * BSZ)
#define NEG_MASK -1000000.0f

// tiled fp16 layout (256-row tiles): tile = 256 rows x 64 cols,
//   fr = row>>4 (0..15), lr = row&15, cb = col>>3 (0..7), e = col&7
//   hw = fr*1024 + cb*128 + lr*8 + e       (tile = 16384 hw = 32 KB)
// Fragment read (ks=cb>>2, g=cb&3): hw = fr*1024 + ks*512 + g*128 + lr*8.
// => ds_read_b128 (64 lanes) covers 1KB contiguous -> conflict-free,
//    global->LDS staging is a plain contiguous copy.
#define THW256 16384

typedef _Float16 f16x8 __attribute__((ext_vector_type(8)));
typedef float    f32x4 __attribute__((ext_vector_type(4)));

__device__ __forceinline__ float fast_tanh(float x) {
    float e = __expf(2.0f * x);
    return 1.0f - 2.0f / (e + 1.0f);
}

// async global(16B) -> LDS, per-lane global src, wave-uniform LDS base
__device__ __forceinline__ void gload16(const _Float16* g, _Float16* l) {
    __builtin_amdgcn_global_load_lds(
        (const __attribute__((address_space(1))) unsigned int*)g,
        (__attribute__((address_space(3))) unsigned int*)l, 16, 0, 0);
}

__device__ __forceinline__ f16x8 frag(const _Float16* buf, int fr, int ks,
                                      int g, int lc) {
    return *reinterpret_cast<const f16x8*>(
        &buf[fr * 1024 + ks * 512 + g * 128 + lc * 8]);
}

__device__ __forceinline__ f16x8 cvt8(float4 x, float4 y) {
    f16x8 o;
    o[0] = (_Float16)x.x; o[1] = (_Float16)x.y;
    o[2] = (_Float16)x.z; o[3] = (_Float16)x.w;
    o[4] = (_Float16)y.x; o[5] = (_Float16)y.y;
    o[6] = (_Float16)y.z; o[7] = (_Float16)y.w;
    return o;
}

// ---------------------------------------------------------------------------
// Merged convert: fp32 [rows][1024] -> fp16 tiled, 256-row tiles.
// Blocks [0, nW) convert W_enc; blocks [nW, nW+nA) convert hids.
// Each block covers 256 threads x 8 elems = 2048 hw = 1/8 tile.
// ---------------------------------------------------------------------------
__global__ __launch_bounds__(256)
void convert_merged_kernel(const float* __restrict__ w_in, _Float16* __restrict__ w_out,
                           const float* __restrict__ a_in, _Float16* __restrict__ a_out,
                           int nW)
{
    int bid = blockIdx.x;
    const float* in;
    _Float16* out;
    if (bid < nW) { in = w_in; out = w_out; }
    else          { in = a_in; out = a_out; bid -= nW; }

    const int part = bid & 7;
    const int tile = bid >> 3;           // rt*16 + kt
    const int kt   = tile & 15;
    const int rt   = tile >> 4;
    const int t    = threadIdx.x;
    const int u    = part * 256 + t;     // 8-elem group 0..2047
    const int fr = u >> 7;
    const int cb = (u >> 4) & 7;
    const int lr = u & 15;

    const size_t row = (size_t)rt * 256 + fr * 16 + lr;
    const int    col = kt * 64 + cb * 8;

    float4 x = *reinterpret_cast<const float4*>(&in[row * KDIM + col]);
    float4 y = *reinterpret_cast<const float4*>(&in[row * KDIM + col + 4]);
    *reinterpret_cast<f16x8*>(&out[(size_t)tile * THW256 + (size_t)u * 8]) = cvt8(x, y);
}

// ---------------------------------------------------------------------------
// fp32 -> fp16 linear (fallback path W conversion)
// ---------------------------------------------------------------------------
__global__ __launch_bounds__(256)
void convert8_kernel(const float* __restrict__ in, _Float16* __restrict__ out)
{
    size_t i = ((size_t)blockIdx.x * 256 + threadIdx.x) * 8;
    float4 x = *reinterpret_cast<const float4*>(in + i);
    float4 y = *reinterpret_cast<const float4*>(in + i + 4);
    *reinterpret_cast<f16x8*>(out + i) = cvt8(x, y);
}

// ---------------------------------------------------------------------------
// decb[b][n] += decoder_state @ W_dec^T  (k-split, atomic; no bias)
// ---------------------------------------------------------------------------
__global__ __launch_bounds__(256)
void dec_kernel(const float* __restrict__ A, const float* __restrict__ W,
                float* __restrict__ out)
{
    const int n0  = blockIdx.x * 64;
    const int k0  = blockIdx.y * 256;
    const int tid = threadIdx.x;
    const int tx  = tid & 15;
    const int ty  = tid >> 4;

    __shared__ float Asl[16][64];
    __shared__ float Bsl[16][64];

    float acc[4][4];
#pragma unroll
    for (int i = 0; i < 4; ++i)
#pragma unroll
        for (int j = 0; j < 4; ++j) acc[i][j] = 0.f;

    const int lr = tid >> 2;
    const int lk = (tid & 3) * 4;

    for (int kb = k0; kb < k0 + 256; kb += 16) {
        float4 a4 = *reinterpret_cast<const float4*>(&A[(size_t)lr * KDIM + kb + lk]);
        float4 b4 = *reinterpret_cast<const float4*>(&W[(size_t)(n0 + lr) * KDIM + kb + lk]);
        __syncthreads();
        Asl[lk + 0][lr] = a4.x; Asl[lk + 1][lr] = a4.y;
        Asl[lk + 2][lr] = a4.z; Asl[lk + 3][lr] = a4.w;
        Bsl[lk + 0][lr] = b4.x; Bsl[lk + 1][lr] = b4.y;
        Bsl[lk + 2][lr] = b4.z; Bsl[lk + 3][lr] = b4.w;
        __syncthreads();
#pragma unroll
        for (int k = 0; k < 16; ++k) {
            float4 av = *reinterpret_cast<const float4*>(&Asl[k][ty * 4]);
            float4 bv = *reinterpret_cast<const float4*>(&Bsl[k][tx * 4]);
            float am[4] = {av.x, av.y, av.z, av.w};
            float bn[4] = {bv.x, bv.y, bv.z, bv.w};
#pragma unroll
            for (int i = 0; i < 4; ++i)
#pragma unroll
                for (int j = 0; j < 4; ++j)
                    acc[i][j] = fmaf(am[i], bn[j], acc[i][j]);
        }
    }
#pragma unroll
    for (int i = 0; i < 4; ++i) {
        int m = ty * 4 + i;
#pragma unroll
        for (int j = 0; j < 4; ++j) {
            int n = n0 + tx * 4 + j;
            atomicAdd(&out[(size_t)m * ADIM + n], acc[i][j]);
        }
    }
}

// ---------------------------------------------------------------------------
// FAST PATH: 256x256 tile, BK=64, 8 waves, R8's verified 4-phase schedule,
// PERSISTENT over 4 consecutive mb's: one continuous 64-tile K-loop per
// block (fill/drain transients amortized 4x). A-tiles for the 4 mb's are
// contiguous; B re-stages its 16 tiles 4x (L2-resident). At each 16-tile
// boundary: tanh+v epilogue flush (dedicated red LDS; As/Bs stay live),
// acc re-zero; next tile's stage already in flight hides the boundary.
// ---------------------------------------------------------------------------
__global__ __launch_bounds__(512, 1)
void enc_score_256(const _Float16* __restrict__ At,   // [256*16] tiles
                   const _Float16* __restrict__ Bt,   // [4*16] tiles
                   const float* __restrict__ decb,    // [64][1024] (no bias)
                   const float* __restrict__ be,      // b_enc
                   const float* __restrict__ bd,      // b_dec
                   const float* __restrict__ v,       // [1024]
                   float* __restrict__ scores)        // [65536]
{
    // grid 256: 64 groups x 4 nbt, XCD-grouped (4 nbt-sharers on one XCD).
    const int bid = blockIdx.x;
    const int nbt = (bid >> 3) & 3;
    const int grp = (bid & 7) + ((bid >> 5) << 3);   // 0..63
    const int mb0 = grp * 4;
    const int n0  = nbt * 256;
    const int tid  = threadIdx.x;
    const int lane = tid & 63;
    const int wid  = tid >> 6;          // 0..7
    const int wm   = wid >> 2;          // 0..1
    const int wn   = wid & 3;           // 0..3
    const int lc   = lane & 15, g = lane >> 4;

    __shared__ __align__(16) _Float16 As[2][THW256];   // 64 KB
    __shared__ __align__(16) _Float16 Bs[2][THW256];   // 64 KB
    __shared__ float red2[256 * 4];                    // 4 KB epilogue scratch

    f32x4 acc[8][4];
#pragma unroll
    for (int i = 0; i < 8; ++i)
#pragma unroll
        for (int j = 0; j < 4; ++j) acc[i][j] = (f32x4){0.f, 0.f, 0.f, 0.f};

    const _Float16* Abase = At + (size_t)(mb0 * 16) * THW256;   // 64 tiles linear
    const _Float16* Bbase = Bt + (size_t)(nbt * 16) * THW256;   // 16 tiles

    // ---- prologue: stage tile 0 into buffer 0 (8 gloads/wave) ----
#pragma unroll
    for (int i = 0; i < 4; ++i) {
        int c = wid * 4 + i;                  // chunk 0..31, 1KB each
        gload16(Abase + c * 512 + lane * 8, &As[0][c * 512]);
        gload16(Bbase + c * 512 + lane * 8, &Bs[0][c * 512]);
    }
    asm volatile("s_waitcnt vmcnt(0)" ::: "memory");
    __builtin_amdgcn_s_barrier();
    asm volatile("" ::: "memory");

    for (int t = 0; t < 64; ++t) {
        const int cur = t & 1;
        const _Float16* Acur = As[cur];
        const _Float16* Bcur = Bs[cur];
        _Float16* Anxt = As[cur ^ 1];
        _Float16* Bnxt = Bs[cur ^ 1];
        const _Float16* Ag = Abase + (size_t)(t + 1) * THW256;
        const _Float16* Bg = Bbase + (size_t)((t + 1) & 15) * THW256;
        const bool pre = (t < 63);

        f16x8 af[4], bf[4];

        // ===== phase 0: ks=0, mi 0..3  (+ stage A of t+1) =====
#pragma unroll
        for (int ni = 0; ni < 4; ++ni) bf[ni] = frag(Bcur, wn * 4 + ni, 0, g, lc);
#pragma unroll
        for (int i = 0; i < 4; ++i)    af[i]  = frag(Acur, wm * 8 + i, 0, g, lc);
        if (pre) {
#pragma unroll
            for (int i = 0; i < 4; ++i) {
                int c = wid * 4 + i;
                gload16(Ag + c * 512 + lane * 8, Anxt + c * 512);
            }
        }
        __builtin_amdgcn_s_barrier();
        asm volatile("s_waitcnt lgkmcnt(0)" ::: "memory");
        __builtin_amdgcn_sched_barrier(0);
        __builtin_amdgcn_s_setprio(1);
#pragma unroll
        for (int i = 0; i < 4; ++i)
#pragma unroll
            for (int ni = 0; ni < 4; ++ni)
                acc[i][ni] = __builtin_amdgcn_mfma_f32_16x16x32_f16(
                    af[i], bf[ni], acc[i][ni], 0, 0, 0);
        __builtin_amdgcn_s_setprio(0);
        __builtin_amdgcn_s_barrier();

        // ===== phase 1: ks=0, mi 4..7  (+ stage B of t+1) =====
#pragma unroll
        for (int i = 0; i < 4; ++i) af[i] = frag(Acur, wm * 8 + 4 + i, 0, g, lc);
        if (pre) {
#pragma unroll
            for (int i = 0; i < 4; ++i) {
                int c = wid * 4 + i;
                gload16(Bg + c * 512 + lane * 8, Bnxt + c * 512);
            }
        }
        __builtin_amdgcn_s_barrier();
        asm volatile("s_waitcnt lgkmcnt(0)" ::: "memory");
        __builtin_amdgcn_sched_barrier(0);
        __builtin_amdgcn_s_setprio(1);
#pragma unroll
        for (int i = 0; i < 4; ++i)
#pragma unroll
            for (int ni = 0; ni < 4; ++ni)
                acc[4 + i][ni] = __builtin_amdgcn_mfma_f32_16x16x32_f16(
                    af[i], bf[ni], acc[4 + i][ni], 0, 0, 0);
        __builtin_amdgcn_s_setprio(0);
        __builtin_amdgcn_s_barrier();

        // ===== phase 2: ks=1, mi 0..3 =====
#pragma unroll
        for (int ni = 0; ni < 4; ++ni) bf[ni] = frag(Bcur, wn * 4 + ni, 1, g, lc);
#pragma unroll
        for (int i = 0; i < 4; ++i)    af[i]  = frag(Acur, wm * 8 + i, 1, g, lc);
        __builtin_amdgcn_s_barrier();
        asm volatile("s_waitcnt lgkmcnt(0)" ::: "memory");
        __builtin_amdgcn_sched_barrier(0);
        __builtin_amdgcn_s_setprio(1);
#pragma unroll
        for (int i = 0; i < 4; ++i)
#pragma unroll
            for (int ni = 0; ni < 4; ++ni)
                acc[i][ni] = __builtin_amdgcn_mfma_f32_16x16x32_f16(
                    af[i], bf[ni], acc[i][ni], 0, 0, 0);
        __builtin_amdgcn_s_setprio(0);
        __builtin_amdgcn_s_barrier();

        // ===== phase 3: ks=1, mi 4..7  (+ drain next-tile stages) =====
#pragma unroll
        for (int i = 0; i < 4; ++i) af[i] = frag(Acur, wm * 8 + 4 + i, 1, g, lc);
        __builtin_amdgcn_s_barrier();
        asm volatile("s_waitcnt lgkmcnt(0)" ::: "memory");
        __builtin_amdgcn_sched_barrier(0);
        __builtin_amdgcn_s_setprio(1);
#pragma unroll
        for (int i = 0; i < 4; ++i)
#pragma unroll
            for (int ni = 0; ni < 4; ++ni)
                acc[4 + i][ni] = __builtin_amdgcn_mfma_f32_16x16x32_f16(
                    af[i], bf[ni], acc[4 + i][ni], 0, 0, 0);
        __builtin_amdgcn_s_setprio(0);
        if (pre) asm volatile("s_waitcnt vmcnt(0)" ::: "memory");
        __builtin_amdgcn_s_barrier();
        asm volatile("" ::: "memory");

        // ===== mb boundary: flush accumulator through tanh+v epilogue =====
        if ((t & 15) == 15) {
            const int m0t = (mb0 + (t >> 4)) * 256;

            float psum[8][4];
#pragma unroll
            for (int mi = 0; mi < 8; ++mi)
#pragma unroll
                for (int r = 0; r < 4; ++r) psum[mi][r] = 0.f;

#pragma unroll
            for (int mi = 0; mi < 8; ++mi) {
#pragma unroll
                for (int ni = 0; ni < 4; ++ni) {
                    int n = n0 + wn * 64 + ni * 16 + lc;
                    float vn = v[n];
                    float bb = be[n] + bd[n];
#pragma unroll
                    for (int r = 0; r < 4; ++r) {
                        int b = ((mi & 3) * 16) + g * 4 + r;   // row & 63
                        float x = acc[mi][ni][r] + decb[(size_t)b * ADIM + n] + bb;
                        psum[mi][r] = fmaf(fast_tanh(x), vn, psum[mi][r]);
                    }
                }
            }
#pragma unroll
            for (int mi = 0; mi < 8; ++mi)
#pragma unroll
                for (int r = 0; r < 4; ++r) {
                    float s = psum[mi][r];
                    s += __shfl_xor(s, 1);
                    s += __shfl_xor(s, 2);
                    s += __shfl_xor(s, 4);
                    s += __shfl_xor(s, 8);
                    psum[mi][r] = s;
                }

            if (lc == 0) {
#pragma unroll
                for (int mi = 0; mi < 8; ++mi)
#pragma unroll
                    for (int r = 0; r < 4; ++r) {
                        int row = wm * 128 + mi * 16 + g * 4 + r;
                        red2[row * 4 + wn] = psum[mi][r];
                    }
            }
            __syncthreads();
            if (tid < 256)
                atomicAdd(&scores[m0t + tid],
                          red2[tid * 4] + red2[tid * 4 + 1] +
                          red2[tid * 4 + 2] + red2[tid * 4 + 3]);
            __syncthreads();   // red2 reads done before next flush overwrites

#pragma unroll
            for (int i = 0; i < 8; ++i)
#pragma unroll
                for (int j = 0; j < 4; ++j) acc[i][j] = (f32x4){0.f, 0.f, 0.f, 0.f};
        }
    }
}

// ---------------------------------------------------------------------------
// FALLBACK (ws too small): reg-staged fp32-A 128x128 version.
// ---------------------------------------------------------------------------
__global__ __launch_bounds__(256)
void enc_score_fallback(const float* __restrict__ A,
                        const _Float16* __restrict__ Bw,
                        const float* __restrict__ decb,
                        const float* __restrict__ be,
                        const float* __restrict__ bd,
                        const float* __restrict__ v,
                        float* __restrict__ scores)
{
    const int bid = blockIdx.x;
    const int nb  = (bid >> 3) & 7;
    const int mb  = (bid & 7) + ((bid >> 6) << 3);
    const int m0 = mb * 128, n0 = nb * 128;
    const int tid  = threadIdx.x;
    const int lane = tid & 63;
    const int wid  = tid >> 6;
    const int wm   = wid >> 1, wn = wid & 1;
    const int lc   = lane & 15, g = lane >> 4;

    __shared__ __align__(16) _Float16 As[128 * 64];
    __shared__ __align__(16) _Float16 Bs[128 * 64];

    const int srow = tid >> 1;
    const int scol = (tid & 1) * 32;
    const int sw   = (srow & 7) << 3;

    f32x4 acc[4][4];
#pragma unroll
    for (int i = 0; i < 4; ++i)
#pragma unroll
        for (int j = 0; j < 4; ++j) acc[i][j] = (f32x4){0.f, 0.f, 0.f, 0.f};

    const float*    Aptr = A  + (size_t)(m0 + srow) * KDIM + scol;
    const _Float16* Bptr = Bw + (size_t)(n0 + srow) * KDIM + scol;

    float4 aR[8];
    uint4  bR[4];
#pragma unroll
    for (int i = 0; i < 8; ++i) aR[i] = reinterpret_cast<const float4*>(Aptr)[i];
#pragma unroll
    for (int i = 0; i < 4; ++i) bR[i] = reinterpret_cast<const uint4*>(Bptr)[i];

    for (int kb = 0; kb < KDIM; kb += 64) {
        __syncthreads();
#pragma unroll
        for (int w = 0; w < 4; ++w) {
            int hw = (srow * 64 + scol + 8 * w) ^ sw;
            *reinterpret_cast<f16x8*>(&As[hw]) = cvt8(aR[2 * w], aR[2 * w + 1]);
            *reinterpret_cast<uint4*>(&Bs[hw]) = bR[w];
        }
        __syncthreads();
        if (kb + 64 < KDIM) {
#pragma unroll
            for (int i = 0; i < 8; ++i)
                aR[i] = reinterpret_cast<const float4*>(Aptr + kb + 64)[i];
#pragma unroll
            for (int i = 0; i < 4; ++i)
                bR[i] = reinterpret_cast<const uint4*>(Bptr + kb + 64)[i];
        }
#pragma unroll
        for (int ks = 0; ks < 2; ++ks) {
            f16x8 af[4], bf[4];
#pragma unroll
            for (int mi = 0; mi < 4; ++mi) {
                int r  = wm * 64 + mi * 16 + lc;
                int hw = (r * 64 + ks * 32 + g * 8) ^ ((r & 7) << 3);
                af[mi] = *reinterpret_cast<const f16x8*>(&As[hw]);
            }
#pragma unroll
            for (int ni = 0; ni < 4; ++ni) {
                int r  = wn * 64 + ni * 16 + lc;
                int hw = (r * 64 + ks * 32 + g * 8) ^ ((r & 7) << 3);
                bf[ni] = *reinterpret_cast<const f16x8*>(&Bs[hw]);
            }
#pragma unroll
            for (int mi = 0; mi < 4; ++mi)
#pragma unroll
                for (int ni = 0; ni < 4; ++ni)
                    acc[mi][ni] = __builtin_amdgcn_mfma_f32_16x16x32_f16(
                        af[mi], bf[ni], acc[mi][ni], 0, 0, 0);
        }
    }

    __syncthreads();

    float psum[4][4];
#pragma unroll
    for (int mi = 0; mi < 4; ++mi)
#pragma unroll
        for (int r = 0; r < 4; ++r) psum[mi][r] = 0.f;

#pragma unroll
    for (int mi = 0; mi < 4; ++mi) {
#pragma unroll
        for (int ni = 0; ni < 4; ++ni) {
            int n = n0 + wn * 64 + ni * 16 + lc;
            float vn = v[n];
            float bb = be[n] + bd[n];
#pragma unroll
            for (int r = 0; r < 4; ++r) {
                int b = mi * 16 + g * 4 + r;
                float x = acc[mi][ni][r] + decb[(size_t)b * ADIM + n] + bb;
                psum[mi][r] = fmaf(fast_tanh(x), vn, psum[mi][r]);
            }
        }
    }
#pragma unroll
    for (int mi = 0; mi < 4; ++mi)
#pragma unroll
        for (int r = 0; r < 4; ++r) {
            float s = psum[mi][r];
            s += __shfl_xor(s, 1);
            s += __shfl_xor(s, 2);
            s += __shfl_xor(s, 4);
            s += __shfl_xor(s, 8);
            psum[mi][r] = s;
        }

    float* red = reinterpret_cast<float*>(As);
    if (lc == 0) {
#pragma unroll
        for (int mi = 0; mi < 4; ++mi)
#pragma unroll
            for (int r = 0; r < 4; ++r) {
                int row = wm * 64 + mi * 16 + g * 4 + r;
                red[row * 2 + wn] = psum[mi][r];
            }
    }
    __syncthreads();
    if (tid < 128)
        atomicAdd(&scores[m0 + tid], red[tid * 2] + red[tid * 2 + 1]);
}

// ---------------------------------------------------------------------------
// Masked softmax over S per batch column, in place. One block per b.
// ---------------------------------------------------------------------------
__global__ __launch_bounds__(256)
void softmax_kernel(const int* __restrict__ lens, float* __restrict__ attn)
{
    const int b   = blockIdx.x;
    const int tid = threadIdx.x;
    const int len = lens[b];

    float sc[4];
#pragma unroll
    for (int k = 0; k < 4; ++k) {
        int s = k * 256 + tid;
        float x = attn[(size_t)s * BSZ + b];
        sc[k] = (s < len) ? x : NEG_MASK;
    }

    __shared__ float red[8];

    float m = fmaxf(fmaxf(sc[0], sc[1]), fmaxf(sc[2], sc[3]));
#pragma unroll
    for (int off = 32; off > 0; off >>= 1) m = fmaxf(m, __shfl_xor(m, off));
    if ((tid & 63) == 0) red[tid >> 6] = m;
    __syncthreads();
    m = fmaxf(fmaxf(red[0], red[1]), fmaxf(red[2], red[3]));

    float e[4];
    float sum = 0.f;
#pragma unroll
    for (int k = 0; k < 4; ++k) { e[k] = expf(sc[k] - m); sum += e[k]; }
#pragma unroll
    for (int off = 32; off > 0; off >>= 1) sum += __shfl_xor(sum, off);
    __syncthreads();
    if ((tid & 63) == 0) red[4 + (tid >> 6)] = sum;
    __syncthreads();
    float total = red[4] + red[5] + red[6] + red[7];
    float inv = 1.f / total;

#pragma unroll
    for (int k = 0; k < 4; ++k) {
        int s = k * 256 + tid;
        attn[(size_t)s * BSZ + b] = e[k] * inv;
    }
}

// ---------------------------------------------------------------------------
// ctx[b][c] = sum_s attn[s][b] * hids[s][b][c]   (fp32 source, coalesced)
// ---------------------------------------------------------------------------
__global__ __launch_bounds__(256)
void ctx_kernel(const float* __restrict__ hids, const float* __restrict__ attn,
                float* __restrict__ ctx)
{
    const int b   = blockIdx.x;
    const int s0  = blockIdx.y * (SRC_LEN / 8);
    const int tid = threadIdx.x;

    float4 acc = make_float4(0.f, 0.f, 0.f, 0.f);
    for (int s = s0; s < s0 + SRC_LEN / 8; ++s) {
        float w = attn[(size_t)s * BSZ + b];
        if (w != 0.f) {
            float4 h = *reinterpret_cast<const float4*>(
                &hids[((size_t)s * BSZ + b) * CDIM + tid * 4]);
            acc.x = fmaf(w, h.x, acc.x);
            acc.y = fmaf(w, h.y, acc.y);
            acc.z = fmaf(w, h.z, acc.z);
            acc.w = fmaf(w, h.w, acc.w);
        }
    }
    float* dst = &ctx[(size_t)b * CDIM + tid * 4];
    atomicAdd(dst + 0, acc.x);
    atomicAdd(dst + 1, acc.y);
    atomicAdd(dst + 2, acc.z);
    atomicAdd(dst + 3, acc.w);
}

// ---------------------------------------------------------------------------
extern "C" void kernel_launch(void* const* d_in, const int* in_sizes, int n_in,
                              void* d_out, int out_size, void* d_ws, size_t ws_size,
                              hipStream_t stream)
{
    const float* dsr   = (const float*)d_in[0];
    const float* hids  = (const float*)d_in[1];
    const int*   lens  = (const int*)  d_in[2];
    const float* W_enc = (const float*)d_in[3];
    const float* b_enc = (const float*)d_in[4];
    const float* W_dec = (const float*)d_in[5];
    const float* b_dec = (const float*)d_in[6];
    const float* v     = (const float*)d_in[7];

    float* out  = (float*)d_out;
    float* ctx  = out;                       // [64*1024]
    float* attn = out + BSZ * CDIM;          // [1024*64] scores -> probs

    const size_t decb_b = (size_t)BSZ * ADIM * 4;     // 256 KB
    const size_t wf16_b = (size_t)ADIM * KDIM * 2;    // 2 MB
    const size_t af16_b = (size_t)MROWS * KDIM * 2;   // 128 MB

    float*    decb = (float*)d_ws;
    _Float16* Wt   = (_Float16*)((char*)d_ws + decb_b);
    _Float16* At   = (_Float16*)((char*)d_ws + decb_b + wf16_b);

    const bool fast = ws_size >= decb_b + wf16_b + af16_b;

    hipMemsetAsync(d_out, 0, (size_t)(BSZ * CDIM + SRC_LEN * BSZ) * sizeof(float), stream);
    hipMemsetAsync(d_ws, 0, decb_b, stream);   // decb is an atomic target

    dec_kernel<<<dim3(16, 4), 256, 0, stream>>>(dsr, W_dec, decb);

    if (fast) {
        const int nW = (ADIM / 256) * 16 * 8;            // 512
        const int nA = (MROWS / 256) * 16 * 8;           // 32768
        convert_merged_kernel<<<nW + nA, 256, 0, stream>>>(W_enc, Wt, hids, At, nW);
        enc_score_256<<<256, 512, 0, stream>>>(At, Wt, decb, b_enc, b_dec, v, attn);
    } else {
        convert8_kernel<<<ADIM * KDIM / 8 / 256, 256, 0, stream>>>(W_enc, Wt);
        enc_score_fallback<<<4096, 256, 0, stream>>>(hids, Wt, decb, b_enc, b_dec, v, attn);
    }
    softmax_kernel<<<BSZ, 256, 0, stream>>>(lens, attn);
    ctx_kernel<<<dim3(BSZ, 8), 256, 0, stream>>>(hids, attn, ctx);
}

// Round 16
// 345.466 us; speedup vs baseline: 3.6484x; 1.1429x over previous
//
#include <hip/hip_runtime.h>
#include <math.h>

#define SRC_LEN  1024
#define BSZ      64
#define CDIM     1024
#define ADIM     1024
#define KDIM     1024
#define MROWS    (SRC_LEN * BSZ)
#define NEG_MASK -1000000.0f

// tiled fp16 layout (256-row tiles): tile = 256 rows x 64 cols,
//   fr = row>>4 (0..15), lr = row&15, cb = col>>3 (0..7), e = col&7
//   hw = fr*1024 + cb*128 + lr*8 + e       (tile = 16384 hw = 32 KB)
// Fragment read (ks=cb>>2, g=cb&3): hw = fr*1024 + ks*512 + g*128 + lr*8.
// => ds_read_b128 (64 lanes) covers 1KB contiguous -> conflict-free,
//    global->LDS staging is a plain contiguous copy.
#define THW256 16384

typedef _Float16 f16x8 __attribute__((ext_vector_type(8)));
typedef float    f32x4 __attribute__((ext_vector_type(4)));

__device__ __forceinline__ float fast_tanh(float x) {
    float e = __expf(2.0f * x);
    return 1.0f - 2.0f / (e + 1.0f);
}

// async global(16B) -> LDS, per-lane global src, wave-uniform LDS base
__device__ __forceinline__ void gload16(const _Float16* g, _Float16* l) {
    __builtin_amdgcn_global_load_lds(
        (const __attribute__((address_space(1))) unsigned int*)g,
        (__attribute__((address_space(3))) unsigned int*)l, 16, 0, 0);
}

__device__ __forceinline__ f16x8 frag(const _Float16* buf, int fr, int ks,
                                      int g, int lc) {
    return *reinterpret_cast<const f16x8*>(
        &buf[fr * 1024 + ks * 512 + g * 128 + lc * 8]);
}

__device__ __forceinline__ f16x8 cvt8(float4 x, float4 y) {
    f16x8 o;
    o[0] = (_Float16)x.x; o[1] = (_Float16)x.y;
    o[2] = (_Float16)x.z; o[3] = (_Float16)x.w;
    o[4] = (_Float16)y.x; o[5] = (_Float16)y.y;
    o[6] = (_Float16)y.z; o[7] = (_Float16)y.w;
    return o;
}

// ---------------------------------------------------------------------------
// Merged convert: fp32 [rows][1024] -> fp16 tiled, 256-row tiles.
// Blocks [0, nW) convert W_enc; blocks [nW, nW+nA) convert hids.
// ---------------------------------------------------------------------------
__global__ __launch_bounds__(256)
void convert_merged_kernel(const float* __restrict__ w_in, _Float16* __restrict__ w_out,
                           const float* __restrict__ a_in, _Float16* __restrict__ a_out,
                           int nW)
{
    int bid = blockIdx.x;
    const float* in;
    _Float16* out;
    if (bid < nW) { in = w_in; out = w_out; }
    else          { in = a_in; out = a_out; bid -= nW; }

    const int part = bid & 7;
    const int tile = bid >> 3;           // rt*16 + kt
    const int kt   = tile & 15;
    const int rt   = tile >> 4;
    const int t    = threadIdx.x;
    const int u    = part * 256 + t;     // 8-elem group 0..2047
    const int fr = u >> 7;
    const int cb = (u >> 4) & 7;
    const int lr = u & 15;

    const size_t row = (size_t)rt * 256 + fr * 16 + lr;
    const int    col = kt * 64 + cb * 8;

    float4 x = *reinterpret_cast<const float4*>(&in[row * KDIM + col]);
    float4 y = *reinterpret_cast<const float4*>(&in[row * KDIM + col + 4]);
    *reinterpret_cast<f16x8*>(&out[(size_t)tile * THW256 + (size_t)u * 8]) = cvt8(x, y);
}

// ---------------------------------------------------------------------------
// fp32 -> fp16 linear (fallback path W conversion)
// ---------------------------------------------------------------------------
__global__ __launch_bounds__(256)
void convert8_kernel(const float* __restrict__ in, _Float16* __restrict__ out)
{
    size_t i = ((size_t)blockIdx.x * 256 + threadIdx.x) * 8;
    float4 x = *reinterpret_cast<const float4*>(in + i);
    float4 y = *reinterpret_cast<const float4*>(in + i + 4);
    *reinterpret_cast<f16x8*>(out + i) = cvt8(x, y);
}

// ---------------------------------------------------------------------------
// decb[b][n] += decoder_state @ W_dec^T  (k-split, atomic; no bias)
// ---------------------------------------------------------------------------
__global__ __launch_bounds__(256)
void dec_kernel(const float* __restrict__ A, const float* __restrict__ W,
                float* __restrict__ out)
{
    const int n0  = blockIdx.x * 64;
    const int k0  = blockIdx.y * 256;
    const int tid = threadIdx.x;
    const int tx  = tid & 15;
    const int ty  = tid >> 4;

    __shared__ float Asl[16][64];
    __shared__ float Bsl[16][64];

    float acc[4][4];
#pragma unroll
    for (int i = 0; i < 4; ++i)
#pragma unroll
        for (int j = 0; j < 4; ++j) acc[i][j] = 0.f;

    const int lr = tid >> 2;
    const int lk = (tid & 3) * 4;

    for (int kb = k0; kb < k0 + 256; kb += 16) {
        float4 a4 = *reinterpret_cast<const float4*>(&A[(size_t)lr * KDIM + kb + lk]);
        float4 b4 = *reinterpret_cast<const float4*>(&W[(size_t)(n0 + lr) * KDIM + kb + lk]);
        __syncthreads();
        Asl[lk + 0][lr] = a4.x; Asl[lk + 1][lr] = a4.y;
        Asl[lk + 2][lr] = a4.z; Asl[lk + 3][lr] = a4.w;
        Bsl[lk + 0][lr] = b4.x; Bsl[lk + 1][lr] = b4.y;
        Bsl[lk + 2][lr] = b4.z; Bsl[lk + 3][lr] = b4.w;
        __syncthreads();
#pragma unroll
        for (int k = 0; k < 16; ++k) {
            float4 av = *reinterpret_cast<const float4*>(&Asl[k][ty * 4]);
            float4 bv = *reinterpret_cast<const float4*>(&Bsl[k][tx * 4]);
            float am[4] = {av.x, av.y, av.z, av.w};
            float bn[4] = {bv.x, bv.y, bv.z, bv.w};
#pragma unroll
            for (int i = 0; i < 4; ++i)
#pragma unroll
                for (int j = 0; j < 4; ++j)
                    acc[i][j] = fmaf(am[i], bn[j], acc[i][j]);
        }
    }
#pragma unroll
    for (int i = 0; i < 4; ++i) {
        int m = ty * 4 + i;
#pragma unroll
        for (int j = 0; j < 4; ++j) {
            int n = n0 + tx * 4 + j;
            atomicAdd(&out[(size_t)m * ADIM + n], acc[i][j]);
        }
    }
}

// ---------------------------------------------------------------------------
// FAST PATH: 256x256 tile, BK=64, 8 waves (R8 schedule, 3 phases/K-tile):
// ph0: {read ks=0 frags (bf4+af4) || stage A(kt+1)} -> bar -> lgkm0 -> 16 MFMA -> bar
// ph1: {read af 4..7 ks=0         || stage B(kt+1)} -> bar -> lgkm0 -> 16 MFMA -> bar
// ph2: {read ks=1 frags (bf4+af8)}                  -> bar -> lgkm0 -> 32 MFMA
//      -> vmcnt(0) -> bar       (phases 2+3 merged: no stage work, one
//      barrier-pair saved; buffering & drain discipline unchanged from R8)
// ---------------------------------------------------------------------------
__global__ __launch_bounds__(512, 1)
void enc_score_256(const _Float16* __restrict__ At,   // [256*16] tiles
                   const _Float16* __restrict__ Bt,   // [4*16] tiles
                   const float* __restrict__ decb,    // [64][1024] (no bias)
                   const float* __restrict__ be,      // b_enc
                   const float* __restrict__ bd,      // b_dec
                   const float* __restrict__ v,       // [1024]
                   float* __restrict__ scores)        // [65536]
{
    // nwg=1024, XCD-grouped: the 4 nbt-sharers of one mb on one XCD.
    const int bid = blockIdx.x;
    const int nbt = (bid >> 3) & 3;
    const int mb  = (bid & 7) + ((bid >> 5) << 3);
    const int m0 = mb * 256, n0 = nbt * 256;
    const int tid  = threadIdx.x;
    const int lane = tid & 63;
    const int wid  = tid >> 6;          // 0..7
    const int wm   = wid >> 2;          // 0..1
    const int wn   = wid & 3;           // 0..3
    const int lc   = lane & 15, g = lane >> 4;

    __shared__ __align__(16) _Float16 As[2][THW256];   // 64 KB
    __shared__ __align__(16) _Float16 Bs[2][THW256];   // 64 KB

    f32x4 acc[8][4];
#pragma unroll
    for (int i = 0; i < 8; ++i)
#pragma unroll
        for (int j = 0; j < 4; ++j) acc[i][j] = (f32x4){0.f, 0.f, 0.f, 0.f};

    const _Float16* Abase = At + (size_t)(mb * 16) * THW256;
    const _Float16* Bbase = Bt + (size_t)(nbt * 16) * THW256;

    // ---- prologue: stage K-tile 0 into buffer 0 (8 gloads/wave) ----
#pragma unroll
    for (int i = 0; i < 4; ++i) {
        int c = wid * 4 + i;                  // chunk 0..31, 1KB each
        gload16(Abase + c * 512 + lane * 8, &As[0][c * 512]);
        gload16(Bbase + c * 512 + lane * 8, &Bs[0][c * 512]);
    }
    asm volatile("s_waitcnt vmcnt(0)" ::: "memory");
    __builtin_amdgcn_s_barrier();
    asm volatile("" ::: "memory");

    for (int kt = 0; kt < 16; ++kt) {
        const int cur = kt & 1;
        const _Float16* Acur = As[cur];
        const _Float16* Bcur = Bs[cur];
        _Float16* Anxt = As[cur ^ 1];
        _Float16* Bnxt = Bs[cur ^ 1];
        const _Float16* Ag = Abase + (size_t)(kt + 1) * THW256;
        const _Float16* Bg = Bbase + (size_t)(kt + 1) * THW256;
        const bool pre = (kt < 15);

        f16x8 af[4], bf[4];

        // ===== phase 0: ks=0, mi 0..3  (+ stage A of kt+1) =====
#pragma unroll
        for (int ni = 0; ni < 4; ++ni) bf[ni] = frag(Bcur, wn * 4 + ni, 0, g, lc);
#pragma unroll
        for (int i = 0; i < 4; ++i)    af[i]  = frag(Acur, wm * 8 + i, 0, g, lc);
        if (pre) {
#pragma unroll
            for (int i = 0; i < 4; ++i) {
                int c = wid * 4 + i;
                gload16(Ag + c * 512 + lane * 8, Anxt + c * 512);
            }
        }
        __builtin_amdgcn_s_barrier();
        asm volatile("s_waitcnt lgkmcnt(0)" ::: "memory");
        __builtin_amdgcn_sched_barrier(0);
        __builtin_amdgcn_s_setprio(1);
#pragma unroll
        for (int i = 0; i < 4; ++i)
#pragma unroll
            for (int ni = 0; ni < 4; ++ni)
                acc[i][ni] = __builtin_amdgcn_mfma_f32_16x16x32_f16(
                    af[i], bf[ni], acc[i][ni], 0, 0, 0);
        __builtin_amdgcn_s_setprio(0);
        __builtin_amdgcn_s_barrier();

        // ===== phase 1: ks=0, mi 4..7  (+ stage B of kt+1) =====
#pragma unroll
        for (int i = 0; i < 4; ++i) af[i] = frag(Acur, wm * 8 + 4 + i, 0, g, lc);
        if (pre) {
#pragma unroll
            for (int i = 0; i < 4; ++i) {
                int c = wid * 4 + i;
                gload16(Bg + c * 512 + lane * 8, Bnxt + c * 512);
            }
        }
        __builtin_amdgcn_s_barrier();
        asm volatile("s_waitcnt lgkmcnt(0)" ::: "memory");
        __builtin_amdgcn_sched_barrier(0);
        __builtin_amdgcn_s_setprio(1);
#pragma unroll
        for (int i = 0; i < 4; ++i)
#pragma unroll
            for (int ni = 0; ni < 4; ++ni)
                acc[4 + i][ni] = __builtin_amdgcn_mfma_f32_16x16x32_f16(
                    af[i], bf[ni], acc[4 + i][ni], 0, 0, 0);
        __builtin_amdgcn_s_setprio(0);
        __builtin_amdgcn_s_barrier();

        // ===== phase 2 (merged 2+3): ks=1, mi 0..7 =====
        f16x8 af8[8];
#pragma unroll
        for (int ni = 0; ni < 4; ++ni) bf[ni] = frag(Bcur, wn * 4 + ni, 1, g, lc);
#pragma unroll
        for (int i = 0; i < 8; ++i)    af8[i] = frag(Acur, wm * 8 + i, 1, g, lc);
        __builtin_amdgcn_s_barrier();
        asm volatile("s_waitcnt lgkmcnt(0)" ::: "memory");
        __builtin_amdgcn_sched_barrier(0);
        __builtin_amdgcn_s_setprio(1);
#pragma unroll
        for (int i = 0; i < 8; ++i)
#pragma unroll
            for (int ni = 0; ni < 4; ++ni)
                acc[i][ni] = __builtin_amdgcn_mfma_f32_16x16x32_f16(
                    af8[i], bf[ni], acc[i][ni], 0, 0, 0);
        __builtin_amdgcn_s_setprio(0);
        if (pre) asm volatile("s_waitcnt vmcnt(0)" ::: "memory");
        __builtin_amdgcn_s_barrier();
        asm volatile("" ::: "memory");
    }

    // ---- fused epilogue: tanh + v-dot + reduce ----
    __syncthreads();

    float psum[8][4];
#pragma unroll
    for (int mi = 0; mi < 8; ++mi)
#pragma unroll
        for (int r = 0; r < 4; ++r) psum[mi][r] = 0.f;

#pragma unroll
    for (int mi = 0; mi < 8; ++mi) {
#pragma unroll
        for (int ni = 0; ni < 4; ++ni) {
            int n = n0 + wn * 64 + ni * 16 + lc;
            float vn = v[n];
            float bb = be[n] + bd[n];
#pragma unroll
            for (int r = 0; r < 4; ++r) {
                int b = ((mi & 3) * 16) + g * 4 + r;   // row & 63
                float x = acc[mi][ni][r] + decb[(size_t)b * ADIM + n] + bb;
                psum[mi][r] = fmaf(fast_tanh(x), vn, psum[mi][r]);
            }
        }
    }
#pragma unroll
    for (int mi = 0; mi < 8; ++mi)
#pragma unroll
        for (int r = 0; r < 4; ++r) {
            float s = psum[mi][r];
            s += __shfl_xor(s, 1);
            s += __shfl_xor(s, 2);
            s += __shfl_xor(s, 4);
            s += __shfl_xor(s, 8);
            psum[mi][r] = s;
        }

    float* red = reinterpret_cast<float*>(&As[0][0]);   // [256][4]
    if (lc == 0) {
#pragma unroll
        for (int mi = 0; mi < 8; ++mi)
#pragma unroll
            for (int r = 0; r < 4; ++r) {
                int row = wm * 128 + mi * 16 + g * 4 + r;
                red[row * 4 + wn] = psum[mi][r];
            }
    }
    __syncthreads();
    if (tid < 256)
        atomicAdd(&scores[m0 + tid],
                  red[tid * 4] + red[tid * 4 + 1] + red[tid * 4 + 2] + red[tid * 4 + 3]);
}

// ---------------------------------------------------------------------------
// FALLBACK (ws too small): reg-staged fp32-A 128x128 version.
// ---------------------------------------------------------------------------
__global__ __launch_bounds__(256)
void enc_score_fallback(const float* __restrict__ A,
                        const _Float16* __restrict__ Bw,
                        const float* __restrict__ decb,
                        const float* __restrict__ be,
                        const float* __restrict__ bd,
                        const float* __restrict__ v,
                        float* __restrict__ scores)
{
    const int bid = blockIdx.x;
    const int nb  = (bid >> 3) & 7;
    const int mb  = (bid & 7) + ((bid >> 6) << 3);
    const int m0 = mb * 128, n0 = nb * 128;
    const int tid  = threadIdx.x;
    const int lane = tid & 63;
    const int wid  = tid >> 6;
    const int wm   = wid >> 1, wn = wid & 1;
    const int lc   = lane & 15, g = lane >> 4;

    __shared__ __align__(16) _Float16 As[128 * 64];
    __shared__ __align__(16) _Float16 Bs[128 * 64];

    const int srow = tid >> 1;
    const int scol = (tid & 1) * 32;
    const int sw   = (srow & 7) << 3;

    f32x4 acc[4][4];
#pragma unroll
    for (int i = 0; i < 4; ++i)
#pragma unroll
        for (int j = 0; j < 4; ++j) acc[i][j] = (f32x4){0.f, 0.f, 0.f, 0.f};

    const float*    Aptr = A  + (size_t)(m0 + srow) * KDIM + scol;
    const _Float16* Bptr = Bw + (size_t)(n0 + srow) * KDIM + scol;

    float4 aR[8];
    uint4  bR[4];
#pragma unroll
    for (int i = 0; i < 8; ++i) aR[i] = reinterpret_cast<const float4*>(Aptr)[i];
#pragma unroll
    for (int i = 0; i < 4; ++i) bR[i] = reinterpret_cast<const uint4*>(Bptr)[i];

    for (int kb = 0; kb < KDIM; kb += 64) {
        __syncthreads();
#pragma unroll
        for (int w = 0; w < 4; ++w) {
            int hw = (srow * 64 + scol + 8 * w) ^ sw;
            *reinterpret_cast<f16x8*>(&As[hw]) = cvt8(aR[2 * w], aR[2 * w + 1]);
            *reinterpret_cast<uint4*>(&Bs[hw]) = bR[w];
        }
        __syncthreads();
        if (kb + 64 < KDIM) {
#pragma unroll
            for (int i = 0; i < 8; ++i)
                aR[i] = reinterpret_cast<const float4*>(Aptr + kb + 64)[i];
#pragma unroll
            for (int i = 0; i < 4; ++i)
                bR[i] = reinterpret_cast<const uint4*>(Bptr + kb + 64)[i];
        }
#pragma unroll
        for (int ks = 0; ks < 2; ++ks) {
            f16x8 af[4], bf[4];
#pragma unroll
            for (int mi = 0; mi < 4; ++mi) {
                int r  = wm * 64 + mi * 16 + lc;
                int hw = (r * 64 + ks * 32 + g * 8) ^ ((r & 7) << 3);
                af[mi] = *reinterpret_cast<const f16x8*>(&As[hw]);
            }
#pragma unroll
            for (int ni = 0; ni < 4; ++ni) {
                int r  = wn * 64 + ni * 16 + lc;
                int hw = (r * 64 + ks * 32 + g * 8) ^ ((r & 7) << 3);
                bf[ni] = *reinterpret_cast<const f16x8*>(&Bs[hw]);
            }
#pragma unroll
            for (int mi = 0; mi < 4; ++mi)
#pragma unroll
                for (int ni = 0; ni < 4; ++ni)
                    acc[mi][ni] = __builtin_amdgcn_mfma_f32_16x16x32_f16(
                        af[mi], bf[ni], acc[mi][ni], 0, 0, 0);
        }
    }

    __syncthreads();

    float psum[4][4];
#pragma unroll
    for (int mi = 0; mi < 4; ++mi)
#pragma unroll
        for (int r = 0; r < 4; ++r) psum[mi][r] = 0.f;

#pragma unroll
    for (int mi = 0; mi < 4; ++mi) {
#pragma unroll
        for (int ni = 0; ni < 4; ++ni) {
            int n = n0 + wn * 64 + ni * 16 + lc;
            float vn = v[n];
            float bb = be[n] + bd[n];
#pragma unroll
            for (int r = 0; r < 4; ++r) {
                int b = mi * 16 + g * 4 + r;
                float x = acc[mi][ni][r] + decb[(size_t)b * ADIM + n] + bb;
                psum[mi][r] = fmaf(fast_tanh(x), vn, psum[mi][r]);
            }
        }
    }
#pragma unroll
    for (int mi = 0; mi < 4; ++mi)
#pragma unroll
        for (int r = 0; r < 4; ++r) {
            float s = psum[mi][r];
            s += __shfl_xor(s, 1);
            s += __shfl_xor(s, 2);
            s += __shfl_xor(s, 4);
            s += __shfl_xor(s, 8);
            psum[mi][r] = s;
        }

    float* red = reinterpret_cast<float*>(As);
    if (lc == 0) {
#pragma unroll
        for (int mi = 0; mi < 4; ++mi)
#pragma unroll
            for (int r = 0; r < 4; ++r) {
                int row = wm * 64 + mi * 16 + g * 4 + r;
                red[row * 2 + wn] = psum[mi][r];
            }
    }
    __syncthreads();
    if (tid < 128)
        atomicAdd(&scores[m0 + tid], red[tid * 2] + red[tid * 2 + 1]);
}

// ---------------------------------------------------------------------------
// Masked softmax over S per batch column, in place. One block per b.
// ---------------------------------------------------------------------------
__global__ __launch_bounds__(256)
void softmax_kernel(const int* __restrict__ lens, float* __restrict__ attn)
{
    const int b   = blockIdx.x;
    const int tid = threadIdx.x;
    const int len = lens[b];

    float sc[4];
#pragma unroll
    for (int k = 0; k < 4; ++k) {
        int s = k * 256 + tid;
        float x = attn[(size_t)s * BSZ + b];
        sc[k] = (s < len) ? x : NEG_MASK;
    }

    __shared__ float red[8];

    float m = fmaxf(fmaxf(sc[0], sc[1]), fmaxf(sc[2], sc[3]));
#pragma unroll
    for (int off = 32; off > 0; off >>= 1) m = fmaxf(m, __shfl_xor(m, off));
    if ((tid & 63) == 0) red[tid >> 6] = m;
    __syncthreads();
    m = fmaxf(fmaxf(red[0], red[1]), fmaxf(red[2], red[3]));

    float e[4];
    float sum = 0.f;
#pragma unroll
    for (int k = 0; k < 4; ++k) { e[k] = expf(sc[k] - m); sum += e[k]; }
#pragma unroll
    for (int off = 32; off > 0; off >>= 1) sum += __shfl_xor(sum, off);
    __syncthreads();
    if ((tid & 63) == 0) red[4 + (tid >> 6)] = sum;
    __syncthreads();
    float total = red[4] + red[5] + red[6] + red[7];
    float inv = 1.f / total;

#pragma unroll
    for (int k = 0; k < 4; ++k) {
        int s = k * 256 + tid;
        attn[(size_t)s * BSZ + b] = e[k] * inv;
    }
}

// ---------------------------------------------------------------------------
// ctx[b][c] = sum_s attn[s][b] * hids[s][b][c]   (fp32 source, coalesced)
// ---------------------------------------------------------------------------
__global__ __launch_bounds__(256)
void ctx_kernel(const float* __restrict__ hids, const float* __restrict__ attn,
                float* __restrict__ ctx)
{
    const int b   = blockIdx.x;
    const int s0  = blockIdx.y * (SRC_LEN / 8);
    const int tid = threadIdx.x;

    float4 acc = make_float4(0.f, 0.f, 0.f, 0.f);
    for (int s = s0; s < s0 + SRC_LEN / 8; ++s) {
        float w = attn[(size_t)s * BSZ + b];
        if (w != 0.f) {
            float4 h = *reinterpret_cast<const float4*>(
                &hids[((size_t)s * BSZ + b) * CDIM + tid * 4]);
            acc.x = fmaf(w, h.x, acc.x);
            acc.y = fmaf(w, h.y, acc.y);
            acc.z = fmaf(w, h.z, acc.z);
            acc.w = fmaf(w, h.w, acc.w);
        }
    }
    float* dst = &ctx[(size_t)b * CDIM + tid * 4];
    atomicAdd(dst + 0, acc.x);
    atomicAdd(dst + 1, acc.y);
    atomicAdd(dst + 2, acc.z);
    atomicAdd(dst + 3, acc.w);
}

// ---------------------------------------------------------------------------
extern "C" void kernel_launch(void* const* d_in, const int* in_sizes, int n_in,
                              void* d_out, int out_size, void* d_ws, size_t ws_size,
                              hipStream_t stream)
{
    const float* dsr   = (const float*)d_in[0];
    const float* hids  = (const float*)d_in[1];
    const int*   lens  = (const int*)  d_in[2];
    const float* W_enc = (const float*)d_in[3];
    const float* b_enc = (const float*)d_in[4];
    const float* W_dec = (const float*)d_in[5];
    const float* b_dec = (const float*)d_in[6];
    const float* v     = (const float*)d_in[7];

    float* out  = (float*)d_out;
    float* ctx  = out;                       // [64*1024]
    float* attn = out + BSZ * CDIM;          // [1024*64] scores -> probs

    const size_t decb_b = (size_t)BSZ * ADIM * 4;     // 256 KB
    const size_t wf16_b = (size_t)ADIM * KDIM * 2;    // 2 MB
    const size_t af16_b = (size_t)MROWS * KDIM * 2;   // 128 MB

    float*    decb = (float*)d_ws;
    _Float16* Wt   = (_Float16*)((char*)d_ws + decb_b);
    _Float16* At   = (_Float16*)((char*)d_ws + decb_b + wf16_b);

    const bool fast = ws_size >= decb_b + wf16_b + af16_b;

    hipMemsetAsync(d_out, 0, (size_t)(BSZ * CDIM + SRC_LEN * BSZ) * sizeof(float), stream);
    hipMemsetAsync(d_ws, 0, decb_b, stream);   // decb is an atomic target

    dec_kernel<<<dim3(16, 4), 256, 0, stream>>>(dsr, W_dec, decb);

    if (fast) {
        const int nW = (ADIM / 256) * 16 * 8;            // 512
        const int nA = (MROWS / 256) * 16 * 8;           // 32768
        convert_merged_kernel<<<nW + nA, 256, 0, stream>>>(W_enc, Wt, hids, At, nW);
        enc_score_256<<<1024, 512, 0, stream>>>(At, Wt, decb, b_enc, b_dec, v, attn);
    } else {
        convert8_kernel<<<ADIM * KDIM / 8 / 256, 256, 0, stream>>>(W_enc, Wt);
        enc_score_fallback<<<4096, 256, 0, stream>>>(hids, Wt, decb, b_enc, b_dec, v, attn);
    }
    softmax_kernel<<<BSZ, 256, 0, stream>>>(lens, attn);
    ctx_kernel<<<dim3(BSZ, 8), 256, 0, stream>>>(hids, attn, ctx);
}

// Round 17
// 328.411 us; speedup vs baseline: 3.8379x; 1.0519x over previous
//
#include <hip/hip_runtime.h>
#include <math.h>

#define SRC_LEN  1024
#define BSZ      64
#define CDIM     1024
#define ADIM     1024
#define KDIM     1024
#define MROWS    (SRC_LEN * BSZ)
#define NEG_MASK -1000000.0f

// tiled fp16 layout (256-row tiles): tile = 256 rows x 64 cols,
//   fr = row>>4 (0..15), lr = row&15, cb = col>>3 (0..7), e = col&7
//   hw = fr*1024 + cb*128 + lr*8 + e       (tile = 16384 hw = 32 KB)
// Fragment read (ks=cb>>2, g=cb&3): hw = fr*1024 + ks*512 + g*128 + lr*8.
// => ds_read_b128 (64 lanes) covers 1KB contiguous -> conflict-free,
//    global->LDS staging is a plain contiguous copy.
#define THW256 16384

typedef _Float16 f16x8 __attribute__((ext_vector_type(8)));
typedef _Float16 f16x4 __attribute__((ext_vector_type(4)));
typedef float    f32x4 __attribute__((ext_vector_type(4)));

__device__ __forceinline__ float fast_tanh(float x) {
    float e = __expf(2.0f * x);
    return 1.0f - 2.0f / (e + 1.0f);
}

// async global(16B) -> LDS, per-lane global src, wave-uniform LDS base
__device__ __forceinline__ void gload16(const _Float16* g, _Float16* l) {
    __builtin_amdgcn_global_load_lds(
        (const __attribute__((address_space(1))) unsigned int*)g,
        (__attribute__((address_space(3))) unsigned int*)l, 16, 0, 0);
}

__device__ __forceinline__ f16x8 frag(const _Float16* buf, int fr, int ks,
                                      int g, int lc) {
    return *reinterpret_cast<const f16x8*>(
        &buf[fr * 1024 + ks * 512 + g * 128 + lc * 8]);
}

__device__ __forceinline__ f16x8 cvt8(float4 x, float4 y) {
    f16x8 o;
    o[0] = (_Float16)x.x; o[1] = (_Float16)x.y;
    o[2] = (_Float16)x.z; o[3] = (_Float16)x.w;
    o[4] = (_Float16)y.x; o[5] = (_Float16)y.y;
    o[6] = (_Float16)y.z; o[7] = (_Float16)y.w;
    return o;
}

// ---------------------------------------------------------------------------
// Merged convert: fp32 [rows][1024] -> fp16 tiled, 256-row tiles.
// Blocks [0, nW) convert W_enc; blocks [nW, nW+nA) convert hids.
// ---------------------------------------------------------------------------
__global__ __launch_bounds__(256)
void convert_merged_kernel(const float* __restrict__ w_in, _Float16* __restrict__ w_out,
                           const float* __restrict__ a_in, _Float16* __restrict__ a_out,
                           int nW)
{
    int bid = blockIdx.x;
    const float* in;
    _Float16* out;
    if (bid < nW) { in = w_in; out = w_out; }
    else          { in = a_in; out = a_out; bid -= nW; }

    const int part = bid & 7;
    const int tile = bid >> 3;           // rt*16 + kt
    const int kt   = tile & 15;
    const int rt   = tile >> 4;
    const int t    = threadIdx.x;
    const int u    = part * 256 + t;     // 8-elem group 0..2047
    const int fr = u >> 7;
    const int cb = (u >> 4) & 7;
    const int lr = u & 15;

    const size_t row = (size_t)rt * 256 + fr * 16 + lr;
    const int    col = kt * 64 + cb * 8;

    float4 x = *reinterpret_cast<const float4*>(&in[row * KDIM + col]);
    float4 y = *reinterpret_cast<const float4*>(&in[row * KDIM + col + 4]);
    *reinterpret_cast<f16x8*>(&out[(size_t)tile * THW256 + (size_t)u * 8]) = cvt8(x, y);
}

// ---------------------------------------------------------------------------
// fp32 -> fp16 linear (fallback path W conversion)
// ---------------------------------------------------------------------------
__global__ __launch_bounds__(256)
void convert8_kernel(const float* __restrict__ in, _Float16* __restrict__ out)
{
    size_t i = ((size_t)blockIdx.x * 256 + threadIdx.x) * 8;
    float4 x = *reinterpret_cast<const float4*>(in + i);
    float4 y = *reinterpret_cast<const float4*>(in + i + 4);
    *reinterpret_cast<f16x8*>(out + i) = cvt8(x, y);
}

// ---------------------------------------------------------------------------
// decb[b][n] += decoder_state @ W_dec^T  (k-split, atomic; no bias)
// ---------------------------------------------------------------------------
__global__ __launch_bounds__(256)
void dec_kernel(const float* __restrict__ A, const float* __restrict__ W,
                float* __restrict__ out)
{
    const int n0  = blockIdx.x * 64;
    const int k0  = blockIdx.y * 256;
    const int tid = threadIdx.x;
    const int tx  = tid & 15;
    const int ty  = tid >> 4;

    __shared__ float Asl[16][64];
    __shared__ float Bsl[16][64];

    float acc[4][4];
#pragma unroll
    for (int i = 0; i < 4; ++i)
#pragma unroll
        for (int j = 0; j < 4; ++j) acc[i][j] = 0.f;

    const int lr = tid >> 2;
    const int lk = (tid & 3) * 4;

    for (int kb = k0; kb < k0 + 256; kb += 16) {
        float4 a4 = *reinterpret_cast<const float4*>(&A[(size_t)lr * KDIM + kb + lk]);
        float4 b4 = *reinterpret_cast<const float4*>(&W[(size_t)(n0 + lr) * KDIM + kb + lk]);
        __syncthreads();
        Asl[lk + 0][lr] = a4.x; Asl[lk + 1][lr] = a4.y;
        Asl[lk + 2][lr] = a4.z; Asl[lk + 3][lr] = a4.w;
        Bsl[lk + 0][lr] = b4.x; Bsl[lk + 1][lr] = b4.y;
        Bsl[lk + 2][lr] = b4.z; Bsl[lk + 3][lr] = b4.w;
        __syncthreads();
#pragma unroll
        for (int k = 0; k < 16; ++k) {
            float4 av = *reinterpret_cast<const float4*>(&Asl[k][ty * 4]);
            float4 bv = *reinterpret_cast<const float4*>(&Bsl[k][tx * 4]);
            float am[4] = {av.x, av.y, av.z, av.w};
            float bn[4] = {bv.x, bv.y, bv.z, bv.w};
#pragma unroll
            for (int i = 0; i < 4; ++i)
#pragma unroll
                for (int j = 0; j < 4; ++j)
                    acc[i][j] = fmaf(am[i], bn[j], acc[i][j]);
        }
    }
#pragma unroll
    for (int i = 0; i < 4; ++i) {
        int m = ty * 4 + i;
#pragma unroll
        for (int j = 0; j < 4; ++j) {
            int n = n0 + tx * 4 + j;
            atomicAdd(&out[(size_t)m * ADIM + n], acc[i][j]);
        }
    }
}

// ---------------------------------------------------------------------------
// FAST PATH: 256x256 tile, BK=64, 8 waves (R16 schedule, 3 phases/K-tile).
// ---------------------------------------------------------------------------
__global__ __launch_bounds__(512, 1)
void enc_score_256(const _Float16* __restrict__ At,   // [256*16] tiles
                   const _Float16* __restrict__ Bt,   // [4*16] tiles
                   const float* __restrict__ decb,    // [64][1024] (no bias)
                   const float* __restrict__ be,      // b_enc
                   const float* __restrict__ bd,      // b_dec
                   const float* __restrict__ v,       // [1024]
                   float* __restrict__ scores)        // [65536]
{
    // nwg=1024, XCD-grouped: the 4 nbt-sharers of one mb on one XCD.
    const int bid = blockIdx.x;
    const int nbt = (bid >> 3) & 3;
    const int mb  = (bid & 7) + ((bid >> 5) << 3);
    const int m0 = mb * 256, n0 = nbt * 256;
    const int tid  = threadIdx.x;
    const int lane = tid & 63;
    const int wid  = tid >> 6;          // 0..7
    const int wm   = wid >> 2;          // 0..1
    const int wn   = wid & 3;           // 0..3
    const int lc   = lane & 15, g = lane >> 4;

    __shared__ __align__(16) _Float16 As[2][THW256];   // 64 KB
    __shared__ __align__(16) _Float16 Bs[2][THW256];   // 64 KB

    f32x4 acc[8][4];
#pragma unroll
    for (int i = 0; i < 8; ++i)
#pragma unroll
        for (int j = 0; j < 4; ++j) acc[i][j] = (f32x4){0.f, 0.f, 0.f, 0.f};

    const _Float16* Abase = At + (size_t)(mb * 16) * THW256;
    const _Float16* Bbase = Bt + (size_t)(nbt * 16) * THW256;

    // ---- prologue: stage K-tile 0 into buffer 0 (8 gloads/wave) ----
#pragma unroll
    for (int i = 0; i < 4; ++i) {
        int c = wid * 4 + i;                  // chunk 0..31, 1KB each
        gload16(Abase + c * 512 + lane * 8, &As[0][c * 512]);
        gload16(Bbase + c * 512 + lane * 8, &Bs[0][c * 512]);
    }
    asm volatile("s_waitcnt vmcnt(0)" ::: "memory");
    __builtin_amdgcn_s_barrier();
    asm volatile("" ::: "memory");

    for (int kt = 0; kt < 16; ++kt) {
        const int cur = kt & 1;
        const _Float16* Acur = As[cur];
        const _Float16* Bcur = Bs[cur];
        _Float16* Anxt = As[cur ^ 1];
        _Float16* Bnxt = Bs[cur ^ 1];
        const _Float16* Ag = Abase + (size_t)(kt + 1) * THW256;
        const _Float16* Bg = Bbase + (size_t)(kt + 1) * THW256;
        const bool pre = (kt < 15);

        f16x8 af[4], bf[4];

        // ===== phase 0: ks=0, mi 0..3  (+ stage A of kt+1) =====
#pragma unroll
        for (int ni = 0; ni < 4; ++ni) bf[ni] = frag(Bcur, wn * 4 + ni, 0, g, lc);
#pragma unroll
        for (int i = 0; i < 4; ++i)    af[i]  = frag(Acur, wm * 8 + i, 0, g, lc);
        if (pre) {
#pragma unroll
            for (int i = 0; i < 4; ++i) {
                int c = wid * 4 + i;
                gload16(Ag + c * 512 + lane * 8, Anxt + c * 512);
            }
        }
        __builtin_amdgcn_s_barrier();
        asm volatile("s_waitcnt lgkmcnt(0)" ::: "memory");
        __builtin_amdgcn_sched_barrier(0);
        __builtin_amdgcn_s_setprio(1);
#pragma unroll
        for (int i = 0; i < 4; ++i)
#pragma unroll
            for (int ni = 0; ni < 4; ++ni)
                acc[i][ni] = __builtin_amdgcn_mfma_f32_16x16x32_f16(
                    af[i], bf[ni], acc[i][ni], 0, 0, 0);
        __builtin_amdgcn_s_setprio(0);
        __builtin_amdgcn_s_barrier();

        // ===== phase 1: ks=0, mi 4..7  (+ stage B of kt+1) =====
#pragma unroll
        for (int i = 0; i < 4; ++i) af[i] = frag(Acur, wm * 8 + 4 + i, 0, g, lc);
        if (pre) {
#pragma unroll
            for (int i = 0; i < 4; ++i) {
                int c = wid * 4 + i;
                gload16(Bg + c * 512 + lane * 8, Bnxt + c * 512);
            }
        }
        __builtin_amdgcn_s_barrier();
        asm volatile("s_waitcnt lgkmcnt(0)" ::: "memory");
        __builtin_amdgcn_sched_barrier(0);
        __builtin_amdgcn_s_setprio(1);
#pragma unroll
        for (int i = 0; i < 4; ++i)
#pragma unroll
            for (int ni = 0; ni < 4; ++ni)
                acc[4 + i][ni] = __builtin_amdgcn_mfma_f32_16x16x32_f16(
                    af[i], bf[ni], acc[4 + i][ni], 0, 0, 0);
        __builtin_amdgcn_s_setprio(0);
        __builtin_amdgcn_s_barrier();

        // ===== phase 2 (merged 2+3): ks=1, mi 0..7 =====
        f16x8 af8[8];
#pragma unroll
        for (int ni = 0; ni < 4; ++ni) bf[ni] = frag(Bcur, wn * 4 + ni, 1, g, lc);
#pragma unroll
        for (int i = 0; i < 8; ++i)    af8[i] = frag(Acur, wm * 8 + i, 1, g, lc);
        __builtin_amdgcn_s_barrier();
        asm volatile("s_waitcnt lgkmcnt(0)" ::: "memory");
        __builtin_amdgcn_sched_barrier(0);
        __builtin_amdgcn_s_setprio(1);
#pragma unroll
        for (int i = 0; i < 8; ++i)
#pragma unroll
            for (int ni = 0; ni < 4; ++ni)
                acc[i][ni] = __builtin_amdgcn_mfma_f32_16x16x32_f16(
                    af8[i], bf[ni], acc[i][ni], 0, 0, 0);
        __builtin_amdgcn_s_setprio(0);
        if (pre) asm volatile("s_waitcnt vmcnt(0)" ::: "memory");
        __builtin_amdgcn_s_barrier();
        asm volatile("" ::: "memory");
    }

    // ---- fused epilogue: tanh + v-dot + reduce ----
    __syncthreads();

    float psum[8][4];
#pragma unroll
    for (int mi = 0; mi < 8; ++mi)
#pragma unroll
        for (int r = 0; r < 4; ++r) psum[mi][r] = 0.f;

#pragma unroll
    for (int mi = 0; mi < 8; ++mi) {
#pragma unroll
        for (int ni = 0; ni < 4; ++ni) {
            int n = n0 + wn * 64 + ni * 16 + lc;
            float vn = v[n];
            float bb = be[n] + bd[n];
#pragma unroll
            for (int r = 0; r < 4; ++r) {
                int b = ((mi & 3) * 16) + g * 4 + r;   // row & 63
                float x = acc[mi][ni][r] + decb[(size_t)b * ADIM + n] + bb;
                psum[mi][r] = fmaf(fast_tanh(x), vn, psum[mi][r]);
            }
        }
    }
#pragma unroll
    for (int mi = 0; mi < 8; ++mi)
#pragma unroll
        for (int r = 0; r < 4; ++r) {
            float s = psum[mi][r];
            s += __shfl_xor(s, 1);
            s += __shfl_xor(s, 2);
            s += __shfl_xor(s, 4);
            s += __shfl_xor(s, 8);
            psum[mi][r] = s;
        }

    float* red = reinterpret_cast<float*>(&As[0][0]);   // [256][4]
    if (lc == 0) {
#pragma unroll
        for (int mi = 0; mi < 8; ++mi)
#pragma unroll
            for (int r = 0; r < 4; ++r) {
                int row = wm * 128 + mi * 16 + g * 4 + r;
                red[row * 4 + wn] = psum[mi][r];
            }
    }
    __syncthreads();
    if (tid < 256)
        atomicAdd(&scores[m0 + tid],
                  red[tid * 4] + red[tid * 4 + 1] + red[tid * 4 + 2] + red[tid * 4 + 3]);
}

// ---------------------------------------------------------------------------
// FALLBACK (ws too small): reg-staged fp32-A 128x128 version.
// ---------------------------------------------------------------------------
__global__ __launch_bounds__(256)
void enc_score_fallback(const float* __restrict__ A,
                        const _Float16* __restrict__ Bw,
                        const float* __restrict__ decb,
                        const float* __restrict__ be,
                        const float* __restrict__ bd,
                        const float* __restrict__ v,
                        float* __restrict__ scores)
{
    const int bid = blockIdx.x;
    const int nb  = (bid >> 3) & 7;
    const int mb  = (bid & 7) + ((bid >> 6) << 3);
    const int m0 = mb * 128, n0 = nb * 128;
    const int tid  = threadIdx.x;
    const int lane = tid & 63;
    const int wid  = tid >> 6;
    const int wm   = wid >> 1, wn = wid & 1;
    const int lc   = lane & 15, g = lane >> 4;

    __shared__ __align__(16) _Float16 As[128 * 64];
    __shared__ __align__(16) _Float16 Bs[128 * 64];

    const int srow = tid >> 1;
    const int scol = (tid & 1) * 32;
    const int sw   = (srow & 7) << 3;

    f32x4 acc[4][4];
#pragma unroll
    for (int i = 0; i < 4; ++i)
#pragma unroll
        for (int j = 0; j < 4; ++j) acc[i][j] = (f32x4){0.f, 0.f, 0.f, 0.f};

    const float*    Aptr = A  + (size_t)(m0 + srow) * KDIM + scol;
    const _Float16* Bptr = Bw + (size_t)(n0 + srow) * KDIM + scol;

    float4 aR[8];
    uint4  bR[4];
#pragma unroll
    for (int i = 0; i < 8; ++i) aR[i] = reinterpret_cast<const float4*>(Aptr)[i];
#pragma unroll
    for (int i = 0; i < 4; ++i) bR[i] = reinterpret_cast<const uint4*>(Bptr)[i];

    for (int kb = 0; kb < KDIM; kb += 64) {
        __syncthreads();
#pragma unroll
        for (int w = 0; w < 4; ++w) {
            int hw = (srow * 64 + scol + 8 * w) ^ sw;
            *reinterpret_cast<f16x8*>(&As[hw]) = cvt8(aR[2 * w], aR[2 * w + 1]);
            *reinterpret_cast<uint4*>(&Bs[hw]) = bR[w];
        }
        __syncthreads();
        if (kb + 64 < KDIM) {
#pragma unroll
            for (int i = 0; i < 8; ++i)
                aR[i] = reinterpret_cast<const float4*>(Aptr + kb + 64)[i];
#pragma unroll
            for (int i = 0; i < 4; ++i)
                bR[i] = reinterpret_cast<const uint4*>(Bptr + kb + 64)[i];
        }
#pragma unroll
        for (int ks = 0; ks < 2; ++ks) {
            f16x8 af[4], bf[4];
#pragma unroll
            for (int mi = 0; mi < 4; ++mi) {
                int r  = wm * 64 + mi * 16 + lc;
                int hw = (r * 64 + ks * 32 + g * 8) ^ ((r & 7) << 3);
                af[mi] = *reinterpret_cast<const f16x8*>(&As[hw]);
            }
#pragma unroll
            for (int ni = 0; ni < 4; ++ni) {
                int r  = wn * 64 + ni * 16 + lc;
                int hw = (r * 64 + ks * 32 + g * 8) ^ ((r & 7) << 3);
                bf[ni] = *reinterpret_cast<const f16x8*>(&Bs[hw]);
            }
#pragma unroll
            for (int mi = 0; mi < 4; ++mi)
#pragma unroll
                for (int ni = 0; ni < 4; ++ni)
                    acc[mi][ni] = __builtin_amdgcn_mfma_f32_16x16x32_f16(
                        af[mi], bf[ni], acc[mi][ni], 0, 0, 0);
        }
    }

    __syncthreads();

    float psum[4][4];
#pragma unroll
    for (int mi = 0; mi < 4; ++mi)
#pragma unroll
        for (int r = 0; r < 4; ++r) psum[mi][r] = 0.f;

#pragma unroll
    for (int mi = 0; mi < 4; ++mi) {
#pragma unroll
        for (int ni = 0; ni < 4; ++ni) {
            int n = n0 + wn * 64 + ni * 16 + lc;
            float vn = v[n];
            float bb = be[n] + bd[n];
#pragma unroll
            for (int r = 0; r < 4; ++r) {
                int b = mi * 16 + g * 4 + r;
                float x = acc[mi][ni][r] + decb[(size_t)b * ADIM + n] + bb;
                psum[mi][r] = fmaf(fast_tanh(x), vn, psum[mi][r]);
            }
        }
    }
#pragma unroll
    for (int mi = 0; mi < 4; ++mi)
#pragma unroll
        for (int r = 0; r < 4; ++r) {
            float s = psum[mi][r];
            s += __shfl_xor(s, 1);
            s += __shfl_xor(s, 2);
            s += __shfl_xor(s, 4);
            s += __shfl_xor(s, 8);
            psum[mi][r] = s;
        }

    float* red = reinterpret_cast<float*>(As);
    if (lc == 0) {
#pragma unroll
        for (int mi = 0; mi < 4; ++mi)
#pragma unroll
            for (int r = 0; r < 4; ++r) {
                int row = wm * 64 + mi * 16 + g * 4 + r;
                red[row * 2 + wn] = psum[mi][r];
            }
    }
    __syncthreads();
    if (tid < 128)
        atomicAdd(&scores[m0 + tid], red[tid * 2] + red[tid * 2 + 1]);
}

// ---------------------------------------------------------------------------
// Masked softmax over S per batch column, in place. One block per b.
// ---------------------------------------------------------------------------
__global__ __launch_bounds__(256)
void softmax_kernel(const int* __restrict__ lens, float* __restrict__ attn)
{
    const int b   = blockIdx.x;
    const int tid = threadIdx.x;
    const int len = lens[b];

    float sc[4];
#pragma unroll
    for (int k = 0; k < 4; ++k) {
        int s = k * 256 + tid;
        float x = attn[(size_t)s * BSZ + b];
        sc[k] = (s < len) ? x : NEG_MASK;
    }

    __shared__ float red[8];

    float m = fmaxf(fmaxf(sc[0], sc[1]), fmaxf(sc[2], sc[3]));
#pragma unroll
    for (int off = 32; off > 0; off >>= 1) m = fmaxf(m, __shfl_xor(m, off));
    if ((tid & 63) == 0) red[tid >> 6] = m;
    __syncthreads();
    m = fmaxf(fmaxf(red[0], red[1]), fmaxf(red[2], red[3]));

    float e[4];
    float sum = 0.f;
#pragma unroll
    for (int k = 0; k < 4; ++k) { e[k] = expf(sc[k] - m); sum += e[k]; }
#pragma unroll
    for (int off = 32; off > 0; off >>= 1) sum += __shfl_xor(sum, off);
    __syncthreads();
    if ((tid & 63) == 0) red[4 + (tid >> 6)] = sum;
    __syncthreads();
    float total = red[4] + red[5] + red[6] + red[7];
    float inv = 1.f / total;

#pragma unroll
    for (int k = 0; k < 4; ++k) {
        int s = k * 256 + tid;
        attn[(size_t)s * BSZ + b] = e[k] * inv;
    }
}

// ---------------------------------------------------------------------------
// ctx from the fp16 tiled At copy (halves read traffic vs fp32 hids).
// grid (8 s-chunks, 64 b): bid = sc + 8*b -> XCD = sc%8, so all 64 b-blocks
// of one s-chunk co-reside on one XCD; their 16B reads tile complete 64B
// lines (4 consecutive m = 4 consecutive b) in that XCD's L2.
// Thread t owns c = t*4 (f16x4, 8B reads).
// ---------------------------------------------------------------------------
__global__ __launch_bounds__(256)
void ctx16_kernel(const _Float16* __restrict__ At, const float* __restrict__ attn,
                  float* __restrict__ ctx)
{
    const int sc  = blockIdx.x;          // 0..7
    const int b   = blockIdx.y;          // 0..63
    const int tid = threadIdx.x;
    const int c   = tid * 4;

    const int kt  = c >> 6;              // tile col-block 0..15
    const int cb  = (c >> 3) & 7;
    const int e   = c & 7;               // 0 or 4
    const int sub = cb * 128 + e;        // within-tile offset minus fr/lr part

    float acc[4] = {0.f, 0.f, 0.f, 0.f};
    for (int s = sc * (SRC_LEN / 8); s < (sc + 1) * (SRC_LEN / 8); ++s) {
        float w = attn[(size_t)s * BSZ + b];
        if (w != 0.f) {
            const int m  = s * BSZ + b;
            const int rt = m >> 8;
            const int fr = (m >> 4) & 15;
            const int lr = m & 15;
            f16x4 h = *reinterpret_cast<const f16x4*>(
                &At[(size_t)(rt * 16 + kt) * THW256 + fr * 1024 + sub + lr * 8]);
#pragma unroll
            for (int j = 0; j < 4; ++j) acc[j] = fmaf(w, (float)h[j], acc[j]);
        }
    }
    float* dst = &ctx[(size_t)b * CDIM + c];
#pragma unroll
    for (int j = 0; j < 4; ++j) atomicAdd(dst + j, acc[j]);
}

// ---------------------------------------------------------------------------
// ctx fp32 (fallback path)
// ---------------------------------------------------------------------------
__global__ __launch_bounds__(256)
void ctx_kernel(const float* __restrict__ hids, const float* __restrict__ attn,
                float* __restrict__ ctx)
{
    const int b   = blockIdx.x;
    const int s0  = blockIdx.y * (SRC_LEN / 8);
    const int tid = threadIdx.x;

    float4 acc = make_float4(0.f, 0.f, 0.f, 0.f);
    for (int s = s0; s < s0 + SRC_LEN / 8; ++s) {
        float w = attn[(size_t)s * BSZ + b];
        if (w != 0.f) {
            float4 h = *reinterpret_cast<const float4*>(
                &hids[((size_t)s * BSZ + b) * CDIM + tid * 4]);
            acc.x = fmaf(w, h.x, acc.x);
            acc.y = fmaf(w, h.y, acc.y);
            acc.z = fmaf(w, h.z, acc.z);
            acc.w = fmaf(w, h.w, acc.w);
        }
    }
    float* dst = &ctx[(size_t)b * CDIM + tid * 4];
    atomicAdd(dst + 0, acc.x);
    atomicAdd(dst + 1, acc.y);
    atomicAdd(dst + 2, acc.z);
    atomicAdd(dst + 3, acc.w);
}

// ---------------------------------------------------------------------------
extern "C" void kernel_launch(void* const* d_in, const int* in_sizes, int n_in,
                              void* d_out, int out_size, void* d_ws, size_t ws_size,
                              hipStream_t stream)
{
    const float* dsr   = (const float*)d_in[0];
    const float* hids  = (const float*)d_in[1];
    const int*   lens  = (const int*)  d_in[2];
    const float* W_enc = (const float*)d_in[3];
    const float* b_enc = (const float*)d_in[4];
    const float* W_dec = (const float*)d_in[5];
    const float* b_dec = (const float*)d_in[6];
    const float* v     = (const float*)d_in[7];

    float* out  = (float*)d_out;
    float* ctx  = out;                       // [64*1024]
    float* attn = out + BSZ * CDIM;          // [1024*64] scores -> probs

    const size_t decb_b = (size_t)BSZ * ADIM * 4;     // 256 KB
    const size_t wf16_b = (size_t)ADIM * KDIM * 2;    // 2 MB
    const size_t af16_b = (size_t)MROWS * KDIM * 2;   // 128 MB

    float*    decb = (float*)d_ws;
    _Float16* Wt   = (_Float16*)((char*)d_ws + decb_b);
    _Float16* At   = (_Float16*)((char*)d_ws + decb_b + wf16_b);

    const bool fast = ws_size >= decb_b + wf16_b + af16_b;

    hipMemsetAsync(d_out, 0, (size_t)(BSZ * CDIM + SRC_LEN * BSZ) * sizeof(float), stream);
    hipMemsetAsync(d_ws, 0, decb_b, stream);   // decb is an atomic target

    dec_kernel<<<dim3(16, 4), 256, 0, stream>>>(dsr, W_dec, decb);

    if (fast) {
        const int nW = (ADIM / 256) * 16 * 8;            // 512
        const int nA = (MROWS / 256) * 16 * 8;           // 32768
        convert_merged_kernel<<<nW + nA, 256, 0, stream>>>(W_enc, Wt, hids, At, nW);
        enc_score_256<<<1024, 512, 0, stream>>>(At, Wt, decb, b_enc, b_dec, v, attn);
        softmax_kernel<<<BSZ, 256, 0, stream>>>(lens, attn);
        ctx16_kernel<<<dim3(8, BSZ), 256, 0, stream>>>(At, attn, ctx);
    } else {
        convert8_kernel<<<ADIM * KDIM / 8 / 256, 256, 0, stream>>>(W_enc, Wt);
        enc_score_fallback<<<4096, 256, 0, stream>>>(hids, Wt, decb, b_enc, b_dec, v, attn);
        softmax_kernel<<<BSZ, 256, 0, stream>>>(lens, attn);
        ctx_kernel<<<dim3(BSZ, 8), 256, 0, stream>>>(hids, attn, ctx);
    }
}

// Round 18
// 314.186 us; speedup vs baseline: 4.0117x; 1.0453x over previous
//
#include <hip/hip_runtime.h>
#include <math.h>

#define SRC_LEN  1024
#define BSZ      64
#define CDIM     1024
#define ADIM     1024
#define KDIM     1024
#define MROWS    (SRC_LEN * BSZ)
#define NEG_MASK -1000000.0f

// tiled fp16 layout (256-row tiles): tile = 256 rows x 64 cols,
//   fr = row>>4 (0..15), lr = row&15, cb = col>>3 (0..7), e = col&7
//   hw = fr*1024 + cb*128 + lr*8 + e       (tile = 16384 hw = 32 KB)
// Fragment read (ks=cb>>2, g=cb&3): hw = fr*1024 + ks*512 + g*128 + lr*8.
// => ds_read_b128 (64 lanes) covers 1KB contiguous -> conflict-free,
//    global->LDS staging is a plain contiguous copy.
#define THW256 16384

typedef _Float16 f16x8 __attribute__((ext_vector_type(8)));
typedef _Float16 f16x4 __attribute__((ext_vector_type(4)));
typedef float    f32x4 __attribute__((ext_vector_type(4)));

__device__ __forceinline__ float fast_tanh(float x) {
    float e = __expf(2.0f * x);
    return 1.0f - 2.0f / (e + 1.0f);
}

// async global(16B) -> LDS, per-lane global src, wave-uniform LDS base
__device__ __forceinline__ void gload16(const _Float16* g, _Float16* l) {
    __builtin_amdgcn_global_load_lds(
        (const __attribute__((address_space(1))) unsigned int*)g,
        (__attribute__((address_space(3))) unsigned int*)l, 16, 0, 0);
}

__device__ __forceinline__ f16x8 frag(const _Float16* buf, int fr, int ks,
                                      int g, int lc) {
    return *reinterpret_cast<const f16x8*>(
        &buf[fr * 1024 + ks * 512 + g * 128 + lc * 8]);
}

__device__ __forceinline__ f16x8 cvt8(float4 x, float4 y) {
    f16x8 o;
    o[0] = (_Float16)x.x; o[1] = (_Float16)x.y;
    o[2] = (_Float16)x.z; o[3] = (_Float16)x.w;
    o[4] = (_Float16)y.x; o[5] = (_Float16)y.y;
    o[6] = (_Float16)y.z; o[7] = (_Float16)y.w;
    return o;
}

// ---------------------------------------------------------------------------
// dec block body: decb[0..63][n0..n0+63] = dsr @ W_dec^T over full K.
// Plain stores (no atomics, no memset needed). Used by prep + fallback.
// ---------------------------------------------------------------------------
__device__ __forceinline__ void dec_block(const float* __restrict__ A,
                                          const float* __restrict__ W,
                                          float* __restrict__ out,
                                          int n0, int tid,
                                          float (*Asl)[64], float (*Bsl)[64])
{
    const int tx = tid & 15;
    const int ty = tid >> 4;

    float acc[4][4];
#pragma unroll
    for (int i = 0; i < 4; ++i)
#pragma unroll
        for (int j = 0; j < 4; ++j) acc[i][j] = 0.f;

    const int lr = tid >> 2;
    const int lk = (tid & 3) * 4;

    for (int kb = 0; kb < KDIM; kb += 16) {
        float4 a4 = *reinterpret_cast<const float4*>(&A[(size_t)lr * KDIM + kb + lk]);
        float4 b4 = *reinterpret_cast<const float4*>(&W[(size_t)(n0 + lr) * KDIM + kb + lk]);
        __syncthreads();
        Asl[lk + 0][lr] = a4.x; Asl[lk + 1][lr] = a4.y;
        Asl[lk + 2][lr] = a4.z; Asl[lk + 3][lr] = a4.w;
        Bsl[lk + 0][lr] = b4.x; Bsl[lk + 1][lr] = b4.y;
        Bsl[lk + 2][lr] = b4.z; Bsl[lk + 3][lr] = b4.w;
        __syncthreads();
#pragma unroll
        for (int k = 0; k < 16; ++k) {
            float4 av = *reinterpret_cast<const float4*>(&Asl[k][ty * 4]);
            float4 bv = *reinterpret_cast<const float4*>(&Bsl[k][tx * 4]);
            float am[4] = {av.x, av.y, av.z, av.w};
            float bn[4] = {bv.x, bv.y, bv.z, bv.w};
#pragma unroll
            for (int i = 0; i < 4; ++i)
#pragma unroll
                for (int j = 0; j < 4; ++j)
                    acc[i][j] = fmaf(am[i], bn[j], acc[i][j]);
        }
    }
#pragma unroll
    for (int i = 0; i < 4; ++i) {
        int m = ty * 4 + i;
#pragma unroll
        for (int j = 0; j < 4; ++j) {
            int n = n0 + tx * 4 + j;
            out[(size_t)m * ADIM + n] = acc[i][j];
        }
    }
}

// ---------------------------------------------------------------------------
// PREP (fast path): blocks [0,16) run dec (full-K, plain store);
// blocks [16, 16+nW+nA) convert W_enc / hids fp32 -> fp16 tiled.
// ---------------------------------------------------------------------------
__global__ __launch_bounds__(256)
void prep_kernel(const float* __restrict__ dsr, const float* __restrict__ Wdec,
                 float* __restrict__ decb,
                 const float* __restrict__ w_in, _Float16* __restrict__ w_out,
                 const float* __restrict__ a_in, _Float16* __restrict__ a_out,
                 int nW)
{
    __shared__ float Asl[16][64];
    __shared__ float Bsl[16][64];

    int bid = blockIdx.x;
    const int t = threadIdx.x;

    if (bid < 16) {
        dec_block(dsr, Wdec, decb, bid * 64, t, Asl, Bsl);
        return;
    }
    bid -= 16;

    const float* in;
    _Float16* out;
    if (bid < nW) { in = w_in; out = w_out; }
    else          { in = a_in; out = a_out; bid -= nW; }

    const int part = bid & 7;
    const int tile = bid >> 3;           // rt*16 + kt
    const int kt   = tile & 15;
    const int rt   = tile >> 4;
    const int u    = part * 256 + t;     // 8-elem group 0..2047
    const int fr = u >> 7;
    const int cb = (u >> 4) & 7;
    const int lr = u & 15;

    const size_t row = (size_t)rt * 256 + fr * 16 + lr;
    const int    col = kt * 64 + cb * 8;

    float4 x = *reinterpret_cast<const float4*>(&in[row * KDIM + col]);
    float4 y = *reinterpret_cast<const float4*>(&in[row * KDIM + col + 4]);
    *reinterpret_cast<f16x8*>(&out[(size_t)tile * THW256 + (size_t)u * 8]) = cvt8(x, y);
}

// ---------------------------------------------------------------------------
// Standalone dec (fallback path)
// ---------------------------------------------------------------------------
__global__ __launch_bounds__(256)
void dec_full_kernel(const float* __restrict__ A, const float* __restrict__ W,
                     float* __restrict__ out)
{
    __shared__ float Asl[16][64];
    __shared__ float Bsl[16][64];
    dec_block(A, W, out, blockIdx.x * 64, threadIdx.x, Asl, Bsl);
}

// ---------------------------------------------------------------------------
// fp32 -> fp16 linear (fallback path W conversion)
// ---------------------------------------------------------------------------
__global__ __launch_bounds__(256)
void convert8_kernel(const float* __restrict__ in, _Float16* __restrict__ out)
{
    size_t i = ((size_t)blockIdx.x * 256 + threadIdx.x) * 8;
    float4 x = *reinterpret_cast<const float4*>(in + i);
    float4 y = *reinterpret_cast<const float4*>(in + i + 4);
    *reinterpret_cast<f16x8*>(out + i) = cvt8(x, y);
}

// ---------------------------------------------------------------------------
// FAST PATH: 256x256 tile, BK=64, 8 waves (R16 schedule, 3 phases/K-tile).
// scores -> ws (atomicAdd; ws scores region memset to 0).
// ---------------------------------------------------------------------------
__global__ __launch_bounds__(512, 1)
void enc_score_256(const _Float16* __restrict__ At,   // [256*16] tiles
                   const _Float16* __restrict__ Bt,   // [4*16] tiles
                   const float* __restrict__ decb,    // [64][1024] (no bias)
                   const float* __restrict__ be,      // b_enc
                   const float* __restrict__ bd,      // b_dec
                   const float* __restrict__ v,       // [1024]
                   float* __restrict__ scores)        // ws [65536]
{
    // nwg=1024, XCD-grouped: the 4 nbt-sharers of one mb on one XCD.
    const int bid = blockIdx.x;
    const int nbt = (bid >> 3) & 3;
    const int mb  = (bid & 7) + ((bid >> 5) << 3);
    const int m0 = mb * 256, n0 = nbt * 256;
    const int tid  = threadIdx.x;
    const int lane = tid & 63;
    const int wid  = tid >> 6;          // 0..7
    const int wm   = wid >> 2;          // 0..1
    const int wn   = wid & 3;           // 0..3
    const int lc   = lane & 15, g = lane >> 4;

    __shared__ __align__(16) _Float16 As[2][THW256];   // 64 KB
    __shared__ __align__(16) _Float16 Bs[2][THW256];   // 64 KB

    f32x4 acc[8][4];
#pragma unroll
    for (int i = 0; i < 8; ++i)
#pragma unroll
        for (int j = 0; j < 4; ++j) acc[i][j] = (f32x4){0.f, 0.f, 0.f, 0.f};

    const _Float16* Abase = At + (size_t)(mb * 16) * THW256;
    const _Float16* Bbase = Bt + (size_t)(nbt * 16) * THW256;

    // ---- prologue: stage K-tile 0 into buffer 0 (8 gloads/wave) ----
#pragma unroll
    for (int i = 0; i < 4; ++i) {
        int c = wid * 4 + i;                  // chunk 0..31, 1KB each
        gload16(Abase + c * 512 + lane * 8, &As[0][c * 512]);
        gload16(Bbase + c * 512 + lane * 8, &Bs[0][c * 512]);
    }
    asm volatile("s_waitcnt vmcnt(0)" ::: "memory");
    __builtin_amdgcn_s_barrier();
    asm volatile("" ::: "memory");

    for (int kt = 0; kt < 16; ++kt) {
        const int cur = kt & 1;
        const _Float16* Acur = As[cur];
        const _Float16* Bcur = Bs[cur];
        _Float16* Anxt = As[cur ^ 1];
        _Float16* Bnxt = Bs[cur ^ 1];
        const _Float16* Ag = Abase + (size_t)(kt + 1) * THW256;
        const _Float16* Bg = Bbase + (size_t)(kt + 1) * THW256;
        const bool pre = (kt < 15);

        f16x8 af[4], bf[4];

        // ===== phase 0: ks=0, mi 0..3  (+ stage A of kt+1) =====
#pragma unroll
        for (int ni = 0; ni < 4; ++ni) bf[ni] = frag(Bcur, wn * 4 + ni, 0, g, lc);
#pragma unroll
        for (int i = 0; i < 4; ++i)    af[i]  = frag(Acur, wm * 8 + i, 0, g, lc);
        if (pre) {
#pragma unroll
            for (int i = 0; i < 4; ++i) {
                int c = wid * 4 + i;
                gload16(Ag + c * 512 + lane * 8, Anxt + c * 512);
            }
        }
        __builtin_amdgcn_s_barrier();
        asm volatile("s_waitcnt lgkmcnt(0)" ::: "memory");
        __builtin_amdgcn_sched_barrier(0);
        __builtin_amdgcn_s_setprio(1);
#pragma unroll
        for (int i = 0; i < 4; ++i)
#pragma unroll
            for (int ni = 0; ni < 4; ++ni)
                acc[i][ni] = __builtin_amdgcn_mfma_f32_16x16x32_f16(
                    af[i], bf[ni], acc[i][ni], 0, 0, 0);
        __builtin_amdgcn_s_setprio(0);
        __builtin_amdgcn_s_barrier();

        // ===== phase 1: ks=0, mi 4..7  (+ stage B of kt+1) =====
#pragma unroll
        for (int i = 0; i < 4; ++i) af[i] = frag(Acur, wm * 8 + 4 + i, 0, g, lc);
        if (pre) {
#pragma unroll
            for (int i = 0; i < 4; ++i) {
                int c = wid * 4 + i;
                gload16(Bg + c * 512 + lane * 8, Bnxt + c * 512);
            }
        }
        __builtin_amdgcn_s_barrier();
        asm volatile("s_waitcnt lgkmcnt(0)" ::: "memory");
        __builtin_amdgcn_sched_barrier(0);
        __builtin_amdgcn_s_setprio(1);
#pragma unroll
        for (int i = 0; i < 4; ++i)
#pragma unroll
            for (int ni = 0; ni < 4; ++ni)
                acc[4 + i][ni] = __builtin_amdgcn_mfma_f32_16x16x32_f16(
                    af[i], bf[ni], acc[4 + i][ni], 0, 0, 0);
        __builtin_amdgcn_s_setprio(0);
        __builtin_amdgcn_s_barrier();

        // ===== phase 2 (merged 2+3): ks=1, mi 0..7 =====
        f16x8 af8[8];
#pragma unroll
        for (int ni = 0; ni < 4; ++ni) bf[ni] = frag(Bcur, wn * 4 + ni, 1, g, lc);
#pragma unroll
        for (int i = 0; i < 8; ++i)    af8[i] = frag(Acur, wm * 8 + i, 1, g, lc);
        __builtin_amdgcn_s_barrier();
        asm volatile("s_waitcnt lgkmcnt(0)" ::: "memory");
        __builtin_amdgcn_sched_barrier(0);
        __builtin_amdgcn_s_setprio(1);
#pragma unroll
        for (int i = 0; i < 8; ++i)
#pragma unroll
            for (int ni = 0; ni < 4; ++ni)
                acc[i][ni] = __builtin_amdgcn_mfma_f32_16x16x32_f16(
                    af8[i], bf[ni], acc[i][ni], 0, 0, 0);
        __builtin_amdgcn_s_setprio(0);
        if (pre) asm volatile("s_waitcnt vmcnt(0)" ::: "memory");
        __builtin_amdgcn_s_barrier();
        asm volatile("" ::: "memory");
    }

    // ---- fused epilogue: tanh + v-dot + reduce ----
    __syncthreads();

    float psum[8][4];
#pragma unroll
    for (int mi = 0; mi < 8; ++mi)
#pragma unroll
        for (int r = 0; r < 4; ++r) psum[mi][r] = 0.f;

#pragma unroll
    for (int mi = 0; mi < 8; ++mi) {
#pragma unroll
        for (int ni = 0; ni < 4; ++ni) {
            int n = n0 + wn * 64 + ni * 16 + lc;
            float vn = v[n];
            float bb = be[n] + bd[n];
#pragma unroll
            for (int r = 0; r < 4; ++r) {
                int b = ((mi & 3) * 16) + g * 4 + r;   // row & 63
                float x = acc[mi][ni][r] + decb[(size_t)b * ADIM + n] + bb;
                psum[mi][r] = fmaf(fast_tanh(x), vn, psum[mi][r]);
            }
        }
    }
#pragma unroll
    for (int mi = 0; mi < 8; ++mi)
#pragma unroll
        for (int r = 0; r < 4; ++r) {
            float s = psum[mi][r];
            s += __shfl_xor(s, 1);
            s += __shfl_xor(s, 2);
            s += __shfl_xor(s, 4);
            s += __shfl_xor(s, 8);
            psum[mi][r] = s;
        }

    float* red = reinterpret_cast<float*>(&As[0][0]);   // [256][4]
    if (lc == 0) {
#pragma unroll
        for (int mi = 0; mi < 8; ++mi)
#pragma unroll
            for (int r = 0; r < 4; ++r) {
                int row = wm * 128 + mi * 16 + g * 4 + r;
                red[row * 4 + wn] = psum[mi][r];
            }
    }
    __syncthreads();
    if (tid < 256)
        atomicAdd(&scores[m0 + tid],
                  red[tid * 4] + red[tid * 4 + 1] + red[tid * 4 + 2] + red[tid * 4 + 3]);
}

// ---------------------------------------------------------------------------
// FALLBACK (ws too small): reg-staged fp32-A 128x128 version (scores -> attn).
// ---------------------------------------------------------------------------
__global__ __launch_bounds__(256)
void enc_score_fallback(const float* __restrict__ A,
                        const _Float16* __restrict__ Bw,
                        const float* __restrict__ decb,
                        const float* __restrict__ be,
                        const float* __restrict__ bd,
                        const float* __restrict__ v,
                        float* __restrict__ scores)
{
    const int bid = blockIdx.x;
    const int nb  = (bid >> 3) & 7;
    const int mb  = (bid & 7) + ((bid >> 6) << 3);
    const int m0 = mb * 128, n0 = nb * 128;
    const int tid  = threadIdx.x;
    const int lane = tid & 63;
    const int wid  = tid >> 6;
    const int wm   = wid >> 1, wn = wid & 1;
    const int lc   = lane & 15, g = lane >> 4;

    __shared__ __align__(16) _Float16 As[128 * 64];
    __shared__ __align__(16) _Float16 Bs[128 * 64];

    const int srow = tid >> 1;
    const int scol = (tid & 1) * 32;
    const int sw   = (srow & 7) << 3;

    f32x4 acc[4][4];
#pragma unroll
    for (int i = 0; i < 4; ++i)
#pragma unroll
        for (int j = 0; j < 4; ++j) acc[i][j] = (f32x4){0.f, 0.f, 0.f, 0.f};

    const float*    Aptr = A  + (size_t)(m0 + srow) * KDIM + scol;
    const _Float16* Bptr = Bw + (size_t)(n0 + srow) * KDIM + scol;

    float4 aR[8];
    uint4  bR[4];
#pragma unroll
    for (int i = 0; i < 8; ++i) aR[i] = reinterpret_cast<const float4*>(Aptr)[i];
#pragma unroll
    for (int i = 0; i < 4; ++i) bR[i] = reinterpret_cast<const uint4*>(Bptr)[i];

    for (int kb = 0; kb < KDIM; kb += 64) {
        __syncthreads();
#pragma unroll
        for (int w = 0; w < 4; ++w) {
            int hw = (srow * 64 + scol + 8 * w) ^ sw;
            *reinterpret_cast<f16x8*>(&As[hw]) = cvt8(aR[2 * w], aR[2 * w + 1]);
            *reinterpret_cast<uint4*>(&Bs[hw]) = bR[w];
        }
        __syncthreads();
        if (kb + 64 < KDIM) {
#pragma unroll
            for (int i = 0; i < 8; ++i)
                aR[i] = reinterpret_cast<const float4*>(Aptr + kb + 64)[i];
#pragma unroll
            for (int i = 0; i < 4; ++i)
                bR[i] = reinterpret_cast<const uint4*>(Bptr + kb + 64)[i];
        }
#pragma unroll
        for (int ks = 0; ks < 2; ++ks) {
            f16x8 af[4], bf[4];
#pragma unroll
            for (int mi = 0; mi < 4; ++mi) {
                int r  = wm * 64 + mi * 16 + lc;
                int hw = (r * 64 + ks * 32 + g * 8) ^ ((r & 7) << 3);
                af[mi] = *reinterpret_cast<const f16x8*>(&As[hw]);
            }
#pragma unroll
            for (int ni = 0; ni < 4; ++ni) {
                int r  = wn * 64 + ni * 16 + lc;
                int hw = (r * 64 + ks * 32 + g * 8) ^ ((r & 7) << 3);
                bf[ni] = *reinterpret_cast<const f16x8*>(&Bs[hw]);
            }
#pragma unroll
            for (int mi = 0; mi < 4; ++mi)
#pragma unroll
                for (int ni = 0; ni < 4; ++ni)
                    acc[mi][ni] = __builtin_amdgcn_mfma_f32_16x16x32_f16(
                        af[mi], bf[ni], acc[mi][ni], 0, 0, 0);
        }
    }

    __syncthreads();

    float psum[4][4];
#pragma unroll
    for (int mi = 0; mi < 4; ++mi)
#pragma unroll
        for (int r = 0; r < 4; ++r) psum[mi][r] = 0.f;

#pragma unroll
    for (int mi = 0; mi < 4; ++mi) {
#pragma unroll
        for (int ni = 0; ni < 4; ++ni) {
            int n = n0 + wn * 64 + ni * 16 + lc;
            float vn = v[n];
            float bb = be[n] + bd[n];
#pragma unroll
            for (int r = 0; r < 4; ++r) {
                int b = mi * 16 + g * 4 + r;
                float x = acc[mi][ni][r] + decb[(size_t)b * ADIM + n] + bb;
                psum[mi][r] = fmaf(fast_tanh(x), vn, psum[mi][r]);
            }
        }
    }
#pragma unroll
    for (int mi = 0; mi < 4; ++mi)
#pragma unroll
        for (int r = 0; r < 4; ++r) {
            float s = psum[mi][r];
            s += __shfl_xor(s, 1);
            s += __shfl_xor(s, 2);
            s += __shfl_xor(s, 4);
            s += __shfl_xor(s, 8);
            psum[mi][r] = s;
        }

    float* red = reinterpret_cast<float*>(As);
    if (lc == 0) {
#pragma unroll
        for (int mi = 0; mi < 4; ++mi)
#pragma unroll
            for (int r = 0; r < 4; ++r) {
                int row = wm * 64 + mi * 16 + g * 4 + r;
                red[row * 2 + wn] = psum[mi][r];
            }
    }
    __syncthreads();
    if (tid < 128)
        atomicAdd(&scores[m0 + tid], red[tid * 2] + red[tid * 2 + 1]);
}

// ---------------------------------------------------------------------------
// Masked softmax over S per batch column, in place (fallback path).
// ---------------------------------------------------------------------------
__global__ __launch_bounds__(256)
void softmax_kernel(const int* __restrict__ lens, float* __restrict__ attn)
{
    const int b   = blockIdx.x;
    const int tid = threadIdx.x;
    const int len = lens[b];

    float sc[4];
#pragma unroll
    for (int k = 0; k < 4; ++k) {
        int s = k * 256 + tid;
        float x = attn[(size_t)s * BSZ + b];
        sc[k] = (s < len) ? x : NEG_MASK;
    }

    __shared__ float red[8];

    float m = fmaxf(fmaxf(sc[0], sc[1]), fmaxf(sc[2], sc[3]));
#pragma unroll
    for (int off = 32; off > 0; off >>= 1) m = fmaxf(m, __shfl_xor(m, off));
    if ((tid & 63) == 0) red[tid >> 6] = m;
    __syncthreads();
    m = fmaxf(fmaxf(red[0], red[1]), fmaxf(red[2], red[3]));

    float e[4];
    float sum = 0.f;
#pragma unroll
    for (int k = 0; k < 4; ++k) { e[k] = expf(sc[k] - m); sum += e[k]; }
#pragma unroll
    for (int off = 32; off > 0; off >>= 1) sum += __shfl_xor(sum, off);
    __syncthreads();
    if ((tid & 63) == 0) red[4 + (tid >> 6)] = sum;
    __syncthreads();
    float total = red[4] + red[5] + red[6] + red[7];
    float inv = 1.f / total;

#pragma unroll
    for (int k = 0; k < 4; ++k) {
        int s = k * 256 + tid;
        attn[(size_t)s * BSZ + b] = e[k] * inv;
    }
}

// ---------------------------------------------------------------------------
// MERGED softmax+ctx (fast path). grid (8 sc, 64 b).
// Each block: read full scores column from ws, compute softmax in-register,
// store weights to LDS; sc==0 blocks write attn output slice (full column);
// then ctx accumulation over this block's s-range from fp16 tiled At.
// No races: scores(ws) read-only here; attn written only by sc==0.
// ---------------------------------------------------------------------------
__global__ __launch_bounds__(256)
void softmax_ctx_kernel(const _Float16* __restrict__ At,
                        const float* __restrict__ scores,  // ws [65536]
                        const int* __restrict__ lens,
                        float* __restrict__ attn,          // out [1024*64]
                        float* __restrict__ ctx)           // out [64*1024]
{
    const int sc  = blockIdx.x;          // 0..7
    const int b   = blockIdx.y;          // 0..63
    const int tid = threadIdx.x;
    const int len = lens[b];

    __shared__ float wl[SRC_LEN];        // 4 KB softmax weights
    __shared__ float red[8];

    // ---- softmax over the full column (each thread holds 4 s-values) ----
    float s4[4];
#pragma unroll
    for (int k = 0; k < 4; ++k) {
        int s = k * 256 + tid;
        float x = scores[(size_t)s * BSZ + b];
        s4[k] = (s < len) ? x : NEG_MASK;
    }
    float m = fmaxf(fmaxf(s4[0], s4[1]), fmaxf(s4[2], s4[3]));
#pragma unroll
    for (int off = 32; off > 0; off >>= 1) m = fmaxf(m, __shfl_xor(m, off));
    if ((tid & 63) == 0) red[tid >> 6] = m;
    __syncthreads();
    m = fmaxf(fmaxf(red[0], red[1]), fmaxf(red[2], red[3]));

    float e[4];
    float sum = 0.f;
#pragma unroll
    for (int k = 0; k < 4; ++k) { e[k] = expf(s4[k] - m); sum += e[k]; }
#pragma unroll
    for (int off = 32; off > 0; off >>= 1) sum += __shfl_xor(sum, off);
    __syncthreads();
    if ((tid & 63) == 0) red[4 + (tid >> 6)] = sum;
    __syncthreads();
    float inv = 1.f / (red[4] + red[5] + red[6] + red[7]);

#pragma unroll
    for (int k = 0; k < 4; ++k) wl[k * 256 + tid] = e[k] * inv;
    __syncthreads();

    if (sc == 0) {
#pragma unroll
        for (int k = 0; k < 4; ++k) {
            int s = k * 256 + tid;
            attn[(size_t)s * BSZ + b] = wl[s];
        }
    }

    // ---- ctx accumulation over this block's s-slice ----
    const int c   = tid * 4;
    const int kt  = c >> 6;
    const int cb  = (c >> 3) & 7;
    const int e2  = c & 7;
    const int sub = cb * 128 + e2;

    float acc[4] = {0.f, 0.f, 0.f, 0.f};
    for (int s = sc * (SRC_LEN / 8); s < (sc + 1) * (SRC_LEN / 8); ++s) {
        float w = wl[s];
        if (w != 0.f) {
            const int mm = s * BSZ + b;
            const int rt = mm >> 8;
            const int fr = (mm >> 4) & 15;
            const int lr = mm & 15;
            f16x4 h = *reinterpret_cast<const f16x4*>(
                &At[(size_t)(rt * 16 + kt) * THW256 + fr * 1024 + sub + lr * 8]);
#pragma unroll
            for (int j = 0; j < 4; ++j) acc[j] = fmaf(w, (float)h[j], acc[j]);
        }
    }
    float* dst = &ctx[(size_t)b * CDIM + c];
#pragma unroll
    for (int j = 0; j < 4; ++j) atomicAdd(dst + j, acc[j]);
}

// ---------------------------------------------------------------------------
// ctx fp32 (fallback path)
// ---------------------------------------------------------------------------
__global__ __launch_bounds__(256)
void ctx_kernel(const float* __restrict__ hids, const float* __restrict__ attn,
                float* __restrict__ ctx)
{
    const int b   = blockIdx.x;
    const int s0  = blockIdx.y * (SRC_LEN / 8);
    const int tid = threadIdx.x;

    float4 acc = make_float4(0.f, 0.f, 0.f, 0.f);
    for (int s = s0; s < s0 + SRC_LEN / 8; ++s) {
        float w = attn[(size_t)s * BSZ + b];
        if (w != 0.f) {
            float4 h = *reinterpret_cast<const float4*>(
                &hids[((size_t)s * BSZ + b) * CDIM + tid * 4]);
            acc.x = fmaf(w, h.x, acc.x);
            acc.y = fmaf(w, h.y, acc.y);
            acc.z = fmaf(w, h.z, acc.z);
            acc.w = fmaf(w, h.w, acc.w);
        }
    }
    float* dst = &ctx[(size_t)b * CDIM + tid * 4];
    atomicAdd(dst + 0, acc.x);
    atomicAdd(dst + 1, acc.y);
    atomicAdd(dst + 2, acc.z);
    atomicAdd(dst + 3, acc.w);
}

// ---------------------------------------------------------------------------
extern "C" void kernel_launch(void* const* d_in, const int* in_sizes, int n_in,
                              void* d_out, int out_size, void* d_ws, size_t ws_size,
                              hipStream_t stream)
{
    const float* dsr   = (const float*)d_in[0];
    const float* hids  = (const float*)d_in[1];
    const int*   lens  = (const int*)  d_in[2];
    const float* W_enc = (const float*)d_in[3];
    const float* b_enc = (const float*)d_in[4];
    const float* W_dec = (const float*)d_in[5];
    const float* b_dec = (const float*)d_in[6];
    const float* v     = (const float*)d_in[7];

    float* out  = (float*)d_out;
    float* ctx  = out;                       // [64*1024]
    float* attn = out + BSZ * CDIM;          // [1024*64]

    const size_t decb_b = (size_t)BSZ * ADIM * 4;     // 256 KB
    const size_t scws_b = (size_t)MROWS * 4;          // 256 KB
    const size_t wf16_b = (size_t)ADIM * KDIM * 2;    // 2 MB
    const size_t af16_b = (size_t)MROWS * KDIM * 2;   // 128 MB

    float*    decb    = (float*)d_ws;
    float*    scoresW = (float*)((char*)d_ws + decb_b);
    _Float16* Wt      = (_Float16*)((char*)d_ws + decb_b + scws_b);
    _Float16* At      = (_Float16*)((char*)d_ws + decb_b + scws_b + wf16_b);

    const bool fast = ws_size >= decb_b + scws_b + wf16_b + af16_b;

    hipMemsetAsync(d_out, 0, (size_t)(BSZ * CDIM + SRC_LEN * BSZ) * sizeof(float), stream);

    if (fast) {
        hipMemsetAsync(scoresW, 0, scws_b, stream);   // enc atomic target
        const int nW = (ADIM / 256) * 16 * 8;            // 512
        const int nA = (MROWS / 256) * 16 * 8;           // 32768
        prep_kernel<<<16 + nW + nA, 256, 0, stream>>>(dsr, W_dec, decb,
                                                      W_enc, Wt, hids, At, nW);
        enc_score_256<<<1024, 512, 0, stream>>>(At, Wt, decb, b_enc, b_dec, v, scoresW);
        softmax_ctx_kernel<<<dim3(8, BSZ), 256, 0, stream>>>(At, scoresW, lens, attn, ctx);
    } else {
        dec_full_kernel<<<16, 256, 0, stream>>>(dsr, W_dec, decb);
        convert8_kernel<<<ADIM * KDIM / 8 / 256, 256, 0, stream>>>(W_enc, Wt);
        enc_score_fallback<<<4096, 256, 0, stream>>>(hids, Wt, decb, b_enc, b_dec, v, attn);
        softmax_kernel<<<BSZ, 256, 0, stream>>>(lens, attn);
        ctx_kernel<<<dim3(BSZ, 8), 256, 0, stream>>>(hids, attn, ctx);
    }
}

// Round 19
// 306.466 us; speedup vs baseline: 4.1127x; 1.0252x over previous
//
#include <hip/hip_runtime.h>
#include <math.h>

#define SRC_LEN  1024
#define BSZ      64
#define CDIM     1024
#define ADIM     1024
#define KDIM     1024
#define MROWS    (SRC_LEN * BSZ)
#define NEG_MASK -1000000.0f

// tiled fp16 layout (256-row tiles): tile = 256 rows x 64 cols,
//   fr = row>>4 (0..15), lr = row&15, cb = col>>3 (0..7), e = col&7
//   hw = fr*1024 + cb*128 + lr*8 + e       (tile = 16384 hw = 32 KB)
// Fragment read (ks=cb>>2, g=cb&3): hw = fr*1024 + ks*512 + g*128 + lr*8.
// => ds_read_b128 (64 lanes) covers 1KB contiguous -> conflict-free,
//    global->LDS staging is a plain contiguous copy.
#define THW256 16384

typedef _Float16 f16x8 __attribute__((ext_vector_type(8)));
typedef _Float16 f16x4 __attribute__((ext_vector_type(4)));
typedef float    f32x4 __attribute__((ext_vector_type(4)));

__device__ __forceinline__ float fast_tanh(float x) {
    float e = __expf(2.0f * x);
    return 1.0f - 2.0f / (e + 1.0f);
}

// async global(16B) -> LDS, per-lane global src, wave-uniform LDS base
__device__ __forceinline__ void gload16(const _Float16* g, _Float16* l) {
    __builtin_amdgcn_global_load_lds(
        (const __attribute__((address_space(1))) unsigned int*)g,
        (__attribute__((address_space(3))) unsigned int*)l, 16, 0, 0);
}

__device__ __forceinline__ f16x8 frag(const _Float16* buf, int fr, int ks,
                                      int g, int lc) {
    return *reinterpret_cast<const f16x8*>(
        &buf[fr * 1024 + ks * 512 + g * 128 + lc * 8]);
}

__device__ __forceinline__ f16x8 cvt8(float4 x, float4 y) {
    f16x8 o;
    o[0] = (_Float16)x.x; o[1] = (_Float16)x.y;
    o[2] = (_Float16)x.z; o[3] = (_Float16)x.w;
    o[4] = (_Float16)y.x; o[5] = (_Float16)y.y;
    o[6] = (_Float16)y.z; o[7] = (_Float16)y.w;
    return o;
}

// ---------------------------------------------------------------------------
// dec block body: decb[0..63][n0..n0+63] = dsr @ W_dec^T over full K.
// Plain stores (no atomics, no memset needed). Used by prep + fallback.
// ---------------------------------------------------------------------------
__device__ __forceinline__ void dec_block(const float* __restrict__ A,
                                          const float* __restrict__ W,
                                          float* __restrict__ out,
                                          int n0, int tid,
                                          float (*Asl)[64], float (*Bsl)[64])
{
    const int tx = tid & 15;
    const int ty = tid >> 4;

    float acc[4][4];
#pragma unroll
    for (int i = 0; i < 4; ++i)
#pragma unroll
        for (int j = 0; j < 4; ++j) acc[i][j] = 0.f;

    const int lr = tid >> 2;
    const int lk = (tid & 3) * 4;

    for (int kb = 0; kb < KDIM; kb += 16) {
        float4 a4 = *reinterpret_cast<const float4*>(&A[(size_t)lr * KDIM + kb + lk]);
        float4 b4 = *reinterpret_cast<const float4*>(&W[(size_t)(n0 + lr) * KDIM + kb + lk]);
        __syncthreads();
        Asl[lk + 0][lr] = a4.x; Asl[lk + 1][lr] = a4.y;
        Asl[lk + 2][lr] = a4.z; Asl[lk + 3][lr] = a4.w;
        Bsl[lk + 0][lr] = b4.x; Bsl[lk + 1][lr] = b4.y;
        Bsl[lk + 2][lr] = b4.z; Bsl[lk + 3][lr] = b4.w;
        __syncthreads();
#pragma unroll
        for (int k = 0; k < 16; ++k) {
            float4 av = *reinterpret_cast<const float4*>(&Asl[k][ty * 4]);
            float4 bv = *reinterpret_cast<const float4*>(&Bsl[k][tx * 4]);
            float am[4] = {av.x, av.y, av.z, av.w};
            float bn[4] = {bv.x, bv.y, bv.z, bv.w};
#pragma unroll
            for (int i = 0; i < 4; ++i)
#pragma unroll
                for (int j = 0; j < 4; ++j)
                    acc[i][j] = fmaf(am[i], bn[j], acc[i][j]);
        }
    }
#pragma unroll
    for (int i = 0; i < 4; ++i) {
        int m = ty * 4 + i;
#pragma unroll
        for (int j = 0; j < 4; ++j) {
            int n = n0 + tx * 4 + j;
            out[(size_t)m * ADIM + n] = acc[i][j];
        }
    }
}

// ---------------------------------------------------------------------------
// PREP (fast path): blocks [0,16) run dec (full-K, plain store);
// blocks [16, 16+nW+nA) convert W_enc / hids fp32 -> fp16 tiled;
// blocks [16+nW+nA, +64) zero scoresW (32 blocks) and ctx (32 blocks)
// -> removes both fast-path hipMemsetAsync dispatches.
// ---------------------------------------------------------------------------
__global__ __launch_bounds__(256)
void prep_kernel(const float* __restrict__ dsr, const float* __restrict__ Wdec,
                 float* __restrict__ decb,
                 const float* __restrict__ w_in, _Float16* __restrict__ w_out,
                 const float* __restrict__ a_in, _Float16* __restrict__ a_out,
                 float* __restrict__ zero1,      // scoresW [65536]
                 float* __restrict__ zero2,      // ctx     [65536]
                 int nW, int nA)
{
    __shared__ float Asl[16][64];
    __shared__ float Bsl[16][64];

    int bid = blockIdx.x;
    const int t = threadIdx.x;

    if (bid < 16) {
        dec_block(dsr, Wdec, decb, bid * 64, t, Asl, Bsl);
        return;
    }
    bid -= 16;

    if (bid >= nW + nA) {   // zero blocks: 2048 floats each (2 float4/thread)
        int zid = bid - nW - nA;              // 0..63
        float* dst = (zid < 32) ? zero1 : zero2;
        int off = (zid & 31) * 2048 + t * 8;
        *reinterpret_cast<float4*>(&dst[off])     = make_float4(0.f, 0.f, 0.f, 0.f);
        *reinterpret_cast<float4*>(&dst[off + 4]) = make_float4(0.f, 0.f, 0.f, 0.f);
        return;
    }

    const float* in;
    _Float16* out;
    if (bid < nW) { in = w_in; out = w_out; }
    else          { in = a_in; out = a_out; bid -= nW; }

    const int part = bid & 7;
    const int tile = bid >> 3;           // rt*16 + kt
    const int kt   = tile & 15;
    const int rt   = tile >> 4;
    const int u    = part * 256 + t;     // 8-elem group 0..2047
    const int fr = u >> 7;
    const int cb = (u >> 4) & 7;
    const int lr = u & 15;

    const size_t row = (size_t)rt * 256 + fr * 16 + lr;
    const int    col = kt * 64 + cb * 8;

    float4 x = *reinterpret_cast<const float4*>(&in[row * KDIM + col]);
    float4 y = *reinterpret_cast<const float4*>(&in[row * KDIM + col + 4]);
    *reinterpret_cast<f16x8*>(&out[(size_t)tile * THW256 + (size_t)u * 8]) = cvt8(x, y);
}

// ---------------------------------------------------------------------------
// Standalone dec (fallback path)
// ---------------------------------------------------------------------------
__global__ __launch_bounds__(256)
void dec_full_kernel(const float* __restrict__ A, const float* __restrict__ W,
                     float* __restrict__ out)
{
    __shared__ float Asl[16][64];
    __shared__ float Bsl[16][64];
    dec_block(A, W, out, blockIdx.x * 64, threadIdx.x, Asl, Bsl);
}

// ---------------------------------------------------------------------------
// fp32 -> fp16 linear (fallback path W conversion)
// ---------------------------------------------------------------------------
__global__ __launch_bounds__(256)
void convert8_kernel(const float* __restrict__ in, _Float16* __restrict__ out)
{
    size_t i = ((size_t)blockIdx.x * 256 + threadIdx.x) * 8;
    float4 x = *reinterpret_cast<const float4*>(in + i);
    float4 y = *reinterpret_cast<const float4*>(in + i + 4);
    *reinterpret_cast<f16x8*>(out + i) = cvt8(x, y);
}

// ---------------------------------------------------------------------------
// FAST PATH: 256x256 tile, BK=64, 8 waves (R16 schedule, 3 phases/K-tile).
// scores -> ws (atomicAdd; zeroed by prep).
// ---------------------------------------------------------------------------
__global__ __launch_bounds__(512, 1)
void enc_score_256(const _Float16* __restrict__ At,   // [256*16] tiles
                   const _Float16* __restrict__ Bt,   // [4*16] tiles
                   const float* __restrict__ decb,    // [64][1024] (no bias)
                   const float* __restrict__ be,      // b_enc
                   const float* __restrict__ bd,      // b_dec
                   const float* __restrict__ v,       // [1024]
                   float* __restrict__ scores)        // ws [65536]
{
    // nwg=1024, XCD-grouped: the 4 nbt-sharers of one mb on one XCD.
    const int bid = blockIdx.x;
    const int nbt = (bid >> 3) & 3;
    const int mb  = (bid & 7) + ((bid >> 5) << 3);
    const int m0 = mb * 256, n0 = nbt * 256;
    const int tid  = threadIdx.x;
    const int lane = tid & 63;
    const int wid  = tid >> 6;          // 0..7
    const int wm   = wid >> 2;          // 0..1
    const int wn   = wid & 3;           // 0..3
    const int lc   = lane & 15, g = lane >> 4;

    __shared__ __align__(16) _Float16 As[2][THW256];   // 64 KB
    __shared__ __align__(16) _Float16 Bs[2][THW256];   // 64 KB

    f32x4 acc[8][4];
#pragma unroll
    for (int i = 0; i < 8; ++i)
#pragma unroll
        for (int j = 0; j < 4; ++j) acc[i][j] = (f32x4){0.f, 0.f, 0.f, 0.f};

    const _Float16* Abase = At + (size_t)(mb * 16) * THW256;
    const _Float16* Bbase = Bt + (size_t)(nbt * 16) * THW256;

    // ---- prologue: stage K-tile 0 into buffer 0 (8 gloads/wave) ----
#pragma unroll
    for (int i = 0; i < 4; ++i) {
        int c = wid * 4 + i;                  // chunk 0..31, 1KB each
        gload16(Abase + c * 512 + lane * 8, &As[0][c * 512]);
        gload16(Bbase + c * 512 + lane * 8, &Bs[0][c * 512]);
    }
    asm volatile("s_waitcnt vmcnt(0)" ::: "memory");
    __builtin_amdgcn_s_barrier();
    asm volatile("" ::: "memory");

    for (int kt = 0; kt < 16; ++kt) {
        const int cur = kt & 1;
        const _Float16* Acur = As[cur];
        const _Float16* Bcur = Bs[cur];
        _Float16* Anxt = As[cur ^ 1];
        _Float16* Bnxt = Bs[cur ^ 1];
        const _Float16* Ag = Abase + (size_t)(kt + 1) * THW256;
        const _Float16* Bg = Bbase + (size_t)(kt + 1) * THW256;
        const bool pre = (kt < 15);

        f16x8 af[4], bf[4];

        // ===== phase 0: ks=0, mi 0..3  (+ stage A of kt+1) =====
#pragma unroll
        for (int ni = 0; ni < 4; ++ni) bf[ni] = frag(Bcur, wn * 4 + ni, 0, g, lc);
#pragma unroll
        for (int i = 0; i < 4; ++i)    af[i]  = frag(Acur, wm * 8 + i, 0, g, lc);
        if (pre) {
#pragma unroll
            for (int i = 0; i < 4; ++i) {
                int c = wid * 4 + i;
                gload16(Ag + c * 512 + lane * 8, Anxt + c * 512);
            }
        }
        __builtin_amdgcn_s_barrier();
        asm volatile("s_waitcnt lgkmcnt(0)" ::: "memory");
        __builtin_amdgcn_sched_barrier(0);
        __builtin_amdgcn_s_setprio(1);
#pragma unroll
        for (int i = 0; i < 4; ++i)
#pragma unroll
            for (int ni = 0; ni < 4; ++ni)
                acc[i][ni] = __builtin_amdgcn_mfma_f32_16x16x32_f16(
                    af[i], bf[ni], acc[i][ni], 0, 0, 0);
        __builtin_amdgcn_s_setprio(0);
        __builtin_amdgcn_s_barrier();

        // ===== phase 1: ks=0, mi 4..7  (+ stage B of kt+1) =====
#pragma unroll
        for (int i = 0; i < 4; ++i) af[i] = frag(Acur, wm * 8 + 4 + i, 0, g, lc);
        if (pre) {
#pragma unroll
            for (int i = 0; i < 4; ++i) {
                int c = wid * 4 + i;
                gload16(Bg + c * 512 + lane * 8, Bnxt + c * 512);
            }
        }
        __builtin_amdgcn_s_barrier();
        asm volatile("s_waitcnt lgkmcnt(0)" ::: "memory");
        __builtin_amdgcn_sched_barrier(0);
        __builtin_amdgcn_s_setprio(1);
#pragma unroll
        for (int i = 0; i < 4; ++i)
#pragma unroll
            for (int ni = 0; ni < 4; ++ni)
                acc[4 + i][ni] = __builtin_amdgcn_mfma_f32_16x16x32_f16(
                    af[i], bf[ni], acc[4 + i][ni], 0, 0, 0);
        __builtin_amdgcn_s_setprio(0);
        __builtin_amdgcn_s_barrier();

        // ===== phase 2 (merged 2+3): ks=1, mi 0..7 =====
        f16x8 af8[8];
#pragma unroll
        for (int ni = 0; ni < 4; ++ni) bf[ni] = frag(Bcur, wn * 4 + ni, 1, g, lc);
#pragma unroll
        for (int i = 0; i < 8; ++i)    af8[i] = frag(Acur, wm * 8 + i, 1, g, lc);
        __builtin_amdgcn_s_barrier();
        asm volatile("s_waitcnt lgkmcnt(0)" ::: "memory");
        __builtin_amdgcn_sched_barrier(0);
        __builtin_amdgcn_s_setprio(1);
#pragma unroll
        for (int i = 0; i < 8; ++i)
#pragma unroll
            for (int ni = 0; ni < 4; ++ni)
                acc[i][ni] = __builtin_amdgcn_mfma_f32_16x16x32_f16(
                    af8[i], bf[ni], acc[i][ni], 0, 0, 0);
        __builtin_amdgcn_s_setprio(0);
        if (pre) asm volatile("s_waitcnt vmcnt(0)" ::: "memory");
        __builtin_amdgcn_s_barrier();
        asm volatile("" ::: "memory");
    }

    // ---- fused epilogue: tanh + v-dot + reduce ----
    __syncthreads();

    float psum[8][4];
#pragma unroll
    for (int mi = 0; mi < 8; ++mi)
#pragma unroll
        for (int r = 0; r < 4; ++r) psum[mi][r] = 0.f;

#pragma unroll
    for (int mi = 0; mi < 8; ++mi) {
#pragma unroll
        for (int ni = 0; ni < 4; ++ni) {
            int n = n0 + wn * 64 + ni * 16 + lc;
            float vn = v[n];
            float bb = be[n] + bd[n];
#pragma unroll
            for (int r = 0; r < 4; ++r) {
                int b = ((mi & 3) * 16) + g * 4 + r;   // row & 63
                float x = acc[mi][ni][r] + decb[(size_t)b * ADIM + n] + bb;
                psum[mi][r] = fmaf(fast_tanh(x), vn, psum[mi][r]);
            }
        }
    }
#pragma unroll
    for (int mi = 0; mi < 8; ++mi)
#pragma unroll
        for (int r = 0; r < 4; ++r) {
            float s = psum[mi][r];
            s += __shfl_xor(s, 1);
            s += __shfl_xor(s, 2);
            s += __shfl_xor(s, 4);
            s += __shfl_xor(s, 8);
            psum[mi][r] = s;
        }

    float* red = reinterpret_cast<float*>(&As[0][0]);   // [256][4]
    if (lc == 0) {
#pragma unroll
        for (int mi = 0; mi < 8; ++mi)
#pragma unroll
            for (int r = 0; r < 4; ++r) {
                int row = wm * 128 + mi * 16 + g * 4 + r;
                red[row * 4 + wn] = psum[mi][r];
            }
    }
    __syncthreads();
    if (tid < 256)
        atomicAdd(&scores[m0 + tid],
                  red[tid * 4] + red[tid * 4 + 1] + red[tid * 4 + 2] + red[tid * 4 + 3]);
}

// ---------------------------------------------------------------------------
// FALLBACK (ws too small): reg-staged fp32-A 128x128 version (scores -> attn).
// ---------------------------------------------------------------------------
__global__ __launch_bounds__(256)
void enc_score_fallback(const float* __restrict__ A,
                        const _Float16* __restrict__ Bw,
                        const float* __restrict__ decb,
                        const float* __restrict__ be,
                        const float* __restrict__ bd,
                        const float* __restrict__ v,
                        float* __restrict__ scores)
{
    const int bid = blockIdx.x;
    const int nb  = (bid >> 3) & 7;
    const int mb  = (bid & 7) + ((bid >> 6) << 3);
    const int m0 = mb * 128, n0 = nb * 128;
    const int tid  = threadIdx.x;
    const int lane = tid & 63;
    const int wid  = tid >> 6;
    const int wm   = wid >> 1, wn = wid & 1;
    const int lc   = lane & 15, g = lane >> 4;

    __shared__ __align__(16) _Float16 As[128 * 64];
    __shared__ __align__(16) _Float16 Bs[128 * 64];

    const int srow = tid >> 1;
    const int scol = (tid & 1) * 32;
    const int sw   = (srow & 7) << 3;

    f32x4 acc[4][4];
#pragma unroll
    for (int i = 0; i < 4; ++i)
#pragma unroll
        for (int j = 0; j < 4; ++j) acc[i][j] = (f32x4){0.f, 0.f, 0.f, 0.f};

    const float*    Aptr = A  + (size_t)(m0 + srow) * KDIM + scol;
    const _Float16* Bptr = Bw + (size_t)(n0 + srow) * KDIM + scol;

    float4 aR[8];
    uint4  bR[4];
#pragma unroll
    for (int i = 0; i < 8; ++i) aR[i] = reinterpret_cast<const float4*>(Aptr)[i];
#pragma unroll
    for (int i = 0; i < 4; ++i) bR[i] = reinterpret_cast<const uint4*>(Bptr)[i];

    for (int kb = 0; kb < KDIM; kb += 64) {
        __syncthreads();
#pragma unroll
        for (int w = 0; w < 4; ++w) {
            int hw = (srow * 64 + scol + 8 * w) ^ sw;
            *reinterpret_cast<f16x8*>(&As[hw]) = cvt8(aR[2 * w], aR[2 * w + 1]);
            *reinterpret_cast<uint4*>(&Bs[hw]) = bR[w];
        }
        __syncthreads();
        if (kb + 64 < KDIM) {
#pragma unroll
            for (int i = 0; i < 8; ++i)
                aR[i] = reinterpret_cast<const float4*>(Aptr + kb + 64)[i];
#pragma unroll
            for (int i = 0; i < 4; ++i)
                bR[i] = reinterpret_cast<const uint4*>(Bptr + kb + 64)[i];
        }
#pragma unroll
        for (int ks = 0; ks < 2; ++ks) {
            f16x8 af[4], bf[4];
#pragma unroll
            for (int mi = 0; mi < 4; ++mi) {
                int r  = wm * 64 + mi * 16 + lc;
                int hw = (r * 64 + ks * 32 + g * 8) ^ ((r & 7) << 3);
                af[mi] = *reinterpret_cast<const f16x8*>(&As[hw]);
            }
#pragma unroll
            for (int ni = 0; ni < 4; ++ni) {
                int r  = wn * 64 + ni * 16 + lc;
                int hw = (r * 64 + ks * 32 + g * 8) ^ ((r & 7) << 3);
                bf[ni] = *reinterpret_cast<const f16x8*>(&Bs[hw]);
            }
#pragma unroll
            for (int mi = 0; mi < 4; ++mi)
#pragma unroll
                for (int ni = 0; ni < 4; ++ni)
                    acc[mi][ni] = __builtin_amdgcn_mfma_f32_16x16x32_f16(
                        af[mi], bf[ni], acc[mi][ni], 0, 0, 0);
        }
    }

    __syncthreads();

    float psum[4][4];
#pragma unroll
    for (int mi = 0; mi < 4; ++mi)
#pragma unroll
        for (int r = 0; r < 4; ++r) psum[mi][r] = 0.f;

#pragma unroll
    for (int mi = 0; mi < 4; ++mi) {
#pragma unroll
        for (int ni = 0; ni < 4; ++ni) {
            int n = n0 + wn * 64 + ni * 16 + lc;
            float vn = v[n];
            float bb = be[n] + bd[n];
#pragma unroll
            for (int r = 0; r < 4; ++r) {
                int b = mi * 16 + g * 4 + r;
                float x = acc[mi][ni][r] + decb[(size_t)b * ADIM + n] + bb;
                psum[mi][r] = fmaf(fast_tanh(x), vn, psum[mi][r]);
            }
        }
    }
#pragma unroll
    for (int mi = 0; mi < 4; ++mi)
#pragma unroll
        for (int r = 0; r < 4; ++r) {
            float s = psum[mi][r];
            s += __shfl_xor(s, 1);
            s += __shfl_xor(s, 2);
            s += __shfl_xor(s, 4);
            s += __shfl_xor(s, 8);
            psum[mi][r] = s;
        }

    float* red = reinterpret_cast<float*>(As);
    if (lc == 0) {
#pragma unroll
        for (int mi = 0; mi < 4; ++mi)
#pragma unroll
            for (int r = 0; r < 4; ++r) {
                int row = wm * 64 + mi * 16 + g * 4 + r;
                red[row * 2 + wn] = psum[mi][r];
            }
    }
    __syncthreads();
    if (tid < 128)
        atomicAdd(&scores[m0 + tid], red[tid * 2] + red[tid * 2 + 1]);
}

// ---------------------------------------------------------------------------
// Masked softmax over S per batch column, in place (fallback path).
// ---------------------------------------------------------------------------
__global__ __launch_bounds__(256)
void softmax_kernel(const int* __restrict__ lens, float* __restrict__ attn)
{
    const int b   = blockIdx.x;
    const int tid = threadIdx.x;
    const int len = lens[b];

    float sc[4];
#pragma unroll
    for (int k = 0; k < 4; ++k) {
        int s = k * 256 + tid;
        float x = attn[(size_t)s * BSZ + b];
        sc[k] = (s < len) ? x : NEG_MASK;
    }

    __shared__ float red[8];

    float m = fmaxf(fmaxf(sc[0], sc[1]), fmaxf(sc[2], sc[3]));
#pragma unroll
    for (int off = 32; off > 0; off >>= 1) m = fmaxf(m, __shfl_xor(m, off));
    if ((tid & 63) == 0) red[tid >> 6] = m;
    __syncthreads();
    m = fmaxf(fmaxf(red[0], red[1]), fmaxf(red[2], red[3]));

    float e[4];
    float sum = 0.f;
#pragma unroll
    for (int k = 0; k < 4; ++k) { e[k] = expf(sc[k] - m); sum += e[k]; }
#pragma unroll
    for (int off = 32; off > 0; off >>= 1) sum += __shfl_xor(sum, off);
    __syncthreads();
    if ((tid & 63) == 0) red[4 + (tid >> 6)] = sum;
    __syncthreads();
    float total = red[4] + red[5] + red[6] + red[7];
    float inv = 1.f / total;

#pragma unroll
    for (int k = 0; k < 4; ++k) {
        int s = k * 256 + tid;
        attn[(size_t)s * BSZ + b] = e[k] * inv;
    }
}

// ---------------------------------------------------------------------------
// MERGED softmax+ctx (fast path). grid (8 sc, 64 b).
// ---------------------------------------------------------------------------
__global__ __launch_bounds__(256)
void softmax_ctx_kernel(const _Float16* __restrict__ At,
                        const float* __restrict__ scores,  // ws [65536]
                        const int* __restrict__ lens,
                        float* __restrict__ attn,          // out [1024*64]
                        float* __restrict__ ctx)           // out [64*1024]
{
    const int sc  = blockIdx.x;          // 0..7
    const int b   = blockIdx.y;          // 0..63
    const int tid = threadIdx.x;
    const int len = lens[b];

    __shared__ float wl[SRC_LEN];        // 4 KB softmax weights
    __shared__ float red[8];

    float s4[4];
#pragma unroll
    for (int k = 0; k < 4; ++k) {
        int s = k * 256 + tid;
        float x = scores[(size_t)s * BSZ + b];
        s4[k] = (s < len) ? x : NEG_MASK;
    }
    float m = fmaxf(fmaxf(s4[0], s4[1]), fmaxf(s4[2], s4[3]));
#pragma unroll
    for (int off = 32; off > 0; off >>= 1) m = fmaxf(m, __shfl_xor(m, off));
    if ((tid & 63) == 0) red[tid >> 6] = m;
    __syncthreads();
    m = fmaxf(fmaxf(red[0], red[1]), fmaxf(red[2], red[3]));

    float e[4];
    float sum = 0.f;
#pragma unroll
    for (int k = 0; k < 4; ++k) { e[k] = expf(s4[k] - m); sum += e[k]; }
#pragma unroll
    for (int off = 32; off > 0; off >>= 1) sum += __shfl_xor(sum, off);
    __syncthreads();
    if ((tid & 63) == 0) red[4 + (tid >> 6)] = sum;
    __syncthreads();
    float inv = 1.f / (red[4] + red[5] + red[6] + red[7]);

#pragma unroll
    for (int k = 0; k < 4; ++k) wl[k * 256 + tid] = e[k] * inv;
    __syncthreads();

    if (sc == 0) {
#pragma unroll
        for (int k = 0; k < 4; ++k) {
            int s = k * 256 + tid;
            attn[(size_t)s * BSZ + b] = wl[s];
        }
    }

    const int c   = tid * 4;
    const int kt  = c >> 6;
    const int cb  = (c >> 3) & 7;
    const int e2  = c & 7;
    const int sub = cb * 128 + e2;

    float acc[4] = {0.f, 0.f, 0.f, 0.f};
    for (int s = sc * (SRC_LEN / 8); s < (sc + 1) * (SRC_LEN / 8); ++s) {
        float w = wl[s];
        if (w != 0.f) {
            const int mm = s * BSZ + b;
            const int rt = mm >> 8;
            const int fr = (mm >> 4) & 15;
            const int lr = mm & 15;
            f16x4 h = *reinterpret_cast<const f16x4*>(
                &At[(size_t)(rt * 16 + kt) * THW256 + fr * 1024 + sub + lr * 8]);
#pragma unroll
            for (int j = 0; j < 4; ++j) acc[j] = fmaf(w, (float)h[j], acc[j]);
        }
    }
    float* dst = &ctx[(size_t)b * CDIM + c];
#pragma unroll
    for (int j = 0; j < 4; ++j) atomicAdd(dst + j, acc[j]);
}

// ---------------------------------------------------------------------------
// ctx fp32 (fallback path)
// ---------------------------------------------------------------------------
__global__ __launch_bounds__(256)
void ctx_kernel(const float* __restrict__ hids, const float* __restrict__ attn,
                float* __restrict__ ctx)
{
    const int b   = blockIdx.x;
    const int s0  = blockIdx.y * (SRC_LEN / 8);
    const int tid = threadIdx.x;

    float4 acc = make_float4(0.f, 0.f, 0.f, 0.f);
    for (int s = s0; s < s0 + SRC_LEN / 8; ++s) {
        float w = attn[(size_t)s * BSZ + b];
        if (w != 0.f) {
            float4 h = *reinterpret_cast<const float4*>(
                &hids[((size_t)s * BSZ + b) * CDIM + tid * 4]);
            acc.x = fmaf(w, h.x, acc.x);
            acc.y = fmaf(w, h.y, acc.y);
            acc.z = fmaf(w, h.z, acc.z);
            acc.w = fmaf(w, h.w, acc.w);
        }
    }
    float* dst = &ctx[(size_t)b * CDIM + tid * 4];
    atomicAdd(dst + 0, acc.x);
    atomicAdd(dst + 1, acc.y);
    atomicAdd(dst + 2, acc.z);
    atomicAdd(dst + 3, acc.w);
}

// ---------------------------------------------------------------------------
extern "C" void kernel_launch(void* const* d_in, const int* in_sizes, int n_in,
                              void* d_out, int out_size, void* d_ws, size_t ws_size,
                              hipStream_t stream)
{
    const float* dsr   = (const float*)d_in[0];
    const float* hids  = (const float*)d_in[1];
    const int*   lens  = (const int*)  d_in[2];
    const float* W_enc = (const float*)d_in[3];
    const float* b_enc = (const float*)d_in[4];
    const float* W_dec = (const float*)d_in[5];
    const float* b_dec = (const float*)d_in[6];
    const float* v     = (const float*)d_in[7];

    float* out  = (float*)d_out;
    float* ctx  = out;                       // [64*1024]
    float* attn = out + BSZ * CDIM;          // [1024*64]

    const size_t decb_b = (size_t)BSZ * ADIM * 4;     // 256 KB
    const size_t scws_b = (size_t)MROWS * 4;          // 256 KB
    const size_t wf16_b = (size_t)ADIM * KDIM * 2;    // 2 MB
    const size_t af16_b = (size_t)MROWS * KDIM * 2;   // 128 MB

    float*    decb    = (float*)d_ws;
    float*    scoresW = (float*)((char*)d_ws + decb_b);
    _Float16* Wt      = (_Float16*)((char*)d_ws + decb_b + scws_b);
    _Float16* At      = (_Float16*)((char*)d_ws + decb_b + scws_b + wf16_b);

    const bool fast = ws_size >= decb_b + scws_b + wf16_b + af16_b;

    if (fast) {
        const int nW = (ADIM / 256) * 16 * 8;            // 512
        const int nA = (MROWS / 256) * 16 * 8;           // 32768
        prep_kernel<<<16 + nW + nA + 64, 256, 0, stream>>>(
            dsr, W_dec, decb, W_enc, Wt, hids, At, scoresW, ctx, nW, nA);
        enc_score_256<<<1024, 512, 0, stream>>>(At, Wt, decb, b_enc, b_dec, v, scoresW);
        softmax_ctx_kernel<<<dim3(8, BSZ), 256, 0, stream>>>(At, scoresW, lens, attn, ctx);
    } else {
        hipMemsetAsync(d_out, 0, (size_t)(BSZ * CDIM + SRC_LEN * BSZ) * sizeof(float), stream);
        dec_full_kernel<<<16, 256, 0, stream>>>(dsr, W_dec, decb);
        convert8_kernel<<<ADIM * KDIM / 8 / 256, 256, 0, stream>>>(W_enc, Wt);
        enc_score_fallback<<<4096, 256, 0, stream>>>(hids, Wt, decb, b_enc, b_dec, v, attn);
        softmax_kernel<<<BSZ, 256, 0, stream>>>(lens, attn);
        ctx_kernel<<<dim3(BSZ, 8), 256, 0, stream>>>(hids, attn, ctx);
    }
}

// Round 20
// 295.888 us; speedup vs baseline: 4.2598x; 1.0358x over previous
//
#include <hip/hip_runtime.h>
#include <math.h>

#define SRC_LEN  1024
#define BSZ      64
#define CDIM     1024
#define ADIM     1024
#define KDIM     1024
#define MROWS    (SRC_LEN * BSZ)
#define NEG_MASK -1000000.0f

// tiled fp16 layout (256-row tiles): tile = 256 rows x 64 cols,
//   fr = row>>4 (0..15), lr = row&15, cb = col>>3 (0..7), e = col&7
//   hw = fr*1024 + cb*128 + lr*8 + e       (tile = 16384 hw = 32 KB)
// At rows are B-MAJOR: m' = b*1024 + s  (enables per-(b,s-range) tile skip;
// tile mb = b*4 + t covers s in [t*256,(t+1)*256) of one b).
// W tiles keep identity rows. Fragment read is conflict-free as before.
#define THW256 16384

typedef _Float16 f16x8 __attribute__((ext_vector_type(8)));
typedef _Float16 f16x4 __attribute__((ext_vector_type(4)));
typedef float    f32x4 __attribute__((ext_vector_type(4)));

__device__ __forceinline__ float fast_tanh(float x) {
    float e = __expf(2.0f * x);
    return 1.0f - 2.0f / (e + 1.0f);
}

// async global(16B) -> LDS, per-lane global src, wave-uniform LDS base
__device__ __forceinline__ void gload16(const _Float16* g, _Float16* l) {
    __builtin_amdgcn_global_load_lds(
        (const __attribute__((address_space(1))) unsigned int*)g,
        (__attribute__((address_space(3))) unsigned int*)l, 16, 0, 0);
}

__device__ __forceinline__ f16x8 frag(const _Float16* buf, int fr, int ks,
                                      int g, int lc) {
    return *reinterpret_cast<const f16x8*>(
        &buf[fr * 1024 + ks * 512 + g * 128 + lc * 8]);
}

__device__ __forceinline__ f16x8 cvt8(float4 x, float4 y) {
    f16x8 o;
    o[0] = (_Float16)x.x; o[1] = (_Float16)x.y;
    o[2] = (_Float16)x.z; o[3] = (_Float16)x.w;
    o[4] = (_Float16)y.x; o[5] = (_Float16)y.y;
    o[6] = (_Float16)y.z; o[7] = (_Float16)y.w;
    return o;
}

// ---------------------------------------------------------------------------
// dec block body: decb[0..63][n0..n0+63] = dsr @ W_dec^T over full K.
// ---------------------------------------------------------------------------
__device__ __forceinline__ void dec_block(const float* __restrict__ A,
                                          const float* __restrict__ W,
                                          float* __restrict__ out,
                                          int n0, int tid,
                                          float (*Asl)[64], float (*Bsl)[64])
{
    const int tx = tid & 15;
    const int ty = tid >> 4;

    float acc[4][4];
#pragma unroll
    for (int i = 0; i < 4; ++i)
#pragma unroll
        for (int j = 0; j < 4; ++j) acc[i][j] = 0.f;

    const int lr = tid >> 2;
    const int lk = (tid & 3) * 4;

    for (int kb = 0; kb < KDIM; kb += 16) {
        float4 a4 = *reinterpret_cast<const float4*>(&A[(size_t)lr * KDIM + kb + lk]);
        float4 b4 = *reinterpret_cast<const float4*>(&W[(size_t)(n0 + lr) * KDIM + kb + lk]);
        __syncthreads();
        Asl[lk + 0][lr] = a4.x; Asl[lk + 1][lr] = a4.y;
        Asl[lk + 2][lr] = a4.z; Asl[lk + 3][lr] = a4.w;
        Bsl[lk + 0][lr] = b4.x; Bsl[lk + 1][lr] = b4.y;
        Bsl[lk + 2][lr] = b4.z; Bsl[lk + 3][lr] = b4.w;
        __syncthreads();
#pragma unroll
        for (int k = 0; k < 16; ++k) {
            float4 av = *reinterpret_cast<const float4*>(&Asl[k][ty * 4]);
            float4 bv = *reinterpret_cast<const float4*>(&Bsl[k][tx * 4]);
            float am[4] = {av.x, av.y, av.z, av.w};
            float bn[4] = {bv.x, bv.y, bv.z, bv.w};
#pragma unroll
            for (int i = 0; i < 4; ++i)
#pragma unroll
                for (int j = 0; j < 4; ++j)
                    acc[i][j] = fmaf(am[i], bn[j], acc[i][j]);
        }
    }
#pragma unroll
    for (int i = 0; i < 4; ++i) {
        int m = ty * 4 + i;
#pragma unroll
        for (int j = 0; j < 4; ++j) {
            int n = n0 + tx * 4 + j;
            out[(size_t)m * ADIM + n] = acc[i][j];
        }
    }
}

// ---------------------------------------------------------------------------
// PREP (fast path): blocks [0,16) dec; [16,16+nW) convert W (identity rows);
// [16+nW, 16+nW+nA) convert hids with B-MAJOR row permutation
// (dst m' = b*1024+s, src row = s*64+b); last 64 blocks zero scoresW + ctx.
// ---------------------------------------------------------------------------
__global__ __launch_bounds__(256)
void prep_kernel(const float* __restrict__ dsr, const float* __restrict__ Wdec,
                 float* __restrict__ decb,
                 const float* __restrict__ w_in, _Float16* __restrict__ w_out,
                 const float* __restrict__ a_in, _Float16* __restrict__ a_out,
                 float* __restrict__ zero1,      // scoresW [65536]
                 float* __restrict__ zero2,      // ctx     [65536]
                 int nW, int nA)
{
    __shared__ float Asl[16][64];
    __shared__ float Bsl[16][64];

    int bid = blockIdx.x;
    const int t = threadIdx.x;

    if (bid < 16) {
        dec_block(dsr, Wdec, decb, bid * 64, t, Asl, Bsl);
        return;
    }
    bid -= 16;

    if (bid >= nW + nA) {   // zero blocks: 2048 floats each
        int zid = bid - nW - nA;              // 0..63
        float* dst = (zid < 32) ? zero1 : zero2;
        int off = (zid & 31) * 2048 + t * 8;
        *reinterpret_cast<float4*>(&dst[off])     = make_float4(0.f, 0.f, 0.f, 0.f);
        *reinterpret_cast<float4*>(&dst[off + 4]) = make_float4(0.f, 0.f, 0.f, 0.f);
        return;
    }

    const bool isA = (bid >= nW);
    const float* in;
    _Float16* out;
    if (!isA) { in = w_in; out = w_out; }
    else      { in = a_in; out = a_out; bid -= nW; }

    const int part = bid & 7;
    const int tile = bid >> 3;           // rt*16 + kt
    const int kt   = tile & 15;
    const int rt   = tile >> 4;
    const int u    = part * 256 + t;     // 8-elem group 0..2047
    const int fr = u >> 7;
    const int cb = (u >> 4) & 7;
    const int lr = u & 15;

    const size_t drow = (size_t)rt * 256 + fr * 16 + lr;   // dst row
    size_t srow;
    if (isA) {
        const int bcol = (int)(drow >> 10);     // b
        const int s    = (int)(drow & 1023);    // s
        srow = (size_t)s * BSZ + bcol;
    } else {
        srow = drow;
    }
    const int col = kt * 64 + cb * 8;

    float4 x = *reinterpret_cast<const float4*>(&in[srow * KDIM + col]);
    float4 y = *reinterpret_cast<const float4*>(&in[srow * KDIM + col + 4]);
    *reinterpret_cast<f16x8*>(&out[(size_t)tile * THW256 + (size_t)u * 8]) = cvt8(x, y);
}

// ---------------------------------------------------------------------------
// Standalone dec (fallback path)
// ---------------------------------------------------------------------------
__global__ __launch_bounds__(256)
void dec_full_kernel(const float* __restrict__ A, const float* __restrict__ W,
                     float* __restrict__ out)
{
    __shared__ float Asl[16][64];
    __shared__ float Bsl[16][64];
    dec_block(A, W, out, blockIdx.x * 64, threadIdx.x, Asl, Bsl);
}

// ---------------------------------------------------------------------------
// fp32 -> fp16 linear (fallback path W conversion)
// ---------------------------------------------------------------------------
__global__ __launch_bounds__(256)
void convert8_kernel(const float* __restrict__ in, _Float16* __restrict__ out)
{
    size_t i = ((size_t)blockIdx.x * 256 + threadIdx.x) * 8;
    float4 x = *reinterpret_cast<const float4*>(in + i);
    float4 y = *reinterpret_cast<const float4*>(in + i + 4);
    *reinterpret_cast<f16x8*>(out + i) = cvt8(x, y);
}

// ---------------------------------------------------------------------------
// FAST PATH: 256x256 tile, BK=64, 8 waves (R16 schedule, 3 phases/K-tile).
// B-major rows: tile mb = b*4 + t covers (b, s in [t*256,(t+1)*256)).
// EARLY-EXIT when len[b] <= t*256 (tile fully masked; scoresW stays 0,
// softmax masks by len regardless). Uniform branch before any barrier.
// scores layout: [b*1024 + s] (b-major).
// ---------------------------------------------------------------------------
__global__ __launch_bounds__(512, 1)
void enc_score_256(const _Float16* __restrict__ At,   // [256*16] tiles, b-major
                   const _Float16* __restrict__ Bt,   // [4*16] tiles
                   const float* __restrict__ decb,    // [64][1024] (no bias)
                   const float* __restrict__ be,      // b_enc
                   const float* __restrict__ bd,      // b_dec
                   const float* __restrict__ v,       // [1024]
                   const int* __restrict__ lens,      // [64]
                   float* __restrict__ scores)        // ws [65536] b-major
{
    // nwg=1024, XCD-grouped: the 4 nbt-sharers of one mb on one XCD.
    const int bid = blockIdx.x;
    const int nbt = (bid >> 3) & 3;
    const int mb  = (bid & 7) + ((bid >> 5) << 3);
    const int bcol = mb >> 2;           // batch column of this tile
    const int t4   = mb & 3;            // s-range quarter

    if (lens[bcol] <= t4 * 256) return; // fully masked tile: skip (uniform)

    const int m0 = mb * 256, n0 = nbt * 256;
    const int tid  = threadIdx.x;
    const int lane = tid & 63;
    const int wid  = tid >> 6;          // 0..7
    const int wm   = wid >> 2;          // 0..1
    const int wn   = wid & 3;           // 0..3
    const int lc   = lane & 15, g = lane >> 4;

    __shared__ __align__(16) _Float16 As[2][THW256];   // 64 KB
    __shared__ __align__(16) _Float16 Bs[2][THW256];   // 64 KB

    f32x4 acc[8][4];
#pragma unroll
    for (int i = 0; i < 8; ++i)
#pragma unroll
        for (int j = 0; j < 4; ++j) acc[i][j] = (f32x4){0.f, 0.f, 0.f, 0.f};

    const _Float16* Abase = At + (size_t)(mb * 16) * THW256;
    const _Float16* Bbase = Bt + (size_t)(nbt * 16) * THW256;

    // ---- prologue: stage K-tile 0 into buffer 0 (8 gloads/wave) ----
#pragma unroll
    for (int i = 0; i < 4; ++i) {
        int c = wid * 4 + i;                  // chunk 0..31, 1KB each
        gload16(Abase + c * 512 + lane * 8, &As[0][c * 512]);
        gload16(Bbase + c * 512 + lane * 8, &Bs[0][c * 512]);
    }
    asm volatile("s_waitcnt vmcnt(0)" ::: "memory");
    __builtin_amdgcn_s_barrier();
    asm volatile("" ::: "memory");

    for (int kt = 0; kt < 16; ++kt) {
        const int cur = kt & 1;
        const _Float16* Acur = As[cur];
        const _Float16* Bcur = Bs[cur];
        _Float16* Anxt = As[cur ^ 1];
        _Float16* Bnxt = Bs[cur ^ 1];
        const _Float16* Ag = Abase + (size_t)(kt + 1) * THW256;
        const _Float16* Bg = Bbase + (size_t)(kt + 1) * THW256;
        const bool pre = (kt < 15);

        f16x8 af[4], bf[4];

        // ===== phase 0: ks=0, mi 0..3  (+ stage A of kt+1) =====
#pragma unroll
        for (int ni = 0; ni < 4; ++ni) bf[ni] = frag(Bcur, wn * 4 + ni, 0, g, lc);
#pragma unroll
        for (int i = 0; i < 4; ++i)    af[i]  = frag(Acur, wm * 8 + i, 0, g, lc);
        if (pre) {
#pragma unroll
            for (int i = 0; i < 4; ++i) {
                int c = wid * 4 + i;
                gload16(Ag + c * 512 + lane * 8, Anxt + c * 512);
            }
        }
        __builtin_amdgcn_s_barrier();
        asm volatile("s_waitcnt lgkmcnt(0)" ::: "memory");
        __builtin_amdgcn_sched_barrier(0);
        __builtin_amdgcn_s_setprio(1);
#pragma unroll
        for (int i = 0; i < 4; ++i)
#pragma unroll
            for (int ni = 0; ni < 4; ++ni)
                acc[i][ni] = __builtin_amdgcn_mfma_f32_16x16x32_f16(
                    af[i], bf[ni], acc[i][ni], 0, 0, 0);
        __builtin_amdgcn_s_setprio(0);
        __builtin_amdgcn_s_barrier();

        // ===== phase 1: ks=0, mi 4..7  (+ stage B of kt+1) =====
#pragma unroll
        for (int i = 0; i < 4; ++i) af[i] = frag(Acur, wm * 8 + 4 + i, 0, g, lc);
        if (pre) {
#pragma unroll
            for (int i = 0; i < 4; ++i) {
                int c = wid * 4 + i;
                gload16(Bg + c * 512 + lane * 8, Bnxt + c * 512);
            }
        }
        __builtin_amdgcn_s_barrier();
        asm volatile("s_waitcnt lgkmcnt(0)" ::: "memory");
        __builtin_amdgcn_sched_barrier(0);
        __builtin_amdgcn_s_setprio(1);
#pragma unroll
        for (int i = 0; i < 4; ++i)
#pragma unroll
            for (int ni = 0; ni < 4; ++ni)
                acc[4 + i][ni] = __builtin_amdgcn_mfma_f32_16x16x32_f16(
                    af[i], bf[ni], acc[4 + i][ni], 0, 0, 0);
        __builtin_amdgcn_s_setprio(0);
        __builtin_amdgcn_s_barrier();

        // ===== phase 2 (merged 2+3): ks=1, mi 0..7 =====
        f16x8 af8[8];
#pragma unroll
        for (int ni = 0; ni < 4; ++ni) bf[ni] = frag(Bcur, wn * 4 + ni, 1, g, lc);
#pragma unroll
        for (int i = 0; i < 8; ++i)    af8[i] = frag(Acur, wm * 8 + i, 1, g, lc);
        __builtin_amdgcn_s_barrier();
        asm volatile("s_waitcnt lgkmcnt(0)" ::: "memory");
        __builtin_amdgcn_sched_barrier(0);
        __builtin_amdgcn_s_setprio(1);
#pragma unroll
        for (int i = 0; i < 8; ++i)
#pragma unroll
            for (int ni = 0; ni < 4; ++ni)
                acc[i][ni] = __builtin_amdgcn_mfma_f32_16x16x32_f16(
                    af8[i], bf[ni], acc[i][ni], 0, 0, 0);
        __builtin_amdgcn_s_setprio(0);
        if (pre) asm volatile("s_waitcnt vmcnt(0)" ::: "memory");
        __builtin_amdgcn_s_barrier();
        asm volatile("" ::: "memory");
    }

    // ---- fused epilogue: tanh + v-dot + reduce (single b per tile) ----
    __syncthreads();

    float psum[8][4];
#pragma unroll
    for (int mi = 0; mi < 8; ++mi)
#pragma unroll
        for (int r = 0; r < 4; ++r) psum[mi][r] = 0.f;

#pragma unroll
    for (int mi = 0; mi < 8; ++mi) {
#pragma unroll
        for (int ni = 0; ni < 4; ++ni) {
            int n = n0 + wn * 64 + ni * 16 + lc;
            float vn = v[n];
            float bb = be[n] + bd[n] + decb[(size_t)bcol * ADIM + n];
#pragma unroll
            for (int r = 0; r < 4; ++r) {
                float x = acc[mi][ni][r] + bb;
                psum[mi][r] = fmaf(fast_tanh(x), vn, psum[mi][r]);
            }
        }
    }
#pragma unroll
    for (int mi = 0; mi < 8; ++mi)
#pragma unroll
        for (int r = 0; r < 4; ++r) {
            float s = psum[mi][r];
            s += __shfl_xor(s, 1);
            s += __shfl_xor(s, 2);
            s += __shfl_xor(s, 4);
            s += __shfl_xor(s, 8);
            psum[mi][r] = s;
        }

    float* red = reinterpret_cast<float*>(&As[0][0]);   // [256][4]
    if (lc == 0) {
#pragma unroll
        for (int mi = 0; mi < 8; ++mi)
#pragma unroll
            for (int r = 0; r < 4; ++r) {
                int row = wm * 128 + mi * 16 + g * 4 + r;
                red[row * 4 + wn] = psum[mi][r];
            }
    }
    __syncthreads();
    if (tid < 256)
        atomicAdd(&scores[m0 + tid],
                  red[tid * 4] + red[tid * 4 + 1] + red[tid * 4 + 2] + red[tid * 4 + 3]);
}

// ---------------------------------------------------------------------------
// FALLBACK (ws too small): reg-staged fp32-A 128x128 version (orig layouts).
// ---------------------------------------------------------------------------
__global__ __launch_bounds__(256)
void enc_score_fallback(const float* __restrict__ A,
                        const _Float16* __restrict__ Bw,
                        const float* __restrict__ decb,
                        const float* __restrict__ be,
                        const float* __restrict__ bd,
                        const float* __restrict__ v,
                        float* __restrict__ scores)
{
    const int bid = blockIdx.x;
    const int nb  = (bid >> 3) & 7;
    const int mb  = (bid & 7) + ((bid >> 6) << 3);
    const int m0 = mb * 128, n0 = nb * 128;
    const int tid  = threadIdx.x;
    const int lane = tid & 63;
    const int wid  = tid >> 6;
    const int wm   = wid >> 1, wn = wid & 1;
    const int lc   = lane & 15, g = lane >> 4;

    __shared__ __align__(16) _Float16 As[128 * 64];
    __shared__ __align__(16) _Float16 Bs[128 * 64];

    const int srow = tid >> 1;
    const int scol = (tid & 1) * 32;
    const int sw   = (srow & 7) << 3;

    f32x4 acc[4][4];
#pragma unroll
    for (int i = 0; i < 4; ++i)
#pragma unroll
        for (int j = 0; j < 4; ++j) acc[i][j] = (f32x4){0.f, 0.f, 0.f, 0.f};

    const float*    Aptr = A  + (size_t)(m0 + srow) * KDIM + scol;
    const _Float16* Bptr = Bw + (size_t)(n0 + srow) * KDIM + scol;

    float4 aR[8];
    uint4  bR[4];
#pragma unroll
    for (int i = 0; i < 8; ++i) aR[i] = reinterpret_cast<const float4*>(Aptr)[i];
#pragma unroll
    for (int i = 0; i < 4; ++i) bR[i] = reinterpret_cast<const uint4*>(Bptr)[i];

    for (int kb = 0; kb < KDIM; kb += 64) {
        __syncthreads();
#pragma unroll
        for (int w = 0; w < 4; ++w) {
            int hw = (srow * 64 + scol + 8 * w) ^ sw;
            *reinterpret_cast<f16x8*>(&As[hw]) = cvt8(aR[2 * w], aR[2 * w + 1]);
            *reinterpret_cast<uint4*>(&Bs[hw]) = bR[w];
        }
        __syncthreads();
        if (kb + 64 < KDIM) {
#pragma unroll
            for (int i = 0; i < 8; ++i)
                aR[i] = reinterpret_cast<const float4*>(Aptr + kb + 64)[i];
#pragma unroll
            for (int i = 0; i < 4; ++i)
                bR[i] = reinterpret_cast<const uint4*>(Bptr + kb + 64)[i];
        }
#pragma unroll
        for (int ks = 0; ks < 2; ++ks) {
            f16x8 af[4], bf[4];
#pragma unroll
            for (int mi = 0; mi < 4; ++mi) {
                int r  = wm * 64 + mi * 16 + lc;
                int hw = (r * 64 + ks * 32 + g * 8) ^ ((r & 7) << 3);
                af[mi] = *reinterpret_cast<const f16x8*>(&As[hw]);
            }
#pragma unroll
            for (int ni = 0; ni < 4; ++ni) {
                int r  = wn * 64 + ni * 16 + lc;
                int hw = (r * 64 + ks * 32 + g * 8) ^ ((r & 7) << 3);
                bf[ni] = *reinterpret_cast<const f16x8*>(&Bs[hw]);
            }
#pragma unroll
            for (int mi = 0; mi < 4; ++mi)
#pragma unroll
                for (int ni = 0; ni < 4; ++ni)
                    acc[mi][ni] = __builtin_amdgcn_mfma_f32_16x16x32_f16(
                        af[mi], bf[ni], acc[mi][ni], 0, 0, 0);
        }
    }

    __syncthreads();

    float psum[4][4];
#pragma unroll
    for (int mi = 0; mi < 4; ++mi)
#pragma unroll
        for (int r = 0; r < 4; ++r) psum[mi][r] = 0.f;

#pragma unroll
    for (int mi = 0; mi < 4; ++mi) {
#pragma unroll
        for (int ni = 0; ni < 4; ++ni) {
            int n = n0 + wn * 64 + ni * 16 + lc;
            float vn = v[n];
            float bb = be[n] + bd[n];
#pragma unroll
            for (int r = 0; r < 4; ++r) {
                int b = mi * 16 + g * 4 + r;
                float x = acc[mi][ni][r] + decb[(size_t)b * ADIM + n] + bb;
                psum[mi][r] = fmaf(fast_tanh(x), vn, psum[mi][r]);
            }
        }
    }
#pragma unroll
    for (int mi = 0; mi < 4; ++mi)
#pragma unroll
        for (int r = 0; r < 4; ++r) {
            float s = psum[mi][r];
            s += __shfl_xor(s, 1);
            s += __shfl_xor(s, 2);
            s += __shfl_xor(s, 4);
            s += __shfl_xor(s, 8);
            psum[mi][r] = s;
        }

    float* red = reinterpret_cast<float*>(As);
    if (lc == 0) {
#pragma unroll
        for (int mi = 0; mi < 4; ++mi)
#pragma unroll
            for (int r = 0; r < 4; ++r) {
                int row = wm * 64 + mi * 16 + g * 4 + r;
                red[row * 2 + wn] = psum[mi][r];
            }
    }
    __syncthreads();
    if (tid < 128)
        atomicAdd(&scores[m0 + tid], red[tid * 2] + red[tid * 2 + 1]);
}

// ---------------------------------------------------------------------------
// Masked softmax over S per batch column, in place (fallback path).
// ---------------------------------------------------------------------------
__global__ __launch_bounds__(256)
void softmax_kernel(const int* __restrict__ lens, float* __restrict__ attn)
{
    const int b   = blockIdx.x;
    const int tid = threadIdx.x;
    const int len = lens[b];

    float sc[4];
#pragma unroll
    for (int k = 0; k < 4; ++k) {
        int s = k * 256 + tid;
        float x = attn[(size_t)s * BSZ + b];
        sc[k] = (s < len) ? x : NEG_MASK;
    }

    __shared__ float red[8];

    float m = fmaxf(fmaxf(sc[0], sc[1]), fmaxf(sc[2], sc[3]));
#pragma unroll
    for (int off = 32; off > 0; off >>= 1) m = fmaxf(m, __shfl_xor(m, off));
    if ((tid & 63) == 0) red[tid >> 6] = m;
    __syncthreads();
    m = fmaxf(fmaxf(red[0], red[1]), fmaxf(red[2], red[3]));

    float e[4];
    float sum = 0.f;
#pragma unroll
    for (int k = 0; k < 4; ++k) { e[k] = expf(sc[k] - m); sum += e[k]; }
#pragma unroll
    for (int off = 32; off > 0; off >>= 1) sum += __shfl_xor(sum, off);
    __syncthreads();
    if ((tid & 63) == 0) red[4 + (tid >> 6)] = sum;
    __syncthreads();
    float total = red[4] + red[5] + red[6] + red[7];
    float inv = 1.f / total;

#pragma unroll
    for (int k = 0; k < 4; ++k) {
        int s = k * 256 + tid;
        attn[(size_t)s * BSZ + b] = e[k] * inv;
    }
}

// ---------------------------------------------------------------------------
// MERGED softmax+ctx (fast path). grid (8 sc, 64 b).
// scores ws is b-major ([b*1024+s], contiguous reads); At is b-major.
// ---------------------------------------------------------------------------
__global__ __launch_bounds__(256)
void softmax_ctx_kernel(const _Float16* __restrict__ At,
                        const float* __restrict__ scores,  // ws [65536] b-major
                        const int* __restrict__ lens,
                        float* __restrict__ attn,          // out [1024*64]
                        float* __restrict__ ctx)           // out [64*1024]
{
    const int sc  = blockIdx.x;          // 0..7
    const int b   = blockIdx.y;          // 0..63
    const int tid = threadIdx.x;
    const int len = lens[b];

    __shared__ float wl[SRC_LEN];        // 4 KB softmax weights
    __shared__ float red[8];

    float s4[4];
#pragma unroll
    for (int k = 0; k < 4; ++k) {
        int s = k * 256 + tid;
        float x = scores[(size_t)b * SRC_LEN + s];
        s4[k] = (s < len) ? x : NEG_MASK;
    }
    float m = fmaxf(fmaxf(s4[0], s4[1]), fmaxf(s4[2], s4[3]));
#pragma unroll
    for (int off = 32; off > 0; off >>= 1) m = fmaxf(m, __shfl_xor(m, off));
    if ((tid & 63) == 0) red[tid >> 6] = m;
    __syncthreads();
    m = fmaxf(fmaxf(red[0], red[1]), fmaxf(red[2], red[3]));

    float e[4];
    float sum = 0.f;
#pragma unroll
    for (int k = 0; k < 4; ++k) { e[k] = expf(s4[k] - m); sum += e[k]; }
#pragma unroll
    for (int off = 32; off > 0; off >>= 1) sum += __shfl_xor(sum, off);
    __syncthreads();
    if ((tid & 63) == 0) red[4 + (tid >> 6)] = sum;
    __syncthreads();
    float inv = 1.f / (red[4] + red[5] + red[6] + red[7]);

#pragma unroll
    for (int k = 0; k < 4; ++k) wl[k * 256 + tid] = e[k] * inv;
    __syncthreads();

    if (sc == 0) {
#pragma unroll
        for (int k = 0; k < 4; ++k) {
            int s = k * 256 + tid;
            attn[(size_t)s * BSZ + b] = wl[s];
        }
    }

    const int c   = tid * 4;
    const int kt  = c >> 6;
    const int cb  = (c >> 3) & 7;
    const int e2  = c & 7;
    const int sub = cb * 128 + e2;

    float acc[4] = {0.f, 0.f, 0.f, 0.f};
    for (int s = sc * (SRC_LEN / 8); s < (sc + 1) * (SRC_LEN / 8); ++s) {
        float w = wl[s];
        if (w != 0.f) {
            const int mm = b * SRC_LEN + s;     // b-major row
            const int rt = mm >> 8;
            const int fr = (mm >> 4) & 15;
            const int lr = mm & 15;
            f16x4 h = *reinterpret_cast<const f16x4*>(
                &At[(size_t)(rt * 16 + kt) * THW256 + fr * 1024 + sub + lr * 8]);
#pragma unroll
            for (int j = 0; j < 4; ++j) acc[j] = fmaf(w, (float)h[j], acc[j]);
        }
    }
    float* dst = &ctx[(size_t)b * CDIM + c];
#pragma unroll
    for (int j = 0; j < 4; ++j) atomicAdd(dst + j, acc[j]);
}

// ---------------------------------------------------------------------------
// ctx fp32 (fallback path)
// ---------------------------------------------------------------------------
__global__ __launch_bounds__(256)
void ctx_kernel(const float* __restrict__ hids, const float* __restrict__ attn,
                float* __restrict__ ctx)
{
    const int b   = blockIdx.x;
    const int s0  = blockIdx.y * (SRC_LEN / 8);
    const int tid = threadIdx.x;

    float4 acc = make_float4(0.f, 0.f, 0.f, 0.f);
    for (int s = s0; s < s0 + SRC_LEN / 8; ++s) {
        float w = attn[(size_t)s * BSZ + b];
        if (w != 0.f) {
            float4 h = *reinterpret_cast<const float4*>(
                &hids[((size_t)s * BSZ + b) * CDIM + tid * 4]);
            acc.x = fmaf(w, h.x, acc.x);
            acc.y = fmaf(w, h.y, acc.y);
            acc.z = fmaf(w, h.z, acc.z);
            acc.w = fmaf(w, h.w, acc.w);
        }
    }
    float* dst = &ctx[(size_t)b * CDIM + tid * 4];
    atomicAdd(dst + 0, acc.x);
    atomicAdd(dst + 1, acc.y);
    atomicAdd(dst + 2, acc.z);
    atomicAdd(dst + 3, acc.w);
}

// ---------------------------------------------------------------------------
extern "C" void kernel_launch(void* const* d_in, const int* in_sizes, int n_in,
                              void* d_out, int out_size, void* d_ws, size_t ws_size,
                              hipStream_t stream)
{
    const float* dsr   = (const float*)d_in[0];
    const float* hids  = (const float*)d_in[1];
    const int*   lens  = (const int*)  d_in[2];
    const float* W_enc = (const float*)d_in[3];
    const float* b_enc = (const float*)d_in[4];
    const float* W_dec = (const float*)d_in[5];
    const float* b_dec = (const float*)d_in[6];
    const float* v     = (const float*)d_in[7];

    float* out  = (float*)d_out;
    float* ctx  = out;                       // [64*1024]
    float* attn = out + BSZ * CDIM;          // [1024*64]

    const size_t decb_b = (size_t)BSZ * ADIM * 4;     // 256 KB
    const size_t scws_b = (size_t)MROWS * 4;          // 256 KB
    const size_t wf16_b = (size_t)ADIM * KDIM * 2;    // 2 MB
    const size_t af16_b = (size_t)MROWS * KDIM * 2;   // 128 MB

    float*    decb    = (float*)d_ws;
    float*    scoresW = (float*)((char*)d_ws + decb_b);
    _Float16* Wt      = (_Float16*)((char*)d_ws + decb_b + scws_b);
    _Float16* At      = (_Float16*)((char*)d_ws + decb_b + scws_b + wf16_b);

    const bool fast = ws_size >= decb_b + scws_b + wf16_b + af16_b;

    if (fast) {
        const int nW = (ADIM / 256) * 16 * 8;            // 512
        const int nA = (MROWS / 256) * 16 * 8;           // 32768
        prep_kernel<<<16 + nW + nA + 64, 256, 0, stream>>>(
            dsr, W_dec, decb, W_enc, Wt, hids, At, scoresW, ctx, nW, nA);
        enc_score_256<<<1024, 512, 0, stream>>>(At, Wt, decb, b_enc, b_dec, v,
                                                lens, scoresW);
        softmax_ctx_kernel<<<dim3(8, BSZ), 256, 0, stream>>>(At, scoresW, lens, attn, ctx);
    } else {
        hipMemsetAsync(d_out, 0, (size_t)(BSZ * CDIM + SRC_LEN * BSZ) * sizeof(float), stream);
        dec_full_kernel<<<16, 256, 0, stream>>>(dsr, W_dec, decb);
        convert8_kernel<<<ADIM * KDIM / 8 / 256, 256, 0, stream>>>(W_enc, Wt);
        enc_score_fallback<<<4096, 256, 0, stream>>>(hids, Wt, decb, b_enc, b_dec, v, attn);
        softmax_kernel<<<BSZ, 256, 0, stream>>>(lens, attn);
        ctx_kernel<<<dim3(BSZ, 8), 256, 0, stream>>>(hids, attn, ctx);
    }
}